// Round 4
// baseline (1069.110 us; speedup 1.0000x reference)
//
#include <hip/hip_runtime.h>
#include <stdint.h>
#include <math.h>

typedef unsigned short u16;
typedef __bf16 bf16x8 __attribute__((ext_vector_type(8)));
typedef float f32x4 __attribute__((ext_vector_type(4)));
typedef short s16x8 __attribute__((ext_vector_type(8)));
union B8 { s16x8 s; bf16x8 b; };

// ---------- helpers ----------
__device__ __forceinline__ u16 f2bf(float f) {
    union { __bf16 h; u16 u; } r;
    r.h = (__bf16)f;                    // native RNE cvt (v_cvt_pk_bf16_f32)
    return r.u;
}
__device__ __forceinline__ uint32_t pk2bf(float a, float b) {
    union { __bf16 h[2]; uint32_t u; } r;
    r.h[0] = (__bf16)a; r.h[1] = (__bf16)b;
    return r.u;
}

typedef const __attribute__((address_space(1))) uint32_t* gas_t;
typedef __attribute__((address_space(3))) uint32_t* las_t;
__device__ __forceinline__ void gld16(const void* g, void* l) {
    __builtin_amdgcn_global_load_lds((gas_t)g, (las_t)l, 16, 0, 0);
}

__host__ __device__ __forceinline__ uint32_t rotl32(uint32_t x, int d) {
    return (x << d) | (x >> (32 - d));
}

// JAX threefry2x32 (20 rounds)
__host__ __device__ __forceinline__ void tf2x32(uint32_t k0, uint32_t k1,
                                                uint32_t& x0, uint32_t& x1) {
    uint32_t k2 = k0 ^ k1 ^ 0x1BD11BDAu;
    x0 += k0; x1 += k1;
    x0 += x1; x1 = rotl32(x1, 13); x1 ^= x0;
    x0 += x1; x1 = rotl32(x1, 15); x1 ^= x0;
    x0 += x1; x1 = rotl32(x1, 26); x1 ^= x0;
    x0 += x1; x1 = rotl32(x1,  6); x1 ^= x0;
    x0 += k1; x1 += k2 + 1u;
    x0 += x1; x1 = rotl32(x1, 17); x1 ^= x0;
    x0 += x1; x1 = rotl32(x1, 29); x1 ^= x0;
    x0 += x1; x1 = rotl32(x1, 16); x1 ^= x0;
    x0 += x1; x1 = rotl32(x1, 24); x1 ^= x0;
    x0 += k2; x1 += k0 + 2u;
    x0 += x1; x1 = rotl32(x1, 13); x1 ^= x0;
    x0 += x1; x1 = rotl32(x1, 15); x1 ^= x0;
    x0 += x1; x1 = rotl32(x1, 26); x1 ^= x0;
    x0 += x1; x1 = rotl32(x1,  6); x1 ^= x0;
    x0 += k0; x1 += k1 + 3u;
    x0 += x1; x1 = rotl32(x1, 17); x1 ^= x0;
    x0 += x1; x1 = rotl32(x1, 29); x1 ^= x0;
    x0 += x1; x1 = rotl32(x1, 16); x1 ^= x0;
    x0 += x1; x1 = rotl32(x1, 24); x1 ^= x0;
    x0 += k1; x1 += k2 + 4u;
    x0 += x1; x1 = rotl32(x1, 13); x1 ^= x0;
    x0 += x1; x1 = rotl32(x1, 15); x1 ^= x0;
    x0 += x1; x1 = rotl32(x1, 26); x1 ^= x0;
    x0 += x1; x1 = rotl32(x1,  6); x1 ^= x0;
    x0 += k2; x1 += k0 + 5u;
}

// XLA ErfInv f32 (Giles polynomial)
__device__ __forceinline__ float erfinv_f(float x) {
    float w = -log1pf(-x * x);
    float p;
    if (w < 5.0f) {
        w = w - 2.5f;
        p = 2.81022636e-08f;
        p = p * w + 3.43273939e-07f;
        p = p * w + -3.5233877e-06f;
        p = p * w + -4.39150654e-06f;
        p = p * w + 0.00021858087f;
        p = p * w + -0.00125372503f;
        p = p * w + -0.00417768164f;
        p = p * w + 0.246640727f;
        p = p * w + 1.50140941f;
    } else {
        w = sqrtf(w) - 3.0f;
        p = -0.000200214257f;
        p = p * w + 0.000100950558f;
        p = p * w + 0.00134934322f;
        p = p * w + -0.00367342844f;
        p = p * w + 0.00573950773f;
        p = p * w + -0.0076224613f;
        p = p * w + 0.00943887047f;
        p = p * w + 1.00167406f;
        p = p * w + 2.83297682f;
    }
    return p * x;
}

__device__ __forceinline__ float tf_normal(uint32_t k0, uint32_t k1, uint32_t idx) {
    uint32_t x0 = 0u, x1 = idx;
    tf2x32(k0, k1, x0, x1);
    uint32_t bits = x0 ^ x1;
    float f = __uint_as_float((bits >> 9) | 0x3f800000u) - 1.0f;
    float u = f * 2.0f - 0.99999994f;
    u = fmaxf(-0.99999994f, u);
    return 1.41421354f * erfinv_f(u);
}

// ---------- noise init ----------
__global__ __launch_bounds__(256) void noise_kernel(
    float* __restrict__ x, u16* __restrict__ xb,
    uint32_t ka0, uint32_t ka1, float ca,
    uint32_t kb0, uint32_t kb1, float cb, int n)
{
    int i = blockIdx.x * 256 + threadIdx.x;
    if (i >= n) return;
    float a = ca * tf_normal(ka0, ka1, (uint32_t)i)
            + cb * tf_normal(kb0, kb1, (uint32_t)i);
    x[i]  = a;
    xb[i] = f2bf(a);
}

// ---------- f32 -> bf16 convert ----------
__global__ __launch_bounds__(256) void cvt_bf16_kernel(
    const float* __restrict__ s, u16* __restrict__ d, int n4)
{
    int i = blockIdx.x * 256 + threadIdx.x;
    if (i >= n4) return;
    float4 v = ((const float4*)s)[i];
    uint2 o;
    o.x = pk2bf(v.x, v.y);
    o.y = pk2bf(v.z, v.w);
    ((uint2*)d)[i] = o;
}

// ---------- build combined QKV weight [L][1536][512] bf16 ----------
__global__ __launch_bounds__(256) void cvt_qkvw_kernel(
    const float* __restrict__ Wq, const float* __restrict__ Wk,
    const float* __restrict__ Wv, u16* __restrict__ dst, int n4)
{
    int i = blockIdx.x * 256 + threadIdx.x;
    if (i >= n4) return;
    int e = i * 4;
    int l = e / 786432;
    int rem = e - l * 786432;
    int sel = rem >> 18;
    int off = rem & 262143;
    const float* src = (sel == 0 ? Wq : sel == 1 ? Wk : Wv) + l * 262144 + off;
    float4 v = *(const float4*)src;
    uint2 o;
    o.x = pk2bf(v.x, v.y);
    o.y = pk2bf(v.z, v.w);
    *(uint2*)(dst + e) = o;
}

// ---------- GEMM: out[M,N] = A @ Bw^T + bias (+resid)(+relu) ----------
// 128 x TN tile, BK=64, 4 waves (2x2). global_load_lds staging, pre-swizzled src.
// QKV mode (TN=128): N=1536 segments -> Q*0.125(out0), K(out1), V transposed(out2).
template<int TN, bool QKV, bool RELU, bool RESID, bool BF16OUT>
__global__ __launch_bounds__(256) void gemm_bt(
    const u16* __restrict__ A, const u16* __restrict__ Bw,
    const float* __restrict__ bias0, const float* __restrict__ bias1,
    const float* __restrict__ bias2, const float* __restrict__ resid,
    void* __restrict__ out0, void* __restrict__ out1, void* __restrict__ out2,
    int M, int N, int K)
{
    constexpr int ACH = 16;            // A chunks (8 rows x 64 k each)
    constexpr int BCH = TN / 8;        // B chunks
    constexpr int CPW = (ACH + BCH) / 4;
    constexpr int NF = TN / 32;        // B frags per wave
    __shared__ __align__(16) u16 At[128 * 64];
    __shared__ __align__(16) u16 Bt[TN * 64];
    const int tid = threadIdx.x;
    const int l = tid & 63;
    const int w = tid >> 6;
    const int wr = w >> 1, wc = w & 1;
    const int mb = blockIdx.y, nb = blockIdx.x;

    const int lrow = l >> 3;
    const int lch  = (l & 7) ^ lrow;

    const u16* aTile = A  + (size_t)(mb * 128) * K + (size_t)lrow * K + lch * 8;
    const u16* bTile = Bw + (size_t)(nb * TN) * K + (size_t)lrow * K + lch * 8;

    f32x4 acc[4][NF] = {};

    for (int k0 = 0; k0 < K; k0 += 64) {
        #pragma unroll
        for (int i = 0; i < CPW; ++i) {
            int c = w * CPW + i;
            if (c < ACH) gld16(aTile + (size_t)(c * 8) * K + k0, &At[c * 512]);
            else gld16(bTile + (size_t)((c - ACH) * 8) * K + k0, &Bt[(c - ACH) * 512]);
        }
        __syncthreads();
        #pragma unroll
        for (int kc = 0; kc < 2; ++kc) {
            B8 af[4], bfr[NF];
            #pragma unroll
            for (int m = 0; m < 4; ++m) {
                int r = wr * 64 + m * 16 + (l & 15);
                int ch = kc * 4 + (l >> 4);
                af[m].s = *(const s16x8*)&At[r * 64 + ((ch ^ (r & 7)) * 8)];
            }
            #pragma unroll
            for (int n = 0; n < NF; ++n) {
                int r = wc * (TN / 2) + n * 16 + (l & 15);
                int ch = kc * 4 + (l >> 4);
                bfr[n].s = *(const s16x8*)&Bt[r * 64 + ((ch ^ (r & 7)) * 8)];
            }
            #pragma unroll
            for (int m = 0; m < 4; ++m)
                #pragma unroll
                for (int n = 0; n < NF; ++n)
                    acc[m][n] = __builtin_amdgcn_mfma_f32_16x16x32_bf16(
                        af[m].b, bfr[n].b, acc[m][n], 0, 0, 0);
        }
        __syncthreads();
    }

    const float* biasp;
    void* outp;
    int colbase, Nout;
    float oscale = 1.0f;
    if constexpr (QKV) {
        int which = nb >> 2;
        colbase = (nb & 3) * 128 + wc * 64;
        if (which == 2) {
            // V: write bf16 transposed into vT[bh][64 d][1024 s]
            float bcol[NF];
            #pragma unroll
            for (int n = 0; n < NF; ++n)
                bcol[n] = bias2[colbase + n * 16 + (l & 15)];
            u16* vT = (u16*)out2;
            #pragma unroll
            for (int m = 0; m < 4; ++m) {
                int row0 = mb * 128 + wr * 64 + m * 16 + (l >> 4) * 4;
                int bb = row0 >> 10, s0 = row0 & 1023;
                #pragma unroll
                for (int n = 0; n < NF; ++n) {
                    int col = colbase + n * 16 + (l & 15);
                    int hh = col >> 6, dd = col & 63;
                    uint2 o;
                    o.x = pk2bf(acc[m][n][0] + bcol[n], acc[m][n][1] + bcol[n]);
                    o.y = pk2bf(acc[m][n][2] + bcol[n], acc[m][n][3] + bcol[n]);
                    *(uint2*)&vT[((size_t)((bb * 8 + hh) * 64 + dd)) * 1024 + s0] = o;
                }
            }
            return;
        }
        biasp = which == 0 ? bias0 : bias1;
        outp  = which == 0 ? out0  : out1;
        if (which == 0) oscale = 0.125f;    // fold softmax scale into Q (exact)
        Nout = 512;
    } else {
        colbase = nb * TN + wc * (TN / 2);
        biasp = bias0;
        outp = out0;
        Nout = N;
    }

    float bcol[NF];
    #pragma unroll
    for (int n = 0; n < NF; ++n)
        bcol[n] = biasp[colbase + n * 16 + (l & 15)];

    #pragma unroll
    for (int m = 0; m < 4; ++m) {
        #pragma unroll
        for (int j = 0; j < 4; ++j) {
            int row = mb * 128 + wr * 64 + m * 16 + (l >> 4) * 4 + j;
            #pragma unroll
            for (int n = 0; n < NF; ++n) {
                int col = colbase + n * 16 + (l & 15);
                float v = acc[m][n][j] + bcol[n];
                if constexpr (QKV) v *= oscale;
                if constexpr (RESID) v += resid[(size_t)row * Nout + col];
                if constexpr (RELU)  v = fmaxf(v, 0.0f);
                if constexpr (BF16OUT) ((u16*)outp)[(size_t)row * Nout + col] = f2bf(v);
                else                   ((float*)outp)[(size_t)row * Nout + col] = v;
            }
        }
    }
}

// ---------- LayerNorm ----------
__global__ __launch_bounds__(256) void ln_kernel(
    float* __restrict__ x, const float* __restrict__ g, const float* __restrict__ b,
    u16* __restrict__ xb)
{
    int row = blockIdx.x * 4 + (threadIdx.x >> 6);
    int l = threadIdx.x & 63;
    float4* xr = (float4*)(x + row * 512);
    float4 v0 = xr[l];
    float4 v1 = xr[l + 64];
    float s = v0.x + v0.y + v0.z + v0.w + v1.x + v1.y + v1.z + v1.w;
    float q = v0.x * v0.x + v0.y * v0.y + v0.z * v0.z + v0.w * v0.w
            + v1.x * v1.x + v1.y * v1.y + v1.z * v1.z + v1.w * v1.w;
    #pragma unroll
    for (int m = 1; m < 64; m <<= 1) {
        s += __shfl_xor(s, m, 64);
        q += __shfl_xor(q, m, 64);
    }
    float mean = s * (1.0f / 512.0f);
    float var  = q * (1.0f / 512.0f) - mean * mean;
    float rstd = rsqrtf(var + 1e-5f);
    const float4* gv = (const float4*)g;
    const float4* bv = (const float4*)b;
    float4 g0 = gv[l], g1 = gv[l + 64], b0 = bv[l], b1 = bv[l + 64];
    float4 o0, o1;
    o0.x = (v0.x - mean) * rstd * g0.x + b0.x;
    o0.y = (v0.y - mean) * rstd * g0.y + b0.y;
    o0.z = (v0.z - mean) * rstd * g0.z + b0.z;
    o0.w = (v0.w - mean) * rstd * g0.w + b0.w;
    o1.x = (v1.x - mean) * rstd * g1.x + b1.x;
    o1.y = (v1.y - mean) * rstd * g1.y + b1.y;
    o1.z = (v1.z - mean) * rstd * g1.z + b1.z;
    o1.w = (v1.w - mean) * rstd * g1.w + b1.w;
    xr[l] = o0; xr[l + 64] = o1;
    uint2 h0, h1;
    h0.x = pk2bf(o0.x, o0.y); h0.y = pk2bf(o0.z, o0.w);
    h1.x = pk2bf(o1.x, o1.y); h1.y = pk2bf(o1.z, o1.w);
    ((uint2*)(xb + row * 512))[l] = h0;
    ((uint2*)(xb + row * 512))[l + 64] = h1;
}

// ---------- fused attention v4: swapped-operand flash, 16 q-rows/wave ----------
// grid (64 bh, 16 qb), 256 thr = 4 independent waves. No barriers, no K/V LDS.
// S^T = mfma(K, Q*0.125-prescaled); q lane-local softmax w/ defer-max;
// O^T = mfma(vT, P^T); P through per-wave 2KB swizzled LDS.
__global__ __launch_bounds__(256) void attn_kernel(
    const u16* __restrict__ Q, const u16* __restrict__ Km,
    const u16* __restrict__ vT, u16* __restrict__ O)
{
    __shared__ __align__(16) char Pl[4][2048];
    const int tid = threadIdx.x;
    const int l = tid & 63;
    const int w = tid >> 6;
    const int g = l >> 4;
    const int q15 = l & 15;
    const int bh = blockIdx.x;
    const int qb = blockIdx.y;          // 0..15
    const int b = bh >> 3, h = bh & 7;
    const int rowQ0 = b * 1024 + qb * 64 + w * 16;
    const int colh = h * 64;
    char* pl = &Pl[w][0];
    const int sw = (q15 & 7) << 4;
    const int rbase = q15 * 128;

    B8 qf[2];
    #pragma unroll
    for (int kc = 0; kc < 2; ++kc)
        qf[kc].s = *(const s16x8*)&Q[(size_t)(rowQ0 + q15) * 512
                                     + colh + kc * 32 + g * 8];

    f32x4 oacc[4] = {};
    float mrun = -__builtin_huge_valf();
    float lrun = 0.0f;

    const u16* Kb0 = Km + (size_t)(b * 1024) * 512 + colh;
    const u16* Vb0 = vT + (size_t)bh * 64 * 1024;

    for (int kt = 0; kt < 16; ++kt) {
        // --- S^T = K (Q*0.125)^T; lane holds S^T[mt*16+g*4+jj][q15]
        f32x4 st[4];
        #pragma unroll
        for (int mt = 0; mt < 4; ++mt) {
            const u16* kr = Kb0 + (size_t)(kt * 64 + mt * 16 + q15) * 512;
            B8 kf0, kf1;
            kf0.s = *(const s16x8*)(kr + g * 8);
            kf1.s = *(const s16x8*)(kr + 32 + g * 8);
            f32x4 t = {0.f, 0.f, 0.f, 0.f};
            t = __builtin_amdgcn_mfma_f32_16x16x32_bf16(kf0.b, qf[0].b, t, 0, 0, 0);
            t = __builtin_amdgcn_mfma_f32_16x16x32_bf16(kf1.b, qf[1].b, t, 0, 0, 0);
            st[mt] = t;
        }

        // --- row max (q lane-local, reduce across g groups)
        float vm = st[0][0];
        #pragma unroll
        for (int mt = 0; mt < 4; ++mt)
            #pragma unroll
            for (int jj = 0; jj < 4; ++jj)
                vm = fmaxf(vm, st[mt][jj]);
        vm = fmaxf(vm, __shfl_xor(vm, 16, 64));
        vm = fmaxf(vm, __shfl_xor(vm, 32, 64));

        // --- defer-max rescale (T13, THR=8)
        if (__any(vm > mrun + 8.0f)) {
            float mn = fmaxf(mrun, vm);
            float alpha = __expf(mrun - mn);
            mrun = mn;
            lrun *= alpha;
            #pragma unroll
            for (int dt = 0; dt < 4; ++dt)
                #pragma unroll
                for (int jj = 0; jj < 4; ++jj)
                    oacc[dt][jj] *= alpha;
        }

        // --- P = exp(S - m), pack bf16 to per-wave LDS; row-sum
        float rs = 0.0f;
        #pragma unroll
        for (int mt = 0; mt < 4; ++mt) {
            float e0 = __expf(st[mt][0] - mrun);
            float e1 = __expf(st[mt][1] - mrun);
            float e2 = __expf(st[mt][2] - mrun);
            float e3 = __expf(st[mt][3] - mrun);
            rs += (e0 + e1) + (e2 + e3);
            uint2 pk;
            pk.x = pk2bf(e0, e1);
            pk.y = pk2bf(e2, e3);
            *(uint2*)(pl + rbase + ((mt * 32 + g * 8) ^ sw)) = pk;
        }
        rs += __shfl_xor(rs, 16, 64);
        rs += __shfl_xor(rs, 32, 64);
        lrun += rs;

        // --- read P^T B-frags
        B8 pf0, pf1;
        pf0.s = *(const s16x8*)(pl + rbase + ((g * 16) ^ sw));
        pf1.s = *(const s16x8*)(pl + rbase + (((4 + g) * 16) ^ sw));

        // --- O^T += vT * P^T
        #pragma unroll
        for (int dt = 0; dt < 4; ++dt) {
            const u16* vr = Vb0 + (size_t)(dt * 16 + q15) * 1024 + kt * 64;
            B8 vf0, vf1;
            vf0.s = *(const s16x8*)(vr + g * 8);
            vf1.s = *(const s16x8*)(vr + 32 + g * 8);
            oacc[dt] = __builtin_amdgcn_mfma_f32_16x16x32_bf16(
                vf0.b, pf0.b, oacc[dt], 0, 0, 0);
            oacc[dt] = __builtin_amdgcn_mfma_f32_16x16x32_bf16(
                vf1.b, pf1.b, oacc[dt], 0, 0, 0);
        }
    }

    // --- epilogue: O[q][d] = O^T / l
    float inv = 1.0f / lrun;
    int row = rowQ0 + q15;
    #pragma unroll
    for (int dt = 0; dt < 4; ++dt) {
        uint2 o;
        o.x = pk2bf(oacc[dt][0] * inv, oacc[dt][1] * inv);
        o.y = pk2bf(oacc[dt][2] * inv, oacc[dt][3] * inv);
        *(uint2*)&O[(size_t)row * 512 + colh + dt * 16 + g * 4] = o;
    }
}

// ---------- launcher ----------
extern "C" void kernel_launch(void* const* d_in, const int* in_sizes, int n_in,
                              void* d_out, int out_size, void* d_ws, size_t ws_size,
                              hipStream_t stream)
{
    const int D = 512, F = 2048, Lc = 4;
    const int Mrows = 8 * 1024;

    const float* Wq   = (const float*)d_in[1];
    const float* Wk   = (const float*)d_in[2];
    const float* Wv   = (const float*)d_in[3];
    const float* bq   = (const float*)d_in[4];
    const float* bk   = (const float*)d_in[5];
    const float* bv   = (const float*)d_in[6];
    const float* Wo   = (const float*)d_in[7];
    const float* bo   = (const float*)d_in[8];
    const float* ln1g = (const float*)d_in[9];
    const float* ln1b = (const float*)d_in[10];
    const float* ln2g = (const float*)d_in[11];
    const float* ln2b = (const float*)d_in[12];
    const float* W1   = (const float*)d_in[13];
    const float* b1   = (const float*)d_in[14];
    const float* W2   = (const float*)d_in[15];
    const float* b2   = (const float*)d_in[16];
    const float* Wout = (const float*)d_in[17];
    const float* bout = (const float*)d_in[18];

    char* p = (char*)d_ws;
    auto alloc = [&](size_t bytes) {
        char* r = p;
        p += (bytes + 255) & ~(size_t)255;
        return r;
    };
    float* xA = (float*)alloc((size_t)Mrows * D * 4);
    float* xB = (float*)alloc((size_t)Mrows * D * 4);
    u16* xb   = (u16*)alloc((size_t)Mrows * D * 2);
    char* pool = alloc((size_t)Mrows * F * 2);
    u16* qb_ = (u16*)pool;
    u16* kb_ = (u16*)(pool + (size_t)Mrows * D * 2);
    u16* vT  = (u16*)(pool + (size_t)Mrows * D * 2 * 2);   // [64 bh][64 d][1024 s]
    u16* ao  = (u16*)(pool + (size_t)Mrows * D * 2 * 3);
    u16* ff1 = (u16*)pool;
    u16* wqkvB = (u16*)alloc((size_t)Lc * 3 * D * D * 2);
    u16* woB   = (u16*)alloc((size_t)Lc * D * D * 2);
    u16* w1B   = (u16*)alloc((size_t)Lc * F * D * 2);
    u16* w2B   = (u16*)alloc((size_t)Lc * D * F * 2);
    u16* woutB = (u16*)alloc((size_t)D * D * 2);

    auto cvt = [&](const float* src, u16* dst, size_t n) {
        int n4 = (int)(n / 4);
        cvt_bf16_kernel<<<(n4 + 255) / 256, 256, 0, stream>>>(src, dst, n4);
    };
    {
        int n4 = Lc * 3 * D * D / 4;
        cvt_qkvw_kernel<<<(n4 + 255) / 256, 256, 0, stream>>>(Wq, Wk, Wv, wqkvB, n4);
    }
    cvt(Wo, woB, (size_t)Lc * D * D);
    cvt(W1, w1B, (size_t)Lc * F * D);
    cvt(W2, w2B, (size_t)Lc * D * F);
    cvt(Wout, woutB, (size_t)D * D);

    // DDIM noise coefficients
    float ac[1000];
    {
        float start = 1e-4f, stop = 0.02f;
        float delta = (stop - start) / 999.0f;
        float prod = 1.0f;
        for (int i = 0; i < 1000; ++i) {
            float beta = start + (float)i * delta;
            prod *= (1.0f - beta);
            ac[i] = prod;
        }
    }
    int ts[2] = {999, 998};
    double cs[2];
    double tail = 1.0;
    for (int idx = 0; idx < 2; ++idx) {
        int t = ts[idx];
        cs[idx] = sqrt(1.0 - (double)ac[t]) * tail;
        tail *= sqrt((double)ac[t]);
    }
    uint32_t kk[2][2];
    for (int idx = 0; idx < 2; ++idx) {
        uint32_t x0 = 0u, x1 = (uint32_t)ts[idx];
        tf2x32(0u, 42u, x0, x1);
        kk[idx][0] = x0; kk[idx][1] = x1;
    }
    int ntot = Mrows * D;
    noise_kernel<<<(ntot + 255) / 256, 256, 0, stream>>>(
        xA, xb,
        kk[0][0], kk[0][1], (float)cs[0],
        kk[1][0], kk[1][1], (float)cs[1], ntot);

    dim3 gqkv(3 * D / 128, Mrows / 128);   // (12, 64)
    dim3 g64(D / 64, Mrows / 128);         // (8, 64)
    dim3 gff1(F / 128, Mrows / 128);       // (16, 64)

    for (int l = 0; l < Lc; ++l) {
        const u16* wqkv_l = wqkvB + (size_t)l * 3 * D * D;
        const u16* wo_l = woB + (size_t)l * D * D;
        const u16* w1_l = w1B + (size_t)l * F * D;
        const u16* w2_l = w2B + (size_t)l * D * F;

        gemm_bt<128, true, false, false, true><<<gqkv, 256, 0, stream>>>(
            xb, wqkv_l, bq + l * D, bk + l * D, bv + l * D, nullptr,
            qb_, kb_, vT, Mrows, 3 * D, D);
        attn_kernel<<<dim3(64, 16), 256, 0, stream>>>(qb_, kb_, vT, ao);
        gemm_bt<64, false, false, true, false><<<g64, 256, 0, stream>>>(
            ao, wo_l, bo + l * D, nullptr, nullptr, xA,
            xB, nullptr, nullptr, Mrows, D, D);
        ln_kernel<<<Mrows / 4, 256, 0, stream>>>(xB, ln1g + l * D, ln1b + l * D, xb);
        gemm_bt<128, false, true, false, true><<<gff1, 256, 0, stream>>>(
            xb, w1_l, b1 + l * F, nullptr, nullptr, nullptr,
            ff1, nullptr, nullptr, Mrows, F, D);
        gemm_bt<64, false, false, true, false><<<g64, 256, 0, stream>>>(
            ff1, w2_l, b2 + l * D, nullptr, nullptr, xB,
            xA, nullptr, nullptr, Mrows, D, F);
        ln_kernel<<<Mrows / 4, 256, 0, stream>>>(xA, ln2g + l * D, ln2b + l * D, xb);
    }
    gemm_bt<64, false, false, false, false><<<g64, 256, 0, stream>>>(
        xb, woutB, bout, nullptr, nullptr, nullptr,
        d_out, nullptr, nullptr, Mrows, D, D);
}

// Round 5
// 754.722 us; speedup vs baseline: 1.4166x; 1.4166x over previous
//
#include <hip/hip_runtime.h>
#include <stdint.h>
#include <math.h>

typedef unsigned short u16;
typedef __bf16 bf16x8 __attribute__((ext_vector_type(8)));
typedef float f32x4 __attribute__((ext_vector_type(4)));
typedef short s16x8 __attribute__((ext_vector_type(8)));
union B8 { s16x8 s; bf16x8 b; };

// ---------- helpers ----------
__device__ __forceinline__ u16 f2bf(float f) {
    union { __bf16 h; u16 u; } r;
    r.h = (__bf16)f;
    return r.u;
}
__device__ __forceinline__ uint32_t pk2bf(float a, float b) {
    union { __bf16 h[2]; uint32_t u; } r;
    r.h[0] = (__bf16)a; r.h[1] = (__bf16)b;
    return r.u;
}

typedef const __attribute__((address_space(1))) uint32_t* gas_t;
typedef __attribute__((address_space(3))) uint32_t* las_t;
__device__ __forceinline__ void gld16(const void* g, void* l) {
    __builtin_amdgcn_global_load_lds((gas_t)g, (las_t)l, 16, 0, 0);
}

__host__ __device__ __forceinline__ uint32_t rotl32(uint32_t x, int d) {
    return (x << d) | (x >> (32 - d));
}

// JAX threefry2x32 (20 rounds)
__host__ __device__ __forceinline__ void tf2x32(uint32_t k0, uint32_t k1,
                                                uint32_t& x0, uint32_t& x1) {
    uint32_t k2 = k0 ^ k1 ^ 0x1BD11BDAu;
    x0 += k0; x1 += k1;
    x0 += x1; x1 = rotl32(x1, 13); x1 ^= x0;
    x0 += x1; x1 = rotl32(x1, 15); x1 ^= x0;
    x0 += x1; x1 = rotl32(x1, 26); x1 ^= x0;
    x0 += x1; x1 = rotl32(x1,  6); x1 ^= x0;
    x0 += k1; x1 += k2 + 1u;
    x0 += x1; x1 = rotl32(x1, 17); x1 ^= x0;
    x0 += x1; x1 = rotl32(x1, 29); x1 ^= x0;
    x0 += x1; x1 = rotl32(x1, 16); x1 ^= x0;
    x0 += x1; x1 = rotl32(x1, 24); x1 ^= x0;
    x0 += k2; x1 += k0 + 2u;
    x0 += x1; x1 = rotl32(x1, 13); x1 ^= x0;
    x0 += x1; x1 = rotl32(x1, 15); x1 ^= x0;
    x0 += x1; x1 = rotl32(x1, 26); x1 ^= x0;
    x0 += x1; x1 = rotl32(x1,  6); x1 ^= x0;
    x0 += k0; x1 += k1 + 3u;
    x0 += x1; x1 = rotl32(x1, 17); x1 ^= x0;
    x0 += x1; x1 = rotl32(x1, 29); x1 ^= x0;
    x0 += x1; x1 = rotl32(x1, 16); x1 ^= x0;
    x0 += x1; x1 = rotl32(x1, 24); x1 ^= x0;
    x0 += k1; x1 += k2 + 4u;
    x0 += x1; x1 = rotl32(x1, 13); x1 ^= x0;
    x0 += x1; x1 = rotl32(x1, 15); x1 ^= x0;
    x0 += x1; x1 = rotl32(x1, 26); x1 ^= x0;
    x0 += x1; x1 = rotl32(x1,  6); x1 ^= x0;
    x0 += k2; x1 += k0 + 5u;
}

// XLA ErfInv f32 (Giles polynomial)
__device__ __forceinline__ float erfinv_f(float x) {
    float w = -log1pf(-x * x);
    float p;
    if (w < 5.0f) {
        w = w - 2.5f;
        p = 2.81022636e-08f;
        p = p * w + 3.43273939e-07f;
        p = p * w + -3.5233877e-06f;
        p = p * w + -4.39150654e-06f;
        p = p * w + 0.00021858087f;
        p = p * w + -0.00125372503f;
        p = p * w + -0.00417768164f;
        p = p * w + 0.246640727f;
        p = p * w + 1.50140941f;
    } else {
        w = sqrtf(w) - 3.0f;
        p = -0.000200214257f;
        p = p * w + 0.000100950558f;
        p = p * w + 0.00134934322f;
        p = p * w + -0.00367342844f;
        p = p * w + 0.00573950773f;
        p = p * w + -0.0076224613f;
        p = p * w + 0.00943887047f;
        p = p * w + 1.00167406f;
        p = p * w + 2.83297682f;
    }
    return p * x;
}

__device__ __forceinline__ float tf_normal(uint32_t k0, uint32_t k1, uint32_t idx) {
    uint32_t x0 = 0u, x1 = idx;
    tf2x32(k0, k1, x0, x1);
    uint32_t bits = x0 ^ x1;
    float f = __uint_as_float((bits >> 9) | 0x3f800000u) - 1.0f;
    float u = f * 2.0f - 0.99999994f;
    u = fmaxf(-0.99999994f, u);
    return 1.41421354f * erfinv_f(u);
}

// ---------- noise init ----------
__global__ __launch_bounds__(256) void noise_kernel(
    float* __restrict__ x, u16* __restrict__ xb,
    uint32_t ka0, uint32_t ka1, float ca,
    uint32_t kb0, uint32_t kb1, float cb, int n)
{
    int i = blockIdx.x * 256 + threadIdx.x;
    if (i >= n) return;
    float a = ca * tf_normal(ka0, ka1, (uint32_t)i)
            + cb * tf_normal(kb0, kb1, (uint32_t)i);
    x[i]  = a;
    xb[i] = f2bf(a);
}

// ---------- f32 -> bf16 convert ----------
__global__ __launch_bounds__(256) void cvt_bf16_kernel(
    const float* __restrict__ s, u16* __restrict__ d, int n4)
{
    int i = blockIdx.x * 256 + threadIdx.x;
    if (i >= n4) return;
    float4 v = ((const float4*)s)[i];
    uint2 o;
    o.x = pk2bf(v.x, v.y);
    o.y = pk2bf(v.z, v.w);
    ((uint2*)d)[i] = o;
}

// ---------- build combined QKV weight [L][1536][512] bf16 ----------
__global__ __launch_bounds__(256) void cvt_qkvw_kernel(
    const float* __restrict__ Wq, const float* __restrict__ Wk,
    const float* __restrict__ Wv, u16* __restrict__ dst, int n4)
{
    int i = blockIdx.x * 256 + threadIdx.x;
    if (i >= n4) return;
    int e = i * 4;
    int l = e / 786432;
    int rem = e - l * 786432;
    int sel = rem >> 18;
    int off = rem & 262143;
    const float* src = (sel == 0 ? Wq : sel == 1 ? Wk : Wv) + l * 262144 + off;
    float4 v = *(const float4*)src;
    uint2 o;
    o.x = pk2bf(v.x, v.y);
    o.y = pk2bf(v.z, v.w);
    *(uint2*)(dst + e) = o;
}

// ---------- GEMM: out[M,N] = A @ Bw^T + bias (+resid)(+relu) ----------
template<int TN, bool QKV, bool RELU, bool RESID, bool BF16OUT>
__global__ __launch_bounds__(256) void gemm_bt(
    const u16* __restrict__ A, const u16* __restrict__ Bw,
    const float* __restrict__ bias0, const float* __restrict__ bias1,
    const float* __restrict__ bias2, const float* __restrict__ resid,
    void* __restrict__ out0, void* __restrict__ out1, void* __restrict__ out2,
    int M, int N, int K)
{
    constexpr int ACH = 16;
    constexpr int BCH = TN / 8;
    constexpr int CPW = (ACH + BCH) / 4;
    constexpr int NF = TN / 32;
    __shared__ __align__(16) u16 At[128 * 64];
    __shared__ __align__(16) u16 Bt[TN * 64];
    const int tid = threadIdx.x;
    const int l = tid & 63;
    const int w = tid >> 6;
    const int wr = w >> 1, wc = w & 1;
    const int mb = blockIdx.y, nb = blockIdx.x;

    const int lrow = l >> 3;
    const int lch  = (l & 7) ^ lrow;

    const u16* aTile = A  + (size_t)(mb * 128) * K + (size_t)lrow * K + lch * 8;
    const u16* bTile = Bw + (size_t)(nb * TN) * K + (size_t)lrow * K + lch * 8;

    f32x4 acc[4][NF] = {};

    for (int k0 = 0; k0 < K; k0 += 64) {
        #pragma unroll
        for (int i = 0; i < CPW; ++i) {
            int c = w * CPW + i;
            if (c < ACH) gld16(aTile + (size_t)(c * 8) * K + k0, &At[c * 512]);
            else gld16(bTile + (size_t)((c - ACH) * 8) * K + k0, &Bt[(c - ACH) * 512]);
        }
        __syncthreads();
        #pragma unroll
        for (int kc = 0; kc < 2; ++kc) {
            B8 af[4], bfr[NF];
            #pragma unroll
            for (int m = 0; m < 4; ++m) {
                int r = wr * 64 + m * 16 + (l & 15);
                int ch = kc * 4 + (l >> 4);
                af[m].s = *(const s16x8*)&At[r * 64 + ((ch ^ (r & 7)) * 8)];
            }
            #pragma unroll
            for (int n = 0; n < NF; ++n) {
                int r = wc * (TN / 2) + n * 16 + (l & 15);
                int ch = kc * 4 + (l >> 4);
                bfr[n].s = *(const s16x8*)&Bt[r * 64 + ((ch ^ (r & 7)) * 8)];
            }
            #pragma unroll
            for (int m = 0; m < 4; ++m)
                #pragma unroll
                for (int n = 0; n < NF; ++n)
                    acc[m][n] = __builtin_amdgcn_mfma_f32_16x16x32_bf16(
                        af[m].b, bfr[n].b, acc[m][n], 0, 0, 0);
        }
        __syncthreads();
    }

    const float* biasp;
    void* outp;
    int colbase, Nout;
    float oscale = 1.0f;
    if constexpr (QKV) {
        int which = nb >> 2;
        colbase = (nb & 3) * 128 + wc * 64;
        if (which == 2) {
            float bcol[NF];
            #pragma unroll
            for (int n = 0; n < NF; ++n)
                bcol[n] = bias2[colbase + n * 16 + (l & 15)];
            u16* vT = (u16*)out2;
            #pragma unroll
            for (int m = 0; m < 4; ++m) {
                int row0 = mb * 128 + wr * 64 + m * 16 + (l >> 4) * 4;
                int bb = row0 >> 10, s0 = row0 & 1023;
                #pragma unroll
                for (int n = 0; n < NF; ++n) {
                    int col = colbase + n * 16 + (l & 15);
                    int hh = col >> 6, dd = col & 63;
                    uint2 o;
                    o.x = pk2bf(acc[m][n][0] + bcol[n], acc[m][n][1] + bcol[n]);
                    o.y = pk2bf(acc[m][n][2] + bcol[n], acc[m][n][3] + bcol[n]);
                    *(uint2*)&vT[((size_t)((bb * 8 + hh) * 64 + dd)) * 1024 + s0] = o;
                }
            }
            return;
        }
        biasp = which == 0 ? bias0 : bias1;
        outp  = which == 0 ? out0  : out1;
        if (which == 0) oscale = 0.125f;
        Nout = 512;
    } else {
        colbase = nb * TN + wc * (TN / 2);
        biasp = bias0;
        outp = out0;
        Nout = N;
    }

    float bcol[NF];
    #pragma unroll
    for (int n = 0; n < NF; ++n)
        bcol[n] = biasp[colbase + n * 16 + (l & 15)];

    #pragma unroll
    for (int m = 0; m < 4; ++m) {
        #pragma unroll
        for (int j = 0; j < 4; ++j) {
            int row = mb * 128 + wr * 64 + m * 16 + (l >> 4) * 4 + j;
            #pragma unroll
            for (int n = 0; n < NF; ++n) {
                int col = colbase + n * 16 + (l & 15);
                float v = acc[m][n][j] + bcol[n];
                if constexpr (QKV) v *= oscale;
                if constexpr (RESID) v += resid[(size_t)row * Nout + col];
                if constexpr (RELU)  v = fmaxf(v, 0.0f);
                if constexpr (BF16OUT) ((u16*)outp)[(size_t)row * Nout + col] = f2bf(v);
                else                   ((float*)outp)[(size_t)row * Nout + col] = v;
            }
        }
    }
}

// ---------- LayerNorm ----------
__global__ __launch_bounds__(256) void ln_kernel(
    float* __restrict__ x, const float* __restrict__ g, const float* __restrict__ b,
    u16* __restrict__ xb)
{
    int row = blockIdx.x * 4 + (threadIdx.x >> 6);
    int l = threadIdx.x & 63;
    float4* xr = (float4*)(x + row * 512);
    float4 v0 = xr[l];
    float4 v1 = xr[l + 64];
    float s = v0.x + v0.y + v0.z + v0.w + v1.x + v1.y + v1.z + v1.w;
    float q = v0.x * v0.x + v0.y * v0.y + v0.z * v0.z + v0.w * v0.w
            + v1.x * v1.x + v1.y * v1.y + v1.z * v1.z + v1.w * v1.w;
    #pragma unroll
    for (int m = 1; m < 64; m <<= 1) {
        s += __shfl_xor(s, m, 64);
        q += __shfl_xor(q, m, 64);
    }
    float mean = s * (1.0f / 512.0f);
    float var  = q * (1.0f / 512.0f) - mean * mean;
    float rstd = rsqrtf(var + 1e-5f);
    const float4* gv = (const float4*)g;
    const float4* bv = (const float4*)b;
    float4 g0 = gv[l], g1 = gv[l + 64], b0 = bv[l], b1 = bv[l + 64];
    float4 o0, o1;
    o0.x = (v0.x - mean) * rstd * g0.x + b0.x;
    o0.y = (v0.y - mean) * rstd * g0.y + b0.y;
    o0.z = (v0.z - mean) * rstd * g0.z + b0.z;
    o0.w = (v0.w - mean) * rstd * g0.w + b0.w;
    o1.x = (v1.x - mean) * rstd * g1.x + b1.x;
    o1.y = (v1.y - mean) * rstd * g1.y + b1.y;
    o1.z = (v1.z - mean) * rstd * g1.z + b1.z;
    o1.w = (v1.w - mean) * rstd * g1.w + b1.w;
    xr[l] = o0; xr[l + 64] = o1;
    uint2 h0, h1;
    h0.x = pk2bf(o0.x, o0.y); h0.y = pk2bf(o0.z, o0.w);
    h1.x = pk2bf(o1.x, o1.y); h1.y = pk2bf(o1.z, o1.w);
    ((uint2*)(xb + row * 512))[l] = h0;
    ((uint2*)(xb + row * 512))[l + 64] = h1;
}

// ---------- fused attention v5: block-shared K/V LDS tiles, 2-phase prefetch ----
// grid (64 bh, 8 qb), 4 waves x 32 q-rows = 128 q-rows/block.
// K and vT (pre-transposed) staged via global_load_lds w/ pre-swizzled source;
// swizzled ds_read_b128 fragments (m97 pattern). Double-buffered, 1 barrier/kt.
// S^T = mfma(K, Q*0.125); q lane-local softmax w/ defer-max; O^T = mfma(V^T, P^T).
__global__ __launch_bounds__(256) void attn_kernel(
    const u16* __restrict__ Q, const u16* __restrict__ Km,
    const u16* __restrict__ vT, u16* __restrict__ O)
{
    __shared__ __align__(16) u16 Kt[2][64 * 64];
    __shared__ __align__(16) u16 Vt[2][64 * 64];
    __shared__ __align__(16) char Pl[4][4096];
    const int tid = threadIdx.x;
    const int l = tid & 63;
    const int w = tid >> 6;
    const int g = l >> 4;
    const int q15 = l & 15;
    const int bh = blockIdx.x;
    const int qb = blockIdx.y;          // 0..7
    const int b = bh >> 3, h = bh & 7;
    const int rowQ0 = b * 1024 + qb * 128 + w * 32;
    const int colh = h * 64;
    char* pl = &Pl[w][0];

    // staging lane geometry: chunk c covers rows c*8..c*8+7 (128B each);
    // lane -> (row = c*8 + l/8, src chunk = (l&7) ^ (row&7)); LDS dest linear.
    const int srow = l >> 3;            // 0..7 within chunk
    const u16* Kbase = Km + (size_t)(b * 1024) * 512 + colh;
    const u16* Vbase = vT + (size_t)bh * 64 * 1024;

    B8 qf[2][2];
    #pragma unroll
    for (int qt = 0; qt < 2; ++qt)
        #pragma unroll
        for (int kc = 0; kc < 2; ++kc)
            qf[qt][kc].s = *(const s16x8*)&Q[(size_t)(rowQ0 + qt * 16 + q15) * 512
                                            + colh + kc * 32 + g * 8];

    f32x4 oacc[4][2] = {};
    float mrun[2], lrun[2];
    mrun[0] = mrun[1] = -__builtin_huge_valf();
    lrun[0] = lrun[1] = 0.0f;

    auto stage = [&](int buf, int kt) {
        #pragma unroll
        for (int i = 0; i < 2; ++i) {
            int c = w * 2 + i;                     // 0..7
            int r = c * 8 + srow;
            int cc = (l & 7) ^ (r & 7);
            gld16(Kbase + (size_t)(kt * 64 + r) * 512 + cc * 8, &Kt[buf][c * 512]);
            gld16(Vbase + (size_t)r * 1024 + kt * 64 + cc * 8, &Vt[buf][c * 512]);
        }
    };

    stage(0, 0);
    __syncthreads();
    int cur = 0;

    for (int kt = 0; kt < 16; ++kt) {
        if (kt < 15) stage(cur ^ 1, kt + 1);
        const u16* KtL = &Kt[cur][0];
        const u16* VtL = &Vt[cur][0];

        // --- S^T = K (Q*0.125)^T
        f32x4 st[2][4];
        #pragma unroll
        for (int mt = 0; mt < 4; ++mt) {
            int r = mt * 16 + q15;
            B8 kf0, kf1;
            kf0.s = *(const s16x8*)&KtL[r * 64 + ((g ^ (r & 7)) * 8)];
            kf1.s = *(const s16x8*)&KtL[r * 64 + (((4 + g) ^ (r & 7)) * 8)];
            #pragma unroll
            for (int qt = 0; qt < 2; ++qt) {
                f32x4 t = {0.f, 0.f, 0.f, 0.f};
                t = __builtin_amdgcn_mfma_f32_16x16x32_bf16(kf0.b, qf[qt][0].b, t, 0, 0, 0);
                t = __builtin_amdgcn_mfma_f32_16x16x32_bf16(kf1.b, qf[qt][1].b, t, 0, 0, 0);
                st[qt][mt] = t;
            }
        }

        // --- online softmax (q lane-local) + pack P to per-wave LDS
        #pragma unroll
        for (int qt = 0; qt < 2; ++qt) {
            float vm = st[qt][0][0];
            #pragma unroll
            for (int mt = 0; mt < 4; ++mt)
                #pragma unroll
                for (int jj = 0; jj < 4; ++jj)
                    vm = fmaxf(vm, st[qt][mt][jj]);
            vm = fmaxf(vm, __shfl_xor(vm, 16, 64));
            vm = fmaxf(vm, __shfl_xor(vm, 32, 64));

            if (__any(vm > mrun[qt] + 8.0f)) {
                float mn = fmaxf(mrun[qt], vm);
                float alpha = __expf(mrun[qt] - mn);
                mrun[qt] = mn;
                lrun[qt] *= alpha;
                #pragma unroll
                for (int dt = 0; dt < 4; ++dt)
                    #pragma unroll
                    for (int jj = 0; jj < 4; ++jj)
                        oacc[dt][qt][jj] *= alpha;
            }

            int qrow = qt * 16 + q15;
            int rbase = qrow * 128;
            int sw = (qrow & 7) << 4;
            float rs = 0.0f;
            #pragma unroll
            for (int mt = 0; mt < 4; ++mt) {
                float e0 = __expf(st[qt][mt][0] - mrun[qt]);
                float e1 = __expf(st[qt][mt][1] - mrun[qt]);
                float e2 = __expf(st[qt][mt][2] - mrun[qt]);
                float e3 = __expf(st[qt][mt][3] - mrun[qt]);
                rs += (e0 + e1) + (e2 + e3);
                uint2 pk;
                pk.x = pk2bf(e0, e1);
                pk.y = pk2bf(e2, e3);
                *(uint2*)(pl + rbase + ((mt * 32 + g * 8) ^ sw)) = pk;
            }
            rs += __shfl_xor(rs, 16, 64);
            rs += __shfl_xor(rs, 32, 64);
            lrun[qt] += rs;
        }

        // --- read P^T B-frags
        B8 pf[2][2];
        #pragma unroll
        for (int qt = 0; qt < 2; ++qt) {
            int qrow = qt * 16 + q15;
            int sw = (qrow & 7) << 4;
            pf[qt][0].s = *(const s16x8*)(pl + qrow * 128 + ((g * 16) ^ sw));
            pf[qt][1].s = *(const s16x8*)(pl + qrow * 128 + (((4 + g) * 16) ^ sw));
        }

        // --- O^T += V^T * P^T
        #pragma unroll
        for (int dt = 0; dt < 4; ++dt) {
            int r = dt * 16 + q15;
            B8 vf0, vf1;
            vf0.s = *(const s16x8*)&VtL[r * 64 + ((g ^ (r & 7)) * 8)];
            vf1.s = *(const s16x8*)&VtL[r * 64 + (((4 + g) ^ (r & 7)) * 8)];
            #pragma unroll
            for (int qt = 0; qt < 2; ++qt) {
                oacc[dt][qt] = __builtin_amdgcn_mfma_f32_16x16x32_bf16(
                    vf0.b, pf[qt][0].b, oacc[dt][qt], 0, 0, 0);
                oacc[dt][qt] = __builtin_amdgcn_mfma_f32_16x16x32_bf16(
                    vf1.b, pf[qt][1].b, oacc[dt][qt], 0, 0, 0);
            }
        }
        __syncthreads();
        cur ^= 1;
    }

    // --- epilogue: O[q][d] = O^T / l
    #pragma unroll
    for (int qt = 0; qt < 2; ++qt) {
        float inv = 1.0f / lrun[qt];
        int row = rowQ0 + qt * 16 + q15;
        #pragma unroll
        for (int dt = 0; dt < 4; ++dt) {
            uint2 o;
            o.x = pk2bf(oacc[dt][qt][0] * inv, oacc[dt][qt][1] * inv);
            o.y = pk2bf(oacc[dt][qt][2] * inv, oacc[dt][qt][3] * inv);
            *(uint2*)&O[(size_t)row * 512 + colh + dt * 16 + g * 4] = o;
        }
    }
}

// ---------- launcher ----------
extern "C" void kernel_launch(void* const* d_in, const int* in_sizes, int n_in,
                              void* d_out, int out_size, void* d_ws, size_t ws_size,
                              hipStream_t stream)
{
    const int D = 512, F = 2048, Lc = 4;
    const int Mrows = 8 * 1024;

    const float* Wq   = (const float*)d_in[1];
    const float* Wk   = (const float*)d_in[2];
    const float* Wv   = (const float*)d_in[3];
    const float* bq   = (const float*)d_in[4];
    const float* bk   = (const float*)d_in[5];
    const float* bv   = (const float*)d_in[6];
    const float* Wo   = (const float*)d_in[7];
    const float* bo   = (const float*)d_in[8];
    const float* ln1g = (const float*)d_in[9];
    const float* ln1b = (const float*)d_in[10];
    const float* ln2g = (const float*)d_in[11];
    const float* ln2b = (const float*)d_in[12];
    const float* W1   = (const float*)d_in[13];
    const float* b1   = (const float*)d_in[14];
    const float* W2   = (const float*)d_in[15];
    const float* b2   = (const float*)d_in[16];
    const float* Wout = (const float*)d_in[17];
    const float* bout = (const float*)d_in[18];

    char* p = (char*)d_ws;
    auto alloc = [&](size_t bytes) {
        char* r = p;
        p += (bytes + 255) & ~(size_t)255;
        return r;
    };
    float* xA = (float*)alloc((size_t)Mrows * D * 4);
    float* xB = (float*)alloc((size_t)Mrows * D * 4);
    u16* xb   = (u16*)alloc((size_t)Mrows * D * 2);
    char* pool = alloc((size_t)Mrows * F * 2);
    u16* qb_ = (u16*)pool;
    u16* kb_ = (u16*)(pool + (size_t)Mrows * D * 2);
    u16* vT  = (u16*)(pool + (size_t)Mrows * D * 2 * 2);   // [64 bh][64 d][1024 s]
    u16* ao  = (u16*)(pool + (size_t)Mrows * D * 2 * 3);
    u16* ff1 = (u16*)pool;
    u16* wqkvB = (u16*)alloc((size_t)Lc * 3 * D * D * 2);
    u16* woB   = (u16*)alloc((size_t)Lc * D * D * 2);
    u16* w1B   = (u16*)alloc((size_t)Lc * F * D * 2);
    u16* w2B   = (u16*)alloc((size_t)Lc * D * F * 2);
    u16* woutB = (u16*)alloc((size_t)D * D * 2);

    auto cvt = [&](const float* src, u16* dst, size_t n) {
        int n4 = (int)(n / 4);
        cvt_bf16_kernel<<<(n4 + 255) / 256, 256, 0, stream>>>(src, dst, n4);
    };
    {
        int n4 = Lc * 3 * D * D / 4;
        cvt_qkvw_kernel<<<(n4 + 255) / 256, 256, 0, stream>>>(Wq, Wk, Wv, wqkvB, n4);
    }
    cvt(Wo, woB, (size_t)Lc * D * D);
    cvt(W1, w1B, (size_t)Lc * F * D);
    cvt(W2, w2B, (size_t)Lc * D * F);
    cvt(Wout, woutB, (size_t)D * D);

    // DDIM noise coefficients
    float ac[1000];
    {
        float start = 1e-4f, stop = 0.02f;
        float delta = (stop - start) / 999.0f;
        float prod = 1.0f;
        for (int i = 0; i < 1000; ++i) {
            float beta = start + (float)i * delta;
            prod *= (1.0f - beta);
            ac[i] = prod;
        }
    }
    int ts[2] = {999, 998};
    double cs[2];
    double tail = 1.0;
    for (int idx = 0; idx < 2; ++idx) {
        int t = ts[idx];
        cs[idx] = sqrt(1.0 - (double)ac[t]) * tail;
        tail *= sqrt((double)ac[t]);
    }
    uint32_t kk[2][2];
    for (int idx = 0; idx < 2; ++idx) {
        uint32_t x0 = 0u, x1 = (uint32_t)ts[idx];
        tf2x32(0u, 42u, x0, x1);
        kk[idx][0] = x0; kk[idx][1] = x1;
    }
    int ntot = Mrows * D;
    noise_kernel<<<(ntot + 255) / 256, 256, 0, stream>>>(
        xA, xb,
        kk[0][0], kk[0][1], (float)cs[0],
        kk[1][0], kk[1][1], (float)cs[1], ntot);

    dim3 gqkv(3 * D / 128, Mrows / 128);   // (12, 64)
    dim3 g64(D / 64, Mrows / 128);         // (8, 64)
    dim3 gff1(F / 128, Mrows / 128);       // (16, 64)

    for (int l = 0; l < Lc; ++l) {
        const u16* wqkv_l = wqkvB + (size_t)l * 3 * D * D;
        const u16* wo_l = woB + (size_t)l * D * D;
        const u16* w1_l = w1B + (size_t)l * F * D;
        const u16* w2_l = w2B + (size_t)l * D * F;

        gemm_bt<128, true, false, false, true><<<gqkv, 256, 0, stream>>>(
            xb, wqkv_l, bq + l * D, bk + l * D, bv + l * D, nullptr,
            qb_, kb_, vT, Mrows, 3 * D, D);
        attn_kernel<<<dim3(64, 8), 256, 0, stream>>>(qb_, kb_, vT, ao);
        gemm_bt<64, false, false, true, false><<<g64, 256, 0, stream>>>(
            ao, wo_l, bo + l * D, nullptr, nullptr, xA,
            xB, nullptr, nullptr, Mrows, D, D);
        ln_kernel<<<Mrows / 4, 256, 0, stream>>>(xB, ln1g + l * D, ln1b + l * D, xb);
        gemm_bt<128, false, true, false, true><<<gff1, 256, 0, stream>>>(
            xb, w1_l, b1 + l * F, nullptr, nullptr, nullptr,
            ff1, nullptr, nullptr, Mrows, F, D);
        gemm_bt<64, false, false, true, false><<<g64, 256, 0, stream>>>(
            ff1, w2_l, b2 + l * D, nullptr, nullptr, xB,
            xA, nullptr, nullptr, Mrows, D, F);
        ln_kernel<<<Mrows / 4, 256, 0, stream>>>(xA, ln2g + l * D, ln2b + l * D, xb);
    }
    gemm_bt<64, false, false, false, false><<<g64, 256, 0, stream>>>(
        xb, woutB, bout, nullptr, nullptr, nullptr,
        d_out, nullptr, nullptr, Mrows, D, D);
}

// Round 6
// 663.150 us; speedup vs baseline: 1.6122x; 1.1381x over previous
//
#include <hip/hip_runtime.h>
#include <stdint.h>
#include <math.h>

typedef unsigned short u16;
typedef __bf16 bf16x8 __attribute__((ext_vector_type(8)));
typedef float f32x4 __attribute__((ext_vector_type(4)));
typedef short s16x8 __attribute__((ext_vector_type(8)));
union B8 { s16x8 s; bf16x8 b; };

// ---------- helpers ----------
__device__ __forceinline__ u16 f2bf(float f) {
    union { __bf16 h; u16 u; } r;
    r.h = (__bf16)f;
    return r.u;
}
__device__ __forceinline__ uint32_t pk2bf(float a, float b) {
    union { __bf16 h[2]; uint32_t u; } r;
    r.h[0] = (__bf16)a; r.h[1] = (__bf16)b;
    return r.u;
}

typedef const __attribute__((address_space(1))) uint32_t* gas_t;
typedef __attribute__((address_space(3))) uint32_t* las_t;
__device__ __forceinline__ void gld16(const void* g, void* l) {
    __builtin_amdgcn_global_load_lds((gas_t)g, (las_t)l, 16, 0, 0);
}

__host__ __device__ __forceinline__ uint32_t rotl32(uint32_t x, int d) {
    return (x << d) | (x >> (32 - d));
}

// JAX threefry2x32 (20 rounds)
__host__ __device__ __forceinline__ void tf2x32(uint32_t k0, uint32_t k1,
                                                uint32_t& x0, uint32_t& x1) {
    uint32_t k2 = k0 ^ k1 ^ 0x1BD11BDAu;
    x0 += k0; x1 += k1;
    x0 += x1; x1 = rotl32(x1, 13); x1 ^= x0;
    x0 += x1; x1 = rotl32(x1, 15); x1 ^= x0;
    x0 += x1; x1 = rotl32(x1, 26); x1 ^= x0;
    x0 += x1; x1 = rotl32(x1,  6); x1 ^= x0;
    x0 += k1; x1 += k2 + 1u;
    x0 += x1; x1 = rotl32(x1, 17); x1 ^= x0;
    x0 += x1; x1 = rotl32(x1, 29); x1 ^= x0;
    x0 += x1; x1 = rotl32(x1, 16); x1 ^= x0;
    x0 += x1; x1 = rotl32(x1, 24); x1 ^= x0;
    x0 += k2; x1 += k0 + 2u;
    x0 += x1; x1 = rotl32(x1, 13); x1 ^= x0;
    x0 += x1; x1 = rotl32(x1, 15); x1 ^= x0;
    x0 += x1; x1 = rotl32(x1, 26); x1 ^= x0;
    x0 += x1; x1 = rotl32(x1,  6); x1 ^= x0;
    x0 += k0; x1 += k1 + 3u;
    x0 += x1; x1 = rotl32(x1, 17); x1 ^= x0;
    x0 += x1; x1 = rotl32(x1, 29); x1 ^= x0;
    x0 += x1; x1 = rotl32(x1, 16); x1 ^= x0;
    x0 += x1; x1 = rotl32(x1, 24); x1 ^= x0;
    x0 += k1; x1 += k2 + 4u;
    x0 += x1; x1 = rotl32(x1, 13); x1 ^= x0;
    x0 += x1; x1 = rotl32(x1, 15); x1 ^= x0;
    x0 += x1; x1 = rotl32(x1, 26); x1 ^= x0;
    x0 += x1; x1 = rotl32(x1,  6); x1 ^= x0;
    x0 += k2; x1 += k0 + 5u;
}

// XLA ErfInv f32 (Giles polynomial)
__device__ __forceinline__ float erfinv_f(float x) {
    float w = -log1pf(-x * x);
    float p;
    if (w < 5.0f) {
        w = w - 2.5f;
        p = 2.81022636e-08f;
        p = p * w + 3.43273939e-07f;
        p = p * w + -3.5233877e-06f;
        p = p * w + -4.39150654e-06f;
        p = p * w + 0.00021858087f;
        p = p * w + -0.00125372503f;
        p = p * w + -0.00417768164f;
        p = p * w + 0.246640727f;
        p = p * w + 1.50140941f;
    } else {
        w = sqrtf(w) - 3.0f;
        p = -0.000200214257f;
        p = p * w + 0.000100950558f;
        p = p * w + 0.00134934322f;
        p = p * w + -0.00367342844f;
        p = p * w + 0.00573950773f;
        p = p * w + -0.0076224613f;
        p = p * w + 0.00943887047f;
        p = p * w + 1.00167406f;
        p = p * w + 2.83297682f;
    }
    return p * x;
}

__device__ __forceinline__ float tf_normal(uint32_t k0, uint32_t k1, uint32_t idx) {
    uint32_t x0 = 0u, x1 = idx;
    tf2x32(k0, k1, x0, x1);
    uint32_t bits = x0 ^ x1;
    float f = __uint_as_float((bits >> 9) | 0x3f800000u) - 1.0f;
    float u = f * 2.0f - 0.99999994f;
    u = fmaxf(-0.99999994f, u);
    return 1.41421354f * erfinv_f(u);
}

// ---------- noise init ----------
__global__ __launch_bounds__(256) void noise_kernel(
    float* __restrict__ x, u16* __restrict__ xb,
    uint32_t ka0, uint32_t ka1, float ca,
    uint32_t kb0, uint32_t kb1, float cb, int n)
{
    int i = blockIdx.x * 256 + threadIdx.x;
    if (i >= n) return;
    float a = ca * tf_normal(ka0, ka1, (uint32_t)i)
            + cb * tf_normal(kb0, kb1, (uint32_t)i);
    x[i]  = a;
    xb[i] = f2bf(a);
}

// ---------- f32 -> bf16 convert ----------
__global__ __launch_bounds__(256) void cvt_bf16_kernel(
    const float* __restrict__ s, u16* __restrict__ d, int n4)
{
    int i = blockIdx.x * 256 + threadIdx.x;
    if (i >= n4) return;
    float4 v = ((const float4*)s)[i];
    uint2 o;
    o.x = pk2bf(v.x, v.y);
    o.y = pk2bf(v.z, v.w);
    ((uint2*)d)[i] = o;
}

// ---------- build combined QKV weight [L][1536][512] bf16 ----------
__global__ __launch_bounds__(256) void cvt_qkvw_kernel(
    const float* __restrict__ Wq, const float* __restrict__ Wk,
    const float* __restrict__ Wv, u16* __restrict__ dst, int n4)
{
    int i = blockIdx.x * 256 + threadIdx.x;
    if (i >= n4) return;
    int e = i * 4;
    int l = e / 786432;
    int rem = e - l * 786432;
    int sel = rem >> 18;
    int off = rem & 262143;
    const float* src = (sel == 0 ? Wq : sel == 1 ? Wk : Wv) + l * 262144 + off;
    float4 v = *(const float4*)src;
    uint2 o;
    o.x = pk2bf(v.x, v.y);
    o.y = pk2bf(v.z, v.w);
    *(uint2*)(dst + e) = o;
}

// ---------- GEMM: out[M,N] = A @ Bw^T + bias (+resid)(+relu) ----------
// 128 x TN tile, BK=64, 4 waves. global_load_lds staging, pre-swizzled source.
// XCD-bijective block swizzle (each XCD gets contiguous mb-chunk x all nb).
// DBUF: 2-phase double-buffer prefetch (stage k+1 before computing k).
template<int TN, bool DBUF, bool QKV, bool RELU, bool RESID, bool BF16OUT>
__global__ __launch_bounds__(256) void gemm_bt(
    const u16* __restrict__ A, const u16* __restrict__ Bw,
    const float* __restrict__ bias0, const float* __restrict__ bias1,
    const float* __restrict__ bias2, const float* __restrict__ resid,
    void* __restrict__ out0, void* __restrict__ out1, void* __restrict__ out2,
    int M, int N, int K)
{
    constexpr int ACH = 16;
    constexpr int BCH = TN / 8;
    constexpr int CPW = (ACH + BCH) / 4;
    constexpr int NF = TN / 32;
    constexpr int NBUF = DBUF ? 2 : 1;
    constexpr int ASZ = 128 * 64;
    constexpr int BSZ = TN * 64;
    __shared__ __align__(16) u16 At[NBUF * ASZ];
    __shared__ __align__(16) u16 Bt[NBUF * BSZ];
    const int tid = threadIdx.x;
    const int l = tid & 63;
    const int w = tid >> 6;
    const int wr = w >> 1, wc = w & 1;

    // XCD-bijective swizzle: HW assigns linear wgid round-robin to 8 XCDs.
    int lid = blockIdx.y * gridDim.x + blockIdx.x;
    int nwg = gridDim.x * gridDim.y;
    int mb, nb;
    if ((nwg & 7) == 0) {
        int nlid = (lid & 7) * (nwg >> 3) + (lid >> 3);
        mb = nlid / gridDim.x;
        nb = nlid - mb * gridDim.x;
    } else { mb = blockIdx.y; nb = blockIdx.x; }

    const int lrow = l >> 3;
    const int lch  = (l & 7) ^ lrow;

    const u16* aTile = A  + (size_t)(mb * 128) * K + (size_t)lrow * K + lch * 8;
    const u16* bTile = Bw + (size_t)(nb * TN) * K + (size_t)lrow * K + lch * 8;

    f32x4 acc[4][NF] = {};

    auto stage = [&](int buf, int k0) {
        #pragma unroll
        for (int i = 0; i < CPW; ++i) {
            int c = w * CPW + i;
            if (c < ACH) gld16(aTile + (size_t)(c * 8) * K + k0, &At[buf * ASZ + c * 512]);
            else gld16(bTile + (size_t)((c - ACH) * 8) * K + k0, &Bt[buf * BSZ + (c - ACH) * 512]);
        }
    };
    auto compute = [&](int buf) {
        const u16* Ac = &At[buf * ASZ];
        const u16* Bc = &Bt[buf * BSZ];
        #pragma unroll
        for (int kc = 0; kc < 2; ++kc) {
            B8 af[4], bfr[NF];
            #pragma unroll
            for (int m = 0; m < 4; ++m) {
                int r = wr * 64 + m * 16 + (l & 15);
                int ch = kc * 4 + (l >> 4);
                af[m].s = *(const s16x8*)&Ac[r * 64 + ((ch ^ (r & 7)) * 8)];
            }
            #pragma unroll
            for (int n = 0; n < NF; ++n) {
                int r = wc * (TN / 2) + n * 16 + (l & 15);
                int ch = kc * 4 + (l >> 4);
                bfr[n].s = *(const s16x8*)&Bc[r * 64 + ((ch ^ (r & 7)) * 8)];
            }
            #pragma unroll
            for (int m = 0; m < 4; ++m)
                #pragma unroll
                for (int n = 0; n < NF; ++n)
                    acc[m][n] = __builtin_amdgcn_mfma_f32_16x16x32_bf16(
                        af[m].b, bfr[n].b, acc[m][n], 0, 0, 0);
        }
    };

    if constexpr (DBUF) {
        stage(0, 0);
        __syncthreads();
        int cur = 0;
        for (int k0 = 0; k0 < K; k0 += 64) {
            if (k0 + 64 < K) stage(cur ^ 1, k0 + 64);
            compute(cur);
            __syncthreads();
            cur ^= 1;
        }
    } else {
        for (int k0 = 0; k0 < K; k0 += 64) {
            stage(0, k0);
            __syncthreads();
            compute(0);
            __syncthreads();
        }
    }

    const float* biasp;
    void* outp;
    int colbase, Nout;
    float oscale = 1.0f;
    if constexpr (QKV) {
        int which = nb >> 2;
        colbase = (nb & 3) * 128 + wc * 64;
        if (which == 2) {
            float bcol[NF];
            #pragma unroll
            for (int n = 0; n < NF; ++n)
                bcol[n] = bias2[colbase + n * 16 + (l & 15)];
            u16* vT = (u16*)out2;
            #pragma unroll
            for (int m = 0; m < 4; ++m) {
                int row0 = mb * 128 + wr * 64 + m * 16 + (l >> 4) * 4;
                int bb = row0 >> 10, s0 = row0 & 1023;
                #pragma unroll
                for (int n = 0; n < NF; ++n) {
                    int col = colbase + n * 16 + (l & 15);
                    int hh = col >> 6, dd = col & 63;
                    uint2 o;
                    o.x = pk2bf(acc[m][n][0] + bcol[n], acc[m][n][1] + bcol[n]);
                    o.y = pk2bf(acc[m][n][2] + bcol[n], acc[m][n][3] + bcol[n]);
                    *(uint2*)&vT[((size_t)((bb * 8 + hh) * 64 + dd)) * 1024 + s0] = o;
                }
            }
            return;
        }
        biasp = which == 0 ? bias0 : bias1;
        outp  = which == 0 ? out0  : out1;
        if (which == 0) oscale = 0.125f;
        Nout = 512;
    } else {
        colbase = nb * TN + wc * (TN / 2);
        biasp = bias0;
        outp = out0;
        Nout = N;
    }

    float bcol[NF];
    #pragma unroll
    for (int n = 0; n < NF; ++n)
        bcol[n] = biasp[colbase + n * 16 + (l & 15)];

    #pragma unroll
    for (int m = 0; m < 4; ++m) {
        #pragma unroll
        for (int j = 0; j < 4; ++j) {
            int row = mb * 128 + wr * 64 + m * 16 + (l >> 4) * 4 + j;
            #pragma unroll
            for (int n = 0; n < NF; ++n) {
                int col = colbase + n * 16 + (l & 15);
                float v = acc[m][n][j] + bcol[n];
                if constexpr (QKV) v *= oscale;
                if constexpr (RESID) v += resid[(size_t)row * Nout + col];
                if constexpr (RELU)  v = fmaxf(v, 0.0f);
                if constexpr (BF16OUT) ((u16*)outp)[(size_t)row * Nout + col] = f2bf(v);
                else                   ((float*)outp)[(size_t)row * Nout + col] = v;
            }
        }
    }
}

// ---------- LayerNorm ----------
__global__ __launch_bounds__(256) void ln_kernel(
    float* __restrict__ x, const float* __restrict__ g, const float* __restrict__ b,
    u16* __restrict__ xb)
{
    int row = blockIdx.x * 4 + (threadIdx.x >> 6);
    int l = threadIdx.x & 63;
    float4* xr = (float4*)(x + row * 512);
    float4 v0 = xr[l];
    float4 v1 = xr[l + 64];
    float s = v0.x + v0.y + v0.z + v0.w + v1.x + v1.y + v1.z + v1.w;
    float q = v0.x * v0.x + v0.y * v0.y + v0.z * v0.z + v0.w * v0.w
            + v1.x * v1.x + v1.y * v1.y + v1.z * v1.z + v1.w * v1.w;
    #pragma unroll
    for (int m = 1; m < 64; m <<= 1) {
        s += __shfl_xor(s, m, 64);
        q += __shfl_xor(q, m, 64);
    }
    float mean = s * (1.0f / 512.0f);
    float var  = q * (1.0f / 512.0f) - mean * mean;
    float rstd = rsqrtf(var + 1e-5f);
    const float4* gv = (const float4*)g;
    const float4* bv = (const float4*)b;
    float4 g0 = gv[l], g1 = gv[l + 64], b0 = bv[l], b1 = bv[l + 64];
    float4 o0, o1;
    o0.x = (v0.x - mean) * rstd * g0.x + b0.x;
    o0.y = (v0.y - mean) * rstd * g0.y + b0.y;
    o0.z = (v0.z - mean) * rstd * g0.z + b0.z;
    o0.w = (v0.w - mean) * rstd * g0.w + b0.w;
    o1.x = (v1.x - mean) * rstd * g1.x + b1.x;
    o1.y = (v1.y - mean) * rstd * g1.y + b1.y;
    o1.z = (v1.z - mean) * rstd * g1.z + b1.z;
    o1.w = (v1.w - mean) * rstd * g1.w + b1.w;
    xr[l] = o0; xr[l + 64] = o1;
    uint2 h0, h1;
    h0.x = pk2bf(o0.x, o0.y); h0.y = pk2bf(o0.z, o0.w);
    h1.x = pk2bf(o1.x, o1.y); h1.y = pk2bf(o1.z, o1.w);
    ((uint2*)(xb + row * 512))[l] = h0;
    ((uint2*)(xb + row * 512))[l + 64] = h1;
}

// ---------- fused attention v5: block-shared K/V LDS tiles, 2-phase prefetch ----
__global__ __launch_bounds__(256) void attn_kernel(
    const u16* __restrict__ Q, const u16* __restrict__ Km,
    const u16* __restrict__ vT, u16* __restrict__ O)
{
    __shared__ __align__(16) u16 Kt[2][64 * 64];
    __shared__ __align__(16) u16 Vt[2][64 * 64];
    __shared__ __align__(16) char Pl[4][4096];
    const int tid = threadIdx.x;
    const int l = tid & 63;
    const int w = tid >> 6;
    const int g = l >> 4;
    const int q15 = l & 15;
    const int bh = blockIdx.x;
    const int qb = blockIdx.y;
    const int b = bh >> 3, h = bh & 7;
    const int rowQ0 = b * 1024 + qb * 128 + w * 32;
    const int colh = h * 64;
    char* pl = &Pl[w][0];

    const int srow = l >> 3;
    const u16* Kbase = Km + (size_t)(b * 1024) * 512 + colh;
    const u16* Vbase = vT + (size_t)bh * 64 * 1024;

    B8 qf[2][2];
    #pragma unroll
    for (int qt = 0; qt < 2; ++qt)
        #pragma unroll
        for (int kc = 0; kc < 2; ++kc)
            qf[qt][kc].s = *(const s16x8*)&Q[(size_t)(rowQ0 + qt * 16 + q15) * 512
                                            + colh + kc * 32 + g * 8];

    f32x4 oacc[4][2] = {};
    float mrun[2], lrun[2];
    mrun[0] = mrun[1] = -__builtin_huge_valf();
    lrun[0] = lrun[1] = 0.0f;

    auto stage = [&](int buf, int kt) {
        #pragma unroll
        for (int i = 0; i < 2; ++i) {
            int c = w * 2 + i;
            int r = c * 8 + srow;
            int cc = (l & 7) ^ (r & 7);
            gld16(Kbase + (size_t)(kt * 64 + r) * 512 + cc * 8, &Kt[buf][c * 512]);
            gld16(Vbase + (size_t)r * 1024 + kt * 64 + cc * 8, &Vt[buf][c * 512]);
        }
    };

    stage(0, 0);
    __syncthreads();
    int cur = 0;

    for (int kt = 0; kt < 16; ++kt) {
        if (kt < 15) stage(cur ^ 1, kt + 1);
        const u16* KtL = &Kt[cur][0];
        const u16* VtL = &Vt[cur][0];

        f32x4 st[2][4];
        #pragma unroll
        for (int mt = 0; mt < 4; ++mt) {
            int r = mt * 16 + q15;
            B8 kf0, kf1;
            kf0.s = *(const s16x8*)&KtL[r * 64 + ((g ^ (r & 7)) * 8)];
            kf1.s = *(const s16x8*)&KtL[r * 64 + (((4 + g) ^ (r & 7)) * 8)];
            #pragma unroll
            for (int qt = 0; qt < 2; ++qt) {
                f32x4 t = {0.f, 0.f, 0.f, 0.f};
                t = __builtin_amdgcn_mfma_f32_16x16x32_bf16(kf0.b, qf[qt][0].b, t, 0, 0, 0);
                t = __builtin_amdgcn_mfma_f32_16x16x32_bf16(kf1.b, qf[qt][1].b, t, 0, 0, 0);
                st[qt][mt] = t;
            }
        }

        #pragma unroll
        for (int qt = 0; qt < 2; ++qt) {
            float vm = st[qt][0][0];
            #pragma unroll
            for (int mt = 0; mt < 4; ++mt)
                #pragma unroll
                for (int jj = 0; jj < 4; ++jj)
                    vm = fmaxf(vm, st[qt][mt][jj]);
            vm = fmaxf(vm, __shfl_xor(vm, 16, 64));
            vm = fmaxf(vm, __shfl_xor(vm, 32, 64));

            if (__any(vm > mrun[qt] + 8.0f)) {
                float mn = fmaxf(mrun[qt], vm);
                float alpha = __expf(mrun[qt] - mn);
                mrun[qt] = mn;
                lrun[qt] *= alpha;
                #pragma unroll
                for (int dt = 0; dt < 4; ++dt)
                    #pragma unroll
                    for (int jj = 0; jj < 4; ++jj)
                        oacc[dt][qt][jj] *= alpha;
            }

            int qrow = qt * 16 + q15;
            int rbase = qrow * 128;
            int sw = (qrow & 7) << 4;
            float rs = 0.0f;
            #pragma unroll
            for (int mt = 0; mt < 4; ++mt) {
                float e0 = __expf(st[qt][mt][0] - mrun[qt]);
                float e1 = __expf(st[qt][mt][1] - mrun[qt]);
                float e2 = __expf(st[qt][mt][2] - mrun[qt]);
                float e3 = __expf(st[qt][mt][3] - mrun[qt]);
                rs += (e0 + e1) + (e2 + e3);
                uint2 pk;
                pk.x = pk2bf(e0, e1);
                pk.y = pk2bf(e2, e3);
                *(uint2*)(pl + rbase + ((mt * 32 + g * 8) ^ sw)) = pk;
            }
            rs += __shfl_xor(rs, 16, 64);
            rs += __shfl_xor(rs, 32, 64);
            lrun[qt] += rs;
        }

        B8 pf[2][2];
        #pragma unroll
        for (int qt = 0; qt < 2; ++qt) {
            int qrow = qt * 16 + q15;
            int sw = (qrow & 7) << 4;
            pf[qt][0].s = *(const s16x8*)(pl + qrow * 128 + ((g * 16) ^ sw));
            pf[qt][1].s = *(const s16x8*)(pl + qrow * 128 + (((4 + g) * 16) ^ sw));
        }

        #pragma unroll
        for (int dt = 0; dt < 4; ++dt) {
            int r = dt * 16 + q15;
            B8 vf0, vf1;
            vf0.s = *(const s16x8*)&VtL[r * 64 + ((g ^ (r & 7)) * 8)];
            vf1.s = *(const s16x8*)&VtL[r * 64 + (((4 + g) ^ (r & 7)) * 8)];
            #pragma unroll
            for (int qt = 0; qt < 2; ++qt) {
                oacc[dt][qt] = __builtin_amdgcn_mfma_f32_16x16x32_bf16(
                    vf0.b, pf[qt][0].b, oacc[dt][qt], 0, 0, 0);
                oacc[dt][qt] = __builtin_amdgcn_mfma_f32_16x16x32_bf16(
                    vf1.b, pf[qt][1].b, oacc[dt][qt], 0, 0, 0);
            }
        }
        __syncthreads();
        cur ^= 1;
    }

    #pragma unroll
    for (int qt = 0; qt < 2; ++qt) {
        float inv = 1.0f / lrun[qt];
        int row = rowQ0 + qt * 16 + q15;
        #pragma unroll
        for (int dt = 0; dt < 4; ++dt) {
            uint2 o;
            o.x = pk2bf(oacc[dt][qt][0] * inv, oacc[dt][qt][1] * inv);
            o.y = pk2bf(oacc[dt][qt][2] * inv, oacc[dt][qt][3] * inv);
            *(uint2*)&O[(size_t)row * 512 + colh + dt * 16 + g * 4] = o;
        }
    }
}

// ---------- launcher ----------
extern "C" void kernel_launch(void* const* d_in, const int* in_sizes, int n_in,
                              void* d_out, int out_size, void* d_ws, size_t ws_size,
                              hipStream_t stream)
{
    const int D = 512, F = 2048, Lc = 4;
    const int Mrows = 8 * 1024;

    const float* Wq   = (const float*)d_in[1];
    const float* Wk   = (const float*)d_in[2];
    const float* Wv   = (const float*)d_in[3];
    const float* bq   = (const float*)d_in[4];
    const float* bk   = (const float*)d_in[5];
    const float* bv   = (const float*)d_in[6];
    const float* Wo   = (const float*)d_in[7];
    const float* bo   = (const float*)d_in[8];
    const float* ln1g = (const float*)d_in[9];
    const float* ln1b = (const float*)d_in[10];
    const float* ln2g = (const float*)d_in[11];
    const float* ln2b = (const float*)d_in[12];
    const float* W1   = (const float*)d_in[13];
    const float* b1   = (const float*)d_in[14];
    const float* W2   = (const float*)d_in[15];
    const float* b2   = (const float*)d_in[16];
    const float* Wout = (const float*)d_in[17];
    const float* bout = (const float*)d_in[18];

    char* p = (char*)d_ws;
    auto alloc = [&](size_t bytes) {
        char* r = p;
        p += (bytes + 255) & ~(size_t)255;
        return r;
    };
    float* xA = (float*)alloc((size_t)Mrows * D * 4);
    float* xB = (float*)alloc((size_t)Mrows * D * 4);
    u16* xb   = (u16*)alloc((size_t)Mrows * D * 2);
    char* pool = alloc((size_t)Mrows * F * 2);
    u16* qb_ = (u16*)pool;
    u16* kb_ = (u16*)(pool + (size_t)Mrows * D * 2);
    u16* vT  = (u16*)(pool + (size_t)Mrows * D * 2 * 2);   // [64 bh][64 d][1024 s]
    u16* ao  = (u16*)(pool + (size_t)Mrows * D * 2 * 3);
    u16* ff1 = (u16*)pool;
    u16* wqkvB = (u16*)alloc((size_t)Lc * 3 * D * D * 2);
    u16* woB   = (u16*)alloc((size_t)Lc * D * D * 2);
    u16* w1B   = (u16*)alloc((size_t)Lc * F * D * 2);
    u16* w2B   = (u16*)alloc((size_t)Lc * D * F * 2);
    u16* woutB = (u16*)alloc((size_t)D * D * 2);

    auto cvt = [&](const float* src, u16* dst, size_t n) {
        int n4 = (int)(n / 4);
        cvt_bf16_kernel<<<(n4 + 255) / 256, 256, 0, stream>>>(src, dst, n4);
    };
    {
        int n4 = Lc * 3 * D * D / 4;
        cvt_qkvw_kernel<<<(n4 + 255) / 256, 256, 0, stream>>>(Wq, Wk, Wv, wqkvB, n4);
    }
    cvt(Wo, woB, (size_t)Lc * D * D);
    cvt(W1, w1B, (size_t)Lc * F * D);
    cvt(W2, w2B, (size_t)Lc * D * F);
    cvt(Wout, woutB, (size_t)D * D);

    // DDIM noise coefficients
    float ac[1000];
    {
        float start = 1e-4f, stop = 0.02f;
        float delta = (stop - start) / 999.0f;
        float prod = 1.0f;
        for (int i = 0; i < 1000; ++i) {
            float beta = start + (float)i * delta;
            prod *= (1.0f - beta);
            ac[i] = prod;
        }
    }
    int ts[2] = {999, 998};
    double cs[2];
    double tail = 1.0;
    for (int idx = 0; idx < 2; ++idx) {
        int t = ts[idx];
        cs[idx] = sqrt(1.0 - (double)ac[t]) * tail;
        tail *= sqrt((double)ac[t]);
    }
    uint32_t kk[2][2];
    for (int idx = 0; idx < 2; ++idx) {
        uint32_t x0 = 0u, x1 = (uint32_t)ts[idx];
        tf2x32(0u, 42u, x0, x1);
        kk[idx][0] = x0; kk[idx][1] = x1;
    }
    int ntot = Mrows * D;
    noise_kernel<<<(ntot + 255) / 256, 256, 0, stream>>>(
        xA, xb,
        kk[0][0], kk[0][1], (float)cs[0],
        kk[1][0], kk[1][1], (float)cs[1], ntot);

    dim3 gqkv(3 * D / 128, Mrows / 128);   // (12, 64) = 768
    dim3 g64(D / 64, Mrows / 128);         // (8, 64) = 512
    dim3 gff1(F / 128, Mrows / 128);       // (16, 64) = 1024

    for (int l = 0; l < Lc; ++l) {
        const u16* wqkv_l = wqkvB + (size_t)l * 3 * D * D;
        const u16* wo_l = woB + (size_t)l * D * D;
        const u16* w1_l = w1B + (size_t)l * F * D;
        const u16* w2_l = w2B + (size_t)l * D * F;

        gemm_bt<128, false, true, false, false, true><<<gqkv, 256, 0, stream>>>(
            xb, wqkv_l, bq + l * D, bk + l * D, bv + l * D, nullptr,
            qb_, kb_, vT, Mrows, 3 * D, D);
        attn_kernel<<<dim3(64, 8), 256, 0, stream>>>(qb_, kb_, vT, ao);
        gemm_bt<64, true, false, false, true, false><<<g64, 256, 0, stream>>>(
            ao, wo_l, bo + l * D, nullptr, nullptr, xA,
            xB, nullptr, nullptr, Mrows, D, D);
        ln_kernel<<<Mrows / 4, 256, 0, stream>>>(xB, ln1g + l * D, ln1b + l * D, xb);
        gemm_bt<128, false, false, true, false, true><<<gff1, 256, 0, stream>>>(
            xb, w1_l, b1 + l * F, nullptr, nullptr, nullptr,
            ff1, nullptr, nullptr, Mrows, F, D);
        gemm_bt<64, true, false, false, true, false><<<g64, 256, 0, stream>>>(
            ff1, w2_l, b2 + l * D, nullptr, nullptr, xB,
            xA, nullptr, nullptr, Mrows, D, F);
        ln_kernel<<<Mrows / 4, 256, 0, stream>>>(xA, ln2g + l * D, ln2b + l * D, xb);
    }
    gemm_bt<64, true, false, false, false, false><<<g64, 256, 0, stream>>>(
        xb, woutB, bout, nullptr, nullptr, nullptr,
        d_out, nullptr, nullptr, Mrows, D, D);
}

// Round 7
// 644.617 us; speedup vs baseline: 1.6585x; 1.0288x over previous
//
#include <hip/hip_runtime.h>
#include <stdint.h>
#include <math.h>

typedef unsigned short u16;
typedef __bf16 bf16x8 __attribute__((ext_vector_type(8)));
typedef float f32x4 __attribute__((ext_vector_type(4)));
typedef short s16x8 __attribute__((ext_vector_type(8)));
union B8 { s16x8 s; bf16x8 b; };

// ---------- helpers ----------
__device__ __forceinline__ u16 f2bf(float f) {
    union { __bf16 h; u16 u; } r;
    r.h = (__bf16)f;
    return r.u;
}
__device__ __forceinline__ uint32_t pk2bf(float a, float b) {
    union { __bf16 h[2]; uint32_t u; } r;
    r.h[0] = (__bf16)a; r.h[1] = (__bf16)b;
    return r.u;
}

typedef const __attribute__((address_space(1))) uint32_t* gas_t;
typedef __attribute__((address_space(3))) uint32_t* las_t;
__device__ __forceinline__ void gld16(const void* g, void* l) {
    __builtin_amdgcn_global_load_lds((gas_t)g, (las_t)l, 16, 0, 0);
}

// host rotl (portable)
__host__ __forceinline__ uint32_t rotl32(uint32_t x, int d) {
    return (x << d) | (x >> (32 - d));
}
// device rotl via v_alignbit (single instruction)
__device__ __forceinline__ uint32_t rotl_d(uint32_t x, int d) {
    return __builtin_amdgcn_alignbit(x, x, (uint32_t)(32 - d));
}

// JAX threefry2x32 (20 rounds) — host version (key folding)
__host__ inline void tf2x32_h(uint32_t k0, uint32_t k1, uint32_t& x0, uint32_t& x1) {
    uint32_t k2 = k0 ^ k1 ^ 0x1BD11BDAu;
    x0 += k0; x1 += k1;
    x0 += x1; x1 = rotl32(x1, 13); x1 ^= x0;
    x0 += x1; x1 = rotl32(x1, 15); x1 ^= x0;
    x0 += x1; x1 = rotl32(x1, 26); x1 ^= x0;
    x0 += x1; x1 = rotl32(x1,  6); x1 ^= x0;
    x0 += k1; x1 += k2 + 1u;
    x0 += x1; x1 = rotl32(x1, 17); x1 ^= x0;
    x0 += x1; x1 = rotl32(x1, 29); x1 ^= x0;
    x0 += x1; x1 = rotl32(x1, 16); x1 ^= x0;
    x0 += x1; x1 = rotl32(x1, 24); x1 ^= x0;
    x0 += k2; x1 += k0 + 2u;
    x0 += x1; x1 = rotl32(x1, 13); x1 ^= x0;
    x0 += x1; x1 = rotl32(x1, 15); x1 ^= x0;
    x0 += x1; x1 = rotl32(x1, 26); x1 ^= x0;
    x0 += x1; x1 = rotl32(x1,  6); x1 ^= x0;
    x0 += k0; x1 += k1 + 3u;
    x0 += x1; x1 = rotl32(x1, 17); x1 ^= x0;
    x0 += x1; x1 = rotl32(x1, 29); x1 ^= x0;
    x0 += x1; x1 = rotl32(x1, 16); x1 ^= x0;
    x0 += x1; x1 = rotl32(x1, 24); x1 ^= x0;
    x0 += k1; x1 += k2 + 4u;
    x0 += x1; x1 = rotl32(x1, 13); x1 ^= x0;
    x0 += x1; x1 = rotl32(x1, 15); x1 ^= x0;
    x0 += x1; x1 = rotl32(x1, 26); x1 ^= x0;
    x0 += x1; x1 = rotl32(x1,  6); x1 ^= x0;
    x0 += k2; x1 += k0 + 5u;
}

// device version with alignbit rotates
__device__ __forceinline__ void tf2x32_d(uint32_t k0, uint32_t k1,
                                         uint32_t& x0, uint32_t& x1) {
    uint32_t k2 = k0 ^ k1 ^ 0x1BD11BDAu;
    x0 += k0; x1 += k1;
    x0 += x1; x1 = rotl_d(x1, 13); x1 ^= x0;
    x0 += x1; x1 = rotl_d(x1, 15); x1 ^= x0;
    x0 += x1; x1 = rotl_d(x1, 26); x1 ^= x0;
    x0 += x1; x1 = rotl_d(x1,  6); x1 ^= x0;
    x0 += k1; x1 += k2 + 1u;
    x0 += x1; x1 = rotl_d(x1, 17); x1 ^= x0;
    x0 += x1; x1 = rotl_d(x1, 29); x1 ^= x0;
    x0 += x1; x1 = rotl_d(x1, 16); x1 ^= x0;
    x0 += x1; x1 = rotl_d(x1, 24); x1 ^= x0;
    x0 += k2; x1 += k0 + 2u;
    x0 += x1; x1 = rotl_d(x1, 13); x1 ^= x0;
    x0 += x1; x1 = rotl_d(x1, 15); x1 ^= x0;
    x0 += x1; x1 = rotl_d(x1, 26); x1 ^= x0;
    x0 += x1; x1 = rotl_d(x1,  6); x1 ^= x0;
    x0 += k0; x1 += k1 + 3u;
    x0 += x1; x1 = rotl_d(x1, 17); x1 ^= x0;
    x0 += x1; x1 = rotl_d(x1, 29); x1 ^= x0;
    x0 += x1; x1 = rotl_d(x1, 16); x1 ^= x0;
    x0 += x1; x1 = rotl_d(x1, 24); x1 ^= x0;
    x0 += k1; x1 += k2 + 4u;
    x0 += x1; x1 = rotl_d(x1, 13); x1 ^= x0;
    x0 += x1; x1 = rotl_d(x1, 15); x1 ^= x0;
    x0 += x1; x1 = rotl_d(x1, 26); x1 ^= x0;
    x0 += x1; x1 = rotl_d(x1,  6); x1 ^= x0;
    x0 += k2; x1 += k0 + 5u;
}

// XLA ErfInv f32 (Giles polynomial); log1p(-x^2) -> fast v_log_f32 path
// (|error| in normal value ~1e-6, far below tolerance)
__device__ __forceinline__ float erfinv_f(float x) {
    float w = -__logf(fmaf(x, -x, 1.0f));
    float p;
    if (w < 5.0f) {
        w = w - 2.5f;
        p = 2.81022636e-08f;
        p = p * w + 3.43273939e-07f;
        p = p * w + -3.5233877e-06f;
        p = p * w + -4.39150654e-06f;
        p = p * w + 0.00021858087f;
        p = p * w + -0.00125372503f;
        p = p * w + -0.00417768164f;
        p = p * w + 0.246640727f;
        p = p * w + 1.50140941f;
    } else {
        w = sqrtf(w) - 3.0f;
        p = -0.000200214257f;
        p = p * w + 0.000100950558f;
        p = p * w + 0.00134934322f;
        p = p * w + -0.00367342844f;
        p = p * w + 0.00573950773f;
        p = p * w + -0.0076224613f;
        p = p * w + 0.00943887047f;
        p = p * w + 1.00167406f;
        p = p * w + 2.83297682f;
    }
    return p * x;
}

__device__ __forceinline__ float tf_normal(uint32_t k0, uint32_t k1, uint32_t idx) {
    uint32_t x0 = 0u, x1 = idx;
    tf2x32_d(k0, k1, x0, x1);
    uint32_t bits = x0 ^ x1;
    float f = __uint_as_float((bits >> 9) | 0x3f800000u) - 1.0f;
    float u = f * 2.0f - 0.99999994f;
    u = fmaxf(-0.99999994f, u);
    return 1.41421354f * erfinv_f(u);
}

// ---------- noise init: 4 elements/thread ----------
__global__ __launch_bounds__(256) void noise_kernel(
    float* __restrict__ x, u16* __restrict__ xb,
    uint32_t ka0, uint32_t ka1, float ca,
    uint32_t kb0, uint32_t kb1, float cb, int n4)
{
    int i = blockIdx.x * 256 + threadIdx.x;
    if (i >= n4) return;
    float4 vx;
    ushort4 vb;
    #pragma unroll
    for (int e = 0; e < 4; ++e) {
        uint32_t idx = (uint32_t)(i * 4 + e);
        float a = ca * tf_normal(ka0, ka1, idx)
                + cb * tf_normal(kb0, kb1, idx);
        (&vx.x)[e] = a;
        (&vb.x)[e] = f2bf(a);
    }
    ((float4*)x)[i] = vx;
    ((ushort4*)xb)[i] = vb;
}

// ---------- f32 -> bf16 convert ----------
__global__ __launch_bounds__(256) void cvt_bf16_kernel(
    const float* __restrict__ s, u16* __restrict__ d, int n4)
{
    int i = blockIdx.x * 256 + threadIdx.x;
    if (i >= n4) return;
    float4 v = ((const float4*)s)[i];
    uint2 o;
    o.x = pk2bf(v.x, v.y);
    o.y = pk2bf(v.z, v.w);
    ((uint2*)d)[i] = o;
}

// ---------- build combined QKV weight [L][1536][512] bf16 ----------
__global__ __launch_bounds__(256) void cvt_qkvw_kernel(
    const float* __restrict__ Wq, const float* __restrict__ Wk,
    const float* __restrict__ Wv, u16* __restrict__ dst, int n4)
{
    int i = blockIdx.x * 256 + threadIdx.x;
    if (i >= n4) return;
    int e = i * 4;
    int l = e / 786432;
    int rem = e - l * 786432;
    int sel = rem >> 18;
    int off = rem & 262143;
    const float* src = (sel == 0 ? Wq : sel == 1 ? Wk : Wv) + l * 262144 + off;
    float4 v = *(const float4*)src;
    uint2 o;
    o.x = pk2bf(v.x, v.y);
    o.y = pk2bf(v.z, v.w);
    *(uint2*)(dst + e) = o;
}

// ---------- GEMM (TN=128 shapes): 128x128 tile, 4 waves ----------
template<int TN, bool DBUF, bool QKV, bool RELU, bool RESID, bool BF16OUT>
__global__ __launch_bounds__(256) void gemm_bt(
    const u16* __restrict__ A, const u16* __restrict__ Bw,
    const float* __restrict__ bias0, const float* __restrict__ bias1,
    const float* __restrict__ bias2, const float* __restrict__ resid,
    void* __restrict__ out0, void* __restrict__ out1, void* __restrict__ out2,
    int M, int N, int K)
{
    constexpr int ACH = 16;
    constexpr int BCH = TN / 8;
    constexpr int CPW = (ACH + BCH) / 4;
    constexpr int NF = TN / 32;
    constexpr int NBUF = DBUF ? 2 : 1;
    constexpr int ASZ = 128 * 64;
    constexpr int BSZ = TN * 64;
    __shared__ __align__(16) u16 At[NBUF * ASZ];
    __shared__ __align__(16) u16 Bt[NBUF * BSZ];
    const int tid = threadIdx.x;
    const int l = tid & 63;
    const int w = tid >> 6;
    const int wr = w >> 1, wc = w & 1;

    int lid = blockIdx.y * gridDim.x + blockIdx.x;
    int nwg = gridDim.x * gridDim.y;
    int mb, nb;
    if ((nwg & 7) == 0) {
        int nlid = (lid & 7) * (nwg >> 3) + (lid >> 3);
        mb = nlid / gridDim.x;
        nb = nlid - mb * gridDim.x;
    } else { mb = blockIdx.y; nb = blockIdx.x; }

    const int lrow = l >> 3;
    const int lch  = (l & 7) ^ lrow;

    const u16* aTile = A  + (size_t)(mb * 128) * K + (size_t)lrow * K + lch * 8;
    const u16* bTile = Bw + (size_t)(nb * TN) * K + (size_t)lrow * K + lch * 8;

    f32x4 acc[4][NF] = {};

    auto stage = [&](int buf, int k0) {
        #pragma unroll
        for (int i = 0; i < CPW; ++i) {
            int c = w * CPW + i;
            if (c < ACH) gld16(aTile + (size_t)(c * 8) * K + k0, &At[buf * ASZ + c * 512]);
            else gld16(bTile + (size_t)((c - ACH) * 8) * K + k0, &Bt[buf * BSZ + (c - ACH) * 512]);
        }
    };
    auto compute = [&](int buf) {
        const u16* Ac = &At[buf * ASZ];
        const u16* Bc = &Bt[buf * BSZ];
        #pragma unroll
        for (int kc = 0; kc < 2; ++kc) {
            B8 af[4], bfr[NF];
            #pragma unroll
            for (int m = 0; m < 4; ++m) {
                int r = wr * 64 + m * 16 + (l & 15);
                int ch = kc * 4 + (l >> 4);
                af[m].s = *(const s16x8*)&Ac[r * 64 + ((ch ^ (r & 7)) * 8)];
            }
            #pragma unroll
            for (int n = 0; n < NF; ++n) {
                int r = wc * (TN / 2) + n * 16 + (l & 15);
                int ch = kc * 4 + (l >> 4);
                bfr[n].s = *(const s16x8*)&Bc[r * 64 + ((ch ^ (r & 7)) * 8)];
            }
            #pragma unroll
            for (int m = 0; m < 4; ++m)
                #pragma unroll
                for (int n = 0; n < NF; ++n)
                    acc[m][n] = __builtin_amdgcn_mfma_f32_16x16x32_bf16(
                        af[m].b, bfr[n].b, acc[m][n], 0, 0, 0);
        }
    };

    if constexpr (DBUF) {
        stage(0, 0);
        __syncthreads();
        int cur = 0;
        for (int k0 = 0; k0 < K; k0 += 64) {
            if (k0 + 64 < K) stage(cur ^ 1, k0 + 64);
            compute(cur);
            __syncthreads();
            cur ^= 1;
        }
    } else {
        for (int k0 = 0; k0 < K; k0 += 64) {
            stage(0, k0);
            __syncthreads();
            compute(0);
            __syncthreads();
        }
    }

    const float* biasp;
    void* outp;
    int colbase, Nout;
    float oscale = 1.0f;
    if constexpr (QKV) {
        int which = nb >> 2;
        colbase = (nb & 3) * 128 + wc * 64;
        if (which == 2) {
            float bcol[NF];
            #pragma unroll
            for (int n = 0; n < NF; ++n)
                bcol[n] = bias2[colbase + n * 16 + (l & 15)];
            u16* vT = (u16*)out2;
            #pragma unroll
            for (int m = 0; m < 4; ++m) {
                int row0 = mb * 128 + wr * 64 + m * 16 + (l >> 4) * 4;
                int bb = row0 >> 10, s0 = row0 & 1023;
                #pragma unroll
                for (int n = 0; n < NF; ++n) {
                    int col = colbase + n * 16 + (l & 15);
                    int hh = col >> 6, dd = col & 63;
                    uint2 o;
                    o.x = pk2bf(acc[m][n][0] + bcol[n], acc[m][n][1] + bcol[n]);
                    o.y = pk2bf(acc[m][n][2] + bcol[n], acc[m][n][3] + bcol[n]);
                    *(uint2*)&vT[((size_t)((bb * 8 + hh) * 64 + dd)) * 1024 + s0] = o;
                }
            }
            return;
        }
        biasp = which == 0 ? bias0 : bias1;
        outp  = which == 0 ? out0  : out1;
        if (which == 0) oscale = 0.125f;
        Nout = 512;
    } else {
        colbase = nb * TN + wc * (TN / 2);
        biasp = bias0;
        outp = out0;
        Nout = N;
    }

    float bcol[NF];
    #pragma unroll
    for (int n = 0; n < NF; ++n)
        bcol[n] = biasp[colbase + n * 16 + (l & 15)];

    #pragma unroll
    for (int m = 0; m < 4; ++m) {
        #pragma unroll
        for (int j = 0; j < 4; ++j) {
            int row = mb * 128 + wr * 64 + m * 16 + (l >> 4) * 4 + j;
            #pragma unroll
            for (int n = 0; n < NF; ++n) {
                int col = colbase + n * 16 + (l & 15);
                float v = acc[m][n][j] + bcol[n];
                if constexpr (QKV) v *= oscale;
                if constexpr (RESID) v += resid[(size_t)row * Nout + col];
                if constexpr (RELU)  v = fmaxf(v, 0.0f);
                if constexpr (BF16OUT) ((u16*)outp)[(size_t)row * Nout + col] = f2bf(v);
                else                   ((float*)outp)[(size_t)row * Nout + col] = v;
            }
        }
    }
}

// ---------- GEMM64: 128x64 tile, 8 waves (512 thr), dbuf, f32 out (+resid) ----
// Same traffic/LDS as 4-wave version but 16 waves/CU for latency hiding.
template<bool RESID>
__global__ __launch_bounds__(512) void gemm64(
    const u16* __restrict__ A, const u16* __restrict__ Bw,
    const float* __restrict__ bias, const float* __restrict__ resid,
    float* __restrict__ out, int N, int K)
{
    constexpr int ACH = 16, BCH = 8;
    constexpr int ASZ = 128 * 64, BSZ = 64 * 64;
    __shared__ __align__(16) u16 At[2 * ASZ];
    __shared__ __align__(16) u16 Bt[2 * BSZ];
    const int tid = threadIdx.x;
    const int l = tid & 63;
    const int w = tid >> 6;            // 0..7
    const int wr = w >> 1, wc = w & 1; // 4x2 wave grid, 32x32 per wave

    int lid = blockIdx.y * gridDim.x + blockIdx.x;
    int nwg = gridDim.x * gridDim.y;
    int nlid = (lid & 7) * (nwg >> 3) + (lid >> 3);
    int mb = nlid / gridDim.x;
    int nb = nlid - mb * gridDim.x;

    const int lrow = l >> 3;
    const int lch  = (l & 7) ^ lrow;

    const u16* aTile = A  + (size_t)(mb * 128) * K + (size_t)lrow * K + lch * 8;
    const u16* bTile = Bw + (size_t)(nb * 64) * K + (size_t)lrow * K + lch * 8;

    f32x4 acc[2][2] = {};

    auto stage = [&](int buf, int k0) {
        #pragma unroll
        for (int i = 0; i < 3; ++i) {
            int c = w * 3 + i;                 // 0..23
            if (c < ACH) gld16(aTile + (size_t)(c * 8) * K + k0, &At[buf * ASZ + c * 512]);
            else gld16(bTile + (size_t)((c - ACH) * 8) * K + k0, &Bt[buf * BSZ + (c - ACH) * 512]);
        }
    };
    auto compute = [&](int buf) {
        const u16* Ac = &At[buf * ASZ];
        const u16* Bc = &Bt[buf * BSZ];
        #pragma unroll
        for (int kc = 0; kc < 2; ++kc) {
            B8 af[2], bfr[2];
            #pragma unroll
            for (int m = 0; m < 2; ++m) {
                int r = wr * 32 + m * 16 + (l & 15);
                int ch = kc * 4 + (l >> 4);
                af[m].s = *(const s16x8*)&Ac[r * 64 + ((ch ^ (r & 7)) * 8)];
            }
            #pragma unroll
            for (int n = 0; n < 2; ++n) {
                int r = wc * 32 + n * 16 + (l & 15);
                int ch = kc * 4 + (l >> 4);
                bfr[n].s = *(const s16x8*)&Bc[r * 64 + ((ch ^ (r & 7)) * 8)];
            }
            #pragma unroll
            for (int m = 0; m < 2; ++m)
                #pragma unroll
                for (int n = 0; n < 2; ++n)
                    acc[m][n] = __builtin_amdgcn_mfma_f32_16x16x32_bf16(
                        af[m].b, bfr[n].b, acc[m][n], 0, 0, 0);
        }
    };

    stage(0, 0);
    __syncthreads();
    int cur = 0;
    for (int k0 = 0; k0 < K; k0 += 64) {
        if (k0 + 64 < K) stage(cur ^ 1, k0 + 64);
        compute(cur);
        __syncthreads();
        cur ^= 1;
    }

    float bcol[2];
    #pragma unroll
    for (int n = 0; n < 2; ++n)
        bcol[n] = bias[nb * 64 + wc * 32 + n * 16 + (l & 15)];

    #pragma unroll
    for (int m = 0; m < 2; ++m) {
        #pragma unroll
        for (int j = 0; j < 4; ++j) {
            int row = mb * 128 + wr * 32 + m * 16 + (l >> 4) * 4 + j;
            #pragma unroll
            for (int n = 0; n < 2; ++n) {
                int col = nb * 64 + wc * 32 + n * 16 + (l & 15);
                float v = acc[m][n][j] + bcol[n];
                if constexpr (RESID) v += resid[(size_t)row * N + col];
                out[(size_t)row * N + col] = v;
            }
        }
    }
}

// ---------- LayerNorm ----------
__global__ __launch_bounds__(256) void ln_kernel(
    float* __restrict__ x, const float* __restrict__ g, const float* __restrict__ b,
    u16* __restrict__ xb)
{
    int row = blockIdx.x * 4 + (threadIdx.x >> 6);
    int l = threadIdx.x & 63;
    float4* xr = (float4*)(x + row * 512);
    float4 v0 = xr[l];
    float4 v1 = xr[l + 64];
    float s = v0.x + v0.y + v0.z + v0.w + v1.x + v1.y + v1.z + v1.w;
    float q = v0.x * v0.x + v0.y * v0.y + v0.z * v0.z + v0.w * v0.w
            + v1.x * v1.x + v1.y * v1.y + v1.z * v1.z + v1.w * v1.w;
    #pragma unroll
    for (int m = 1; m < 64; m <<= 1) {
        s += __shfl_xor(s, m, 64);
        q += __shfl_xor(q, m, 64);
    }
    float mean = s * (1.0f / 512.0f);
    float var  = q * (1.0f / 512.0f) - mean * mean;
    float rstd = rsqrtf(var + 1e-5f);
    const float4* gv = (const float4*)g;
    const float4* bv = (const float4*)b;
    float4 g0 = gv[l], g1 = gv[l + 64], b0 = bv[l], b1 = bv[l + 64];
    float4 o0, o1;
    o0.x = (v0.x - mean) * rstd * g0.x + b0.x;
    o0.y = (v0.y - mean) * rstd * g0.y + b0.y;
    o0.z = (v0.z - mean) * rstd * g0.z + b0.z;
    o0.w = (v0.w - mean) * rstd * g0.w + b0.w;
    o1.x = (v1.x - mean) * rstd * g1.x + b1.x;
    o1.y = (v1.y - mean) * rstd * g1.y + b1.y;
    o1.z = (v1.z - mean) * rstd * g1.z + b1.z;
    o1.w = (v1.w - mean) * rstd * g1.w + b1.w;
    xr[l] = o0; xr[l + 64] = o1;
    uint2 h0, h1;
    h0.x = pk2bf(o0.x, o0.y); h0.y = pk2bf(o0.z, o0.w);
    h1.x = pk2bf(o1.x, o1.y); h1.y = pk2bf(o1.z, o1.w);
    ((uint2*)(xb + row * 512))[l] = h0;
    ((uint2*)(xb + row * 512))[l + 64] = h1;
}

// ---------- fused attention v5 ----------
__global__ __launch_bounds__(256) void attn_kernel(
    const u16* __restrict__ Q, const u16* __restrict__ Km,
    const u16* __restrict__ vT, u16* __restrict__ O)
{
    __shared__ __align__(16) u16 Kt[2][64 * 64];
    __shared__ __align__(16) u16 Vt[2][64 * 64];
    __shared__ __align__(16) char Pl[4][4096];
    const int tid = threadIdx.x;
    const int l = tid & 63;
    const int w = tid >> 6;
    const int g = l >> 4;
    const int q15 = l & 15;
    const int bh = blockIdx.x;
    const int qb = blockIdx.y;
    const int b = bh >> 3, h = bh & 7;
    const int rowQ0 = b * 1024 + qb * 128 + w * 32;
    const int colh = h * 64;
    char* pl = &Pl[w][0];

    const int srow = l >> 3;
    const u16* Kbase = Km + (size_t)(b * 1024) * 512 + colh;
    const u16* Vbase = vT + (size_t)bh * 64 * 1024;

    B8 qf[2][2];
    #pragma unroll
    for (int qt = 0; qt < 2; ++qt)
        #pragma unroll
        for (int kc = 0; kc < 2; ++kc)
            qf[qt][kc].s = *(const s16x8*)&Q[(size_t)(rowQ0 + qt * 16 + q15) * 512
                                            + colh + kc * 32 + g * 8];

    f32x4 oacc[4][2] = {};
    float mrun[2], lrun[2];
    mrun[0] = mrun[1] = -__builtin_huge_valf();
    lrun[0] = lrun[1] = 0.0f;

    auto stage = [&](int buf, int kt) {
        #pragma unroll
        for (int i = 0; i < 2; ++i) {
            int c = w * 2 + i;
            int r = c * 8 + srow;
            int cc = (l & 7) ^ (r & 7);
            gld16(Kbase + (size_t)(kt * 64 + r) * 512 + cc * 8, &Kt[buf][c * 512]);
            gld16(Vbase + (size_t)r * 1024 + kt * 64 + cc * 8, &Vt[buf][c * 512]);
        }
    };

    stage(0, 0);
    __syncthreads();
    int cur = 0;

    for (int kt = 0; kt < 16; ++kt) {
        if (kt < 15) stage(cur ^ 1, kt + 1);
        const u16* KtL = &Kt[cur][0];
        const u16* VtL = &Vt[cur][0];

        f32x4 st[2][4];
        #pragma unroll
        for (int mt = 0; mt < 4; ++mt) {
            int r = mt * 16 + q15;
            B8 kf0, kf1;
            kf0.s = *(const s16x8*)&KtL[r * 64 + ((g ^ (r & 7)) * 8)];
            kf1.s = *(const s16x8*)&KtL[r * 64 + (((4 + g) ^ (r & 7)) * 8)];
            #pragma unroll
            for (int qt = 0; qt < 2; ++qt) {
                f32x4 t = {0.f, 0.f, 0.f, 0.f};
                t = __builtin_amdgcn_mfma_f32_16x16x32_bf16(kf0.b, qf[qt][0].b, t, 0, 0, 0);
                t = __builtin_amdgcn_mfma_f32_16x16x32_bf16(kf1.b, qf[qt][1].b, t, 0, 0, 0);
                st[qt][mt] = t;
            }
        }

        #pragma unroll
        for (int qt = 0; qt < 2; ++qt) {
            float vm = st[qt][0][0];
            #pragma unroll
            for (int mt = 0; mt < 4; ++mt)
                #pragma unroll
                for (int jj = 0; jj < 4; ++jj)
                    vm = fmaxf(vm, st[qt][mt][jj]);
            vm = fmaxf(vm, __shfl_xor(vm, 16, 64));
            vm = fmaxf(vm, __shfl_xor(vm, 32, 64));

            if (__any(vm > mrun[qt] + 8.0f)) {
                float mn = fmaxf(mrun[qt], vm);
                float alpha = __expf(mrun[qt] - mn);
                mrun[qt] = mn;
                lrun[qt] *= alpha;
                #pragma unroll
                for (int dt = 0; dt < 4; ++dt)
                    #pragma unroll
                    for (int jj = 0; jj < 4; ++jj)
                        oacc[dt][qt][jj] *= alpha;
            }

            int qrow = qt * 16 + q15;
            int rbase = qrow * 128;
            int sw = (qrow & 7) << 4;
            float rs = 0.0f;
            #pragma unroll
            for (int mt = 0; mt < 4; ++mt) {
                float e0 = __expf(st[qt][mt][0] - mrun[qt]);
                float e1 = __expf(st[qt][mt][1] - mrun[qt]);
                float e2 = __expf(st[qt][mt][2] - mrun[qt]);
                float e3 = __expf(st[qt][mt][3] - mrun[qt]);
                rs += (e0 + e1) + (e2 + e3);
                uint2 pk;
                pk.x = pk2bf(e0, e1);
                pk.y = pk2bf(e2, e3);
                *(uint2*)(pl + rbase + ((mt * 32 + g * 8) ^ sw)) = pk;
            }
            rs += __shfl_xor(rs, 16, 64);
            rs += __shfl_xor(rs, 32, 64);
            lrun[qt] += rs;
        }

        B8 pf[2][2];
        #pragma unroll
        for (int qt = 0; qt < 2; ++qt) {
            int qrow = qt * 16 + q15;
            int sw = (qrow & 7) << 4;
            pf[qt][0].s = *(const s16x8*)(pl + qrow * 128 + ((g * 16) ^ sw));
            pf[qt][1].s = *(const s16x8*)(pl + qrow * 128 + (((4 + g) * 16) ^ sw));
        }

        #pragma unroll
        for (int dt = 0; dt < 4; ++dt) {
            int r = dt * 16 + q15;
            B8 vf0, vf1;
            vf0.s = *(const s16x8*)&VtL[r * 64 + ((g ^ (r & 7)) * 8)];
            vf1.s = *(const s16x8*)&VtL[r * 64 + (((4 + g) ^ (r & 7)) * 8)];
            #pragma unroll
            for (int qt = 0; qt < 2; ++qt) {
                oacc[dt][qt] = __builtin_amdgcn_mfma_f32_16x16x32_bf16(
                    vf0.b, pf[qt][0].b, oacc[dt][qt], 0, 0, 0);
                oacc[dt][qt] = __builtin_amdgcn_mfma_f32_16x16x32_bf16(
                    vf1.b, pf[qt][1].b, oacc[dt][qt], 0, 0, 0);
            }
        }
        __syncthreads();
        cur ^= 1;
    }

    #pragma unroll
    for (int qt = 0; qt < 2; ++qt) {
        float inv = 1.0f / lrun[qt];
        int row = rowQ0 + qt * 16 + q15;
        #pragma unroll
        for (int dt = 0; dt < 4; ++dt) {
            uint2 o;
            o.x = pk2bf(oacc[dt][qt][0] * inv, oacc[dt][qt][1] * inv);
            o.y = pk2bf(oacc[dt][qt][2] * inv, oacc[dt][qt][3] * inv);
            *(uint2*)&O[(size_t)row * 512 + colh + dt * 16 + g * 4] = o;
        }
    }
}

// ---------- launcher ----------
extern "C" void kernel_launch(void* const* d_in, const int* in_sizes, int n_in,
                              void* d_out, int out_size, void* d_ws, size_t ws_size,
                              hipStream_t stream)
{
    const int D = 512, F = 2048, Lc = 4;
    const int Mrows = 8 * 1024;

    const float* Wq   = (const float*)d_in[1];
    const float* Wk   = (const float*)d_in[2];
    const float* Wv   = (const float*)d_in[3];
    const float* bq   = (const float*)d_in[4];
    const float* bk   = (const float*)d_in[5];
    const float* bv   = (const float*)d_in[6];
    const float* Wo   = (const float*)d_in[7];
    const float* bo   = (const float*)d_in[8];
    const float* ln1g = (const float*)d_in[9];
    const float* ln1b = (const float*)d_in[10];
    const float* ln2g = (const float*)d_in[11];
    const float* ln2b = (const float*)d_in[12];
    const float* W1   = (const float*)d_in[13];
    const float* b1   = (const float*)d_in[14];
    const float* W2   = (const float*)d_in[15];
    const float* b2   = (const float*)d_in[16];
    const float* Wout = (const float*)d_in[17];
    const float* bout = (const float*)d_in[18];

    char* p = (char*)d_ws;
    auto alloc = [&](size_t bytes) {
        char* r = p;
        p += (bytes + 255) & ~(size_t)255;
        return r;
    };
    float* xA = (float*)alloc((size_t)Mrows * D * 4);
    float* xB = (float*)alloc((size_t)Mrows * D * 4);
    u16* xb   = (u16*)alloc((size_t)Mrows * D * 2);
    char* pool = alloc((size_t)Mrows * F * 2);
    u16* qb_ = (u16*)pool;
    u16* kb_ = (u16*)(pool + (size_t)Mrows * D * 2);
    u16* vT  = (u16*)(pool + (size_t)Mrows * D * 2 * 2);   // [64 bh][64 d][1024 s]
    u16* ao  = (u16*)(pool + (size_t)Mrows * D * 2 * 3);
    u16* ff1 = (u16*)pool;
    u16* wqkvB = (u16*)alloc((size_t)Lc * 3 * D * D * 2);
    u16* woB   = (u16*)alloc((size_t)Lc * D * D * 2);
    u16* w1B   = (u16*)alloc((size_t)Lc * F * D * 2);
    u16* w2B   = (u16*)alloc((size_t)Lc * D * F * 2);
    u16* woutB = (u16*)alloc((size_t)D * D * 2);

    auto cvt = [&](const float* src, u16* dst, size_t n) {
        int n4 = (int)(n / 4);
        cvt_bf16_kernel<<<(n4 + 255) / 256, 256, 0, stream>>>(src, dst, n4);
    };
    {
        int n4 = Lc * 3 * D * D / 4;
        cvt_qkvw_kernel<<<(n4 + 255) / 256, 256, 0, stream>>>(Wq, Wk, Wv, wqkvB, n4);
    }
    cvt(Wo, woB, (size_t)Lc * D * D);
    cvt(W1, w1B, (size_t)Lc * F * D);
    cvt(W2, w2B, (size_t)Lc * D * F);
    cvt(Wout, woutB, (size_t)D * D);

    // DDIM noise coefficients
    float ac[1000];
    {
        float start = 1e-4f, stop = 0.02f;
        float delta = (stop - start) / 999.0f;
        float prod = 1.0f;
        for (int i = 0; i < 1000; ++i) {
            float beta = start + (float)i * delta;
            prod *= (1.0f - beta);
            ac[i] = prod;
        }
    }
    int ts[2] = {999, 998};
    double cs[2];
    double tail = 1.0;
    for (int idx = 0; idx < 2; ++idx) {
        int t = ts[idx];
        cs[idx] = sqrt(1.0 - (double)ac[t]) * tail;
        tail *= sqrt((double)ac[t]);
    }
    uint32_t kk[2][2];
    for (int idx = 0; idx < 2; ++idx) {
        uint32_t x0 = 0u, x1 = (uint32_t)ts[idx];
        tf2x32_h(0u, 42u, x0, x1);
        kk[idx][0] = x0; kk[idx][1] = x1;
    }
    int n4tot = Mrows * D / 4;
    noise_kernel<<<(n4tot + 255) / 256, 256, 0, stream>>>(
        xA, xb,
        kk[0][0], kk[0][1], (float)cs[0],
        kk[1][0], kk[1][1], (float)cs[1], n4tot);

    dim3 gqkv(3 * D / 128, Mrows / 128);   // (12, 64) = 768
    dim3 g64(D / 64, Mrows / 128);         // (8, 64) = 512
    dim3 gff1(F / 128, Mrows / 128);       // (16, 64) = 1024

    for (int l = 0; l < Lc; ++l) {
        const u16* wqkv_l = wqkvB + (size_t)l * 3 * D * D;
        const u16* wo_l = woB + (size_t)l * D * D;
        const u16* w1_l = w1B + (size_t)l * F * D;
        const u16* w2_l = w2B + (size_t)l * D * F;

        gemm_bt<128, false, true, false, false, true><<<gqkv, 256, 0, stream>>>(
            xb, wqkv_l, bq + l * D, bk + l * D, bv + l * D, nullptr,
            qb_, kb_, vT, Mrows, 3 * D, D);
        attn_kernel<<<dim3(64, 8), 256, 0, stream>>>(qb_, kb_, vT, ao);
        gemm64<true><<<g64, 512, 0, stream>>>(
            ao, wo_l, bo + l * D, xA, xB, D, D);
        ln_kernel<<<Mrows / 4, 256, 0, stream>>>(xB, ln1g + l * D, ln1b + l * D, xb);
        gemm_bt<128, false, false, true, false, true><<<gff1, 256, 0, stream>>>(
            xb, w1_l, b1 + l * F, nullptr, nullptr, nullptr,
            ff1, nullptr, nullptr, Mrows, F, D);
        gemm64<true><<<g64, 512, 0, stream>>>(
            ff1, w2_l, b2 + l * D, xB, xA, D, F);
        ln_kernel<<<Mrows / 4, 256, 0, stream>>>(xA, ln2g + l * D, ln2b + l * D, xb);
    }
    gemm64<false><<<g64, 512, 0, stream>>>(
        xb, woutB, bout, nullptr, (float*)d_out, D, D);
}

// Round 9
// 616.079 us; speedup vs baseline: 1.7353x; 1.0463x over previous
//
#include <hip/hip_runtime.h>
#include <stdint.h>
#include <math.h>

typedef unsigned short u16;
typedef __bf16 bf16x8 __attribute__((ext_vector_type(8)));
typedef float f32x4 __attribute__((ext_vector_type(4)));
typedef short s16x8 __attribute__((ext_vector_type(8)));
union B8 { s16x8 s; bf16x8 b; };

// ---------- helpers ----------
__device__ __forceinline__ u16 f2bf(float f) {
    union { __bf16 h; u16 u; } r;
    r.h = (__bf16)f;
    return r.u;
}
__device__ __forceinline__ uint32_t pk2bf(float a, float b) {
    union { __bf16 h[2]; uint32_t u; } r;
    r.h[0] = (__bf16)a; r.h[1] = (__bf16)b;
    return r.u;
}
__device__ __forceinline__ float fexp2(float x) {
    return __builtin_amdgcn_exp2f(x);   // raw v_exp_f32
}

typedef const __attribute__((address_space(1))) uint32_t* gas_t;
typedef __attribute__((address_space(3))) uint32_t* las_t;
__device__ __forceinline__ void gld16(const void* g, void* l) {
    __builtin_amdgcn_global_load_lds((gas_t)g, (las_t)l, 16, 0, 0);
}

// host rotl (portable)
__host__ __forceinline__ uint32_t rotl32(uint32_t x, int d) {
    return (x << d) | (x >> (32 - d));
}
// device rotl via v_alignbit (single instruction)
__device__ __forceinline__ uint32_t rotl_d(uint32_t x, int d) {
    return __builtin_amdgcn_alignbit(x, x, (uint32_t)(32 - d));
}

// JAX threefry2x32 (20 rounds) — host version (key folding)
__host__ inline void tf2x32_h(uint32_t k0, uint32_t k1, uint32_t& x0, uint32_t& x1) {
    uint32_t k2 = k0 ^ k1 ^ 0x1BD11BDAu;
    x0 += k0; x1 += k1;
    x0 += x1; x1 = rotl32(x1, 13); x1 ^= x0;
    x0 += x1; x1 = rotl32(x1, 15); x1 ^= x0;
    x0 += x1; x1 = rotl32(x1, 26); x1 ^= x0;
    x0 += x1; x1 = rotl32(x1,  6); x1 ^= x0;
    x0 += k1; x1 += k2 + 1u;
    x0 += x1; x1 = rotl32(x1, 17); x1 ^= x0;
    x0 += x1; x1 = rotl32(x1, 29); x1 ^= x0;
    x0 += x1; x1 = rotl32(x1, 16); x1 ^= x0;
    x0 += x1; x1 = rotl32(x1, 24); x1 ^= x0;
    x0 += k2; x1 += k0 + 2u;
    x0 += x1; x1 = rotl32(x1, 13); x1 ^= x0;
    x0 += x1; x1 = rotl32(x1, 15); x1 ^= x0;
    x0 += x1; x1 = rotl32(x1, 26); x1 ^= x0;
    x0 += x1; x1 = rotl32(x1,  6); x1 ^= x0;
    x0 += k0; x1 += k1 + 3u;
    x0 += x1; x1 = rotl32(x1, 17); x1 ^= x0;
    x0 += x1; x1 = rotl32(x1, 29); x1 ^= x0;
    x0 += x1; x1 = rotl32(x1, 16); x1 ^= x0;
    x0 += x1; x1 = rotl32(x1, 24); x1 ^= x0;
    x0 += k1; x1 += k2 + 4u;
    x0 += x1; x1 = rotl32(x1, 13); x1 ^= x0;
    x0 += x1; x1 = rotl32(x1, 15); x1 ^= x0;
    x0 += x1; x1 = rotl32(x1, 26); x1 ^= x0;
    x0 += x1; x1 = rotl32(x1,  6); x1 ^= x0;
    x0 += k2; x1 += k0 + 5u;
}

// device version with alignbit rotates
__device__ __forceinline__ void tf2x32_d(uint32_t k0, uint32_t k1,
                                         uint32_t& x0, uint32_t& x1) {
    uint32_t k2 = k0 ^ k1 ^ 0x1BD11BDAu;
    x0 += k0; x1 += k1;
    x0 += x1; x1 = rotl_d(x1, 13); x1 ^= x0;
    x0 += x1; x1 = rotl_d(x1, 15); x1 ^= x0;
    x0 += x1; x1 = rotl_d(x1, 26); x1 ^= x0;
    x0 += x1; x1 = rotl_d(x1,  6); x1 ^= x0;
    x0 += k1; x1 += k2 + 1u;
    x0 += x1; x1 = rotl_d(x1, 17); x1 ^= x0;
    x0 += x1; x1 = rotl_d(x1, 29); x1 ^= x0;
    x0 += x1; x1 = rotl_d(x1, 16); x1 ^= x0;
    x0 += x1; x1 = rotl_d(x1, 24); x1 ^= x0;
    x0 += k2; x1 += k0 + 2u;
    x0 += x1; x1 = rotl_d(x1, 13); x1 ^= x0;
    x0 += x1; x1 = rotl_d(x1, 15); x1 ^= x0;
    x0 += x1; x1 = rotl_d(x1, 26); x1 ^= x0;
    x0 += x1; x1 = rotl_d(x1,  6); x1 ^= x0;
    x0 += k0; x1 += k1 + 3u;
    x0 += x1; x1 = rotl_d(x1, 17); x1 ^= x0;
    x0 += x1; x1 = rotl_d(x1, 29); x1 ^= x0;
    x0 += x1; x1 = rotl_d(x1, 16); x1 ^= x0;
    x0 += x1; x1 = rotl_d(x1, 24); x1 ^= x0;
    x0 += k1; x1 += k2 + 4u;
    x0 += x1; x1 = rotl_d(x1, 13); x1 ^= x0;
    x0 += x1; x1 = rotl_d(x1, 15); x1 ^= x0;
    x0 += x1; x1 = rotl_d(x1, 26); x1 ^= x0;
    x0 += x1; x1 = rotl_d(x1,  6); x1 ^= x0;
    x0 += k2; x1 += k0 + 5u;
}

// XLA ErfInv f32 (Giles polynomial); log1p(-x^2) -> fast v_log_f32 path
__device__ __forceinline__ float erfinv_f(float x) {
    float w = -__logf(fmaf(x, -x, 1.0f));
    float p;
    if (w < 5.0f) {
        w = w - 2.5f;
        p = 2.81022636e-08f;
        p = p * w + 3.43273939e-07f;
        p = p * w + -3.5233877e-06f;
        p = p * w + -4.39150654e-06f;
        p = p * w + 0.00021858087f;
        p = p * w + -0.00125372503f;
        p = p * w + -0.00417768164f;
        p = p * w + 0.246640727f;
        p = p * w + 1.50140941f;
    } else {
        w = sqrtf(w) - 3.0f;
        p = -0.000200214257f;
        p = p * w + 0.000100950558f;
        p = p * w + 0.00134934322f;
        p = p * w + -0.00367342844f;
        p = p * w + 0.00573950773f;
        p = p * w + -0.0076224613f;
        p = p * w + 0.00943887047f;
        p = p * w + 1.00167406f;
        p = p * w + 2.83297682f;
    }
    return p * x;
}

__device__ __forceinline__ float tf_normal(uint32_t k0, uint32_t k1, uint32_t idx) {
    uint32_t x0 = 0u, x1 = idx;
    tf2x32_d(k0, k1, x0, x1);
    uint32_t bits = x0 ^ x1;
    float f = __uint_as_float((bits >> 9) | 0x3f800000u) - 1.0f;
    float u = f * 2.0f - 0.99999994f;
    u = fmaxf(-0.99999994f, u);
    return 1.41421354f * erfinv_f(u);
}

// ---------- noise init: 4 elements/thread ----------
__global__ __launch_bounds__(256) void noise_kernel(
    float* __restrict__ x, u16* __restrict__ xb,
    uint32_t ka0, uint32_t ka1, float ca,
    uint32_t kb0, uint32_t kb1, float cb, int n4)
{
    int i = blockIdx.x * 256 + threadIdx.x;
    if (i >= n4) return;
    float4 vx;
    ushort4 vb;
    #pragma unroll
    for (int e = 0; e < 4; ++e) {
        uint32_t idx = (uint32_t)(i * 4 + e);
        float a = ca * tf_normal(ka0, ka1, idx)
                + cb * tf_normal(kb0, kb1, idx);
        (&vx.x)[e] = a;
        (&vb.x)[e] = f2bf(a);
    }
    ((float4*)x)[i] = vx;
    ((ushort4*)xb)[i] = vb;
}

// ---------- f32 -> bf16 convert ----------
__global__ __launch_bounds__(256) void cvt_bf16_kernel(
    const float* __restrict__ s, u16* __restrict__ d, int n4)
{
    int i = blockIdx.x * 256 + threadIdx.x;
    if (i >= n4) return;
    float4 v = ((const float4*)s)[i];
    uint2 o;
    o.x = pk2bf(v.x, v.y);
    o.y = pk2bf(v.z, v.w);
    ((uint2*)d)[i] = o;
}

// ---------- build combined QKV weight [L][1536][512] bf16 ----------
__global__ __launch_bounds__(256) void cvt_qkvw_kernel(
    const float* __restrict__ Wq, const float* __restrict__ Wk,
    const float* __restrict__ Wv, u16* __restrict__ dst, int n4)
{
    int i = blockIdx.x * 256 + threadIdx.x;
    if (i >= n4) return;
    int e = i * 4;
    int l = e / 786432;
    int rem = e - l * 786432;
    int sel = rem >> 18;
    int off = rem & 262143;
    const float* src = (sel == 0 ? Wq : sel == 1 ? Wk : Wv) + l * 262144 + off;
    float4 v = *(const float4*)src;
    uint2 o;
    o.x = pk2bf(v.x, v.y);
    o.y = pk2bf(v.z, v.w);
    *(uint2*)(dst + e) = o;
}

// ---------- GEMM (TN=128 shapes): 128x128 tile, 4 waves ----------
template<int TN, bool DBUF, bool QKV, bool RELU, bool RESID, bool BF16OUT>
__global__ __launch_bounds__(256) void gemm_bt(
    const u16* __restrict__ A, const u16* __restrict__ Bw,
    const float* __restrict__ bias0, const float* __restrict__ bias1,
    const float* __restrict__ bias2, const float* __restrict__ resid,
    void* __restrict__ out0, void* __restrict__ out1, void* __restrict__ out2,
    int M, int N, int K)
{
    constexpr int ACH = 16;
    constexpr int BCH = TN / 8;
    constexpr int CPW = (ACH + BCH) / 4;
    constexpr int NF = TN / 32;
    constexpr int NBUF = DBUF ? 2 : 1;
    constexpr int ASZ = 128 * 64;
    constexpr int BSZ = TN * 64;
    __shared__ __align__(16) u16 At[NBUF * ASZ];
    __shared__ __align__(16) u16 Bt[NBUF * BSZ];
    const int tid = threadIdx.x;
    const int l = tid & 63;
    const int w = tid >> 6;
    const int wr = w >> 1, wc = w & 1;

    int lid = blockIdx.y * gridDim.x + blockIdx.x;
    int nwg = gridDim.x * gridDim.y;
    int mb, nb;
    if ((nwg & 7) == 0) {
        int nlid = (lid & 7) * (nwg >> 3) + (lid >> 3);
        mb = nlid / gridDim.x;
        nb = nlid - mb * gridDim.x;
    } else { mb = blockIdx.y; nb = blockIdx.x; }

    const int lrow = l >> 3;
    const int lch  = (l & 7) ^ lrow;

    const u16* aTile = A  + (size_t)(mb * 128) * K + (size_t)lrow * K + lch * 8;
    const u16* bTile = Bw + (size_t)(nb * TN) * K + (size_t)lrow * K + lch * 8;

    f32x4 acc[4][NF] = {};

    auto stage = [&](int buf, int k0) {
        #pragma unroll
        for (int i = 0; i < CPW; ++i) {
            int c = w * CPW + i;
            if (c < ACH) gld16(aTile + (size_t)(c * 8) * K + k0, &At[buf * ASZ + c * 512]);
            else gld16(bTile + (size_t)((c - ACH) * 8) * K + k0, &Bt[buf * BSZ + (c - ACH) * 512]);
        }
    };
    auto compute = [&](int buf) {
        const u16* Ac = &At[buf * ASZ];
        const u16* Bc = &Bt[buf * BSZ];
        #pragma unroll
        for (int kc = 0; kc < 2; ++kc) {
            B8 af[4], bfr[NF];
            #pragma unroll
            for (int m = 0; m < 4; ++m) {
                int r = wr * 64 + m * 16 + (l & 15);
                int ch = kc * 4 + (l >> 4);
                af[m].s = *(const s16x8*)&Ac[r * 64 + ((ch ^ (r & 7)) * 8)];
            }
            #pragma unroll
            for (int n = 0; n < NF; ++n) {
                int r = wc * (TN / 2) + n * 16 + (l & 15);
                int ch = kc * 4 + (l >> 4);
                bfr[n].s = *(const s16x8*)&Bc[r * 64 + ((ch ^ (r & 7)) * 8)];
            }
            #pragma unroll
            for (int m = 0; m < 4; ++m)
                #pragma unroll
                for (int n = 0; n < NF; ++n)
                    acc[m][n] = __builtin_amdgcn_mfma_f32_16x16x32_bf16(
                        af[m].b, bfr[n].b, acc[m][n], 0, 0, 0);
        }
    };

    if constexpr (DBUF) {
        stage(0, 0);
        __syncthreads();
        int cur = 0;
        for (int k0 = 0; k0 < K; k0 += 64) {
            if (k0 + 64 < K) stage(cur ^ 1, k0 + 64);
            compute(cur);
            __syncthreads();
            cur ^= 1;
        }
    } else {
        for (int k0 = 0; k0 < K; k0 += 64) {
            stage(0, k0);
            __syncthreads();
            compute(0);
            __syncthreads();
        }
    }

    const float* biasp;
    void* outp;
    int colbase, Nout;
    float oscale = 1.0f;
    if constexpr (QKV) {
        int which = nb >> 2;
        colbase = (nb & 3) * 128 + wc * 64;
        if (which == 2) {
            float bcol[NF];
            #pragma unroll
            for (int n = 0; n < NF; ++n)
                bcol[n] = bias2[colbase + n * 16 + (l & 15)];
            u16* vT = (u16*)out2;
            #pragma unroll
            for (int m = 0; m < 4; ++m) {
                int row0 = mb * 128 + wr * 64 + m * 16 + (l >> 4) * 4;
                int bb = row0 >> 10, s0 = row0 & 1023;
                #pragma unroll
                for (int n = 0; n < NF; ++n) {
                    int col = colbase + n * 16 + (l & 15);
                    int hh = col >> 6, dd = col & 63;
                    uint2 o;
                    o.x = pk2bf(acc[m][n][0] + bcol[n], acc[m][n][1] + bcol[n]);
                    o.y = pk2bf(acc[m][n][2] + bcol[n], acc[m][n][3] + bcol[n]);
                    *(uint2*)&vT[((size_t)((bb * 8 + hh) * 64 + dd)) * 1024 + s0] = o;
                }
            }
            return;
        }
        biasp = which == 0 ? bias0 : bias1;
        outp  = which == 0 ? out0  : out1;
        if (which == 0) oscale = 0.18033688f;   // 0.125 * log2(e): exp2 softmax
        Nout = 512;
    } else {
        colbase = nb * TN + wc * (TN / 2);
        biasp = bias0;
        outp = out0;
        Nout = N;
    }

    float bcol[NF];
    #pragma unroll
    for (int n = 0; n < NF; ++n)
        bcol[n] = biasp[colbase + n * 16 + (l & 15)];

    #pragma unroll
    for (int m = 0; m < 4; ++m) {
        #pragma unroll
        for (int j = 0; j < 4; ++j) {
            int row = mb * 128 + wr * 64 + m * 16 + (l >> 4) * 4 + j;
            #pragma unroll
            for (int n = 0; n < NF; ++n) {
                int col = colbase + n * 16 + (l & 15);
                float v = acc[m][n][j] + bcol[n];
                if constexpr (QKV) v *= oscale;
                if constexpr (RESID) v += resid[(size_t)row * Nout + col];
                if constexpr (RELU)  v = fmaxf(v, 0.0f);
                if constexpr (BF16OUT) ((u16*)outp)[(size_t)row * Nout + col] = f2bf(v);
                else                   ((float*)outp)[(size_t)row * Nout + col] = v;
            }
        }
    }
}

// ---------- GEMM64: 128x64 tile, 8 waves (512 thr), dbuf, f32 out (+resid) ----
template<bool RESID>
__global__ __launch_bounds__(512) void gemm64(
    const u16* __restrict__ A, const u16* __restrict__ Bw,
    const float* __restrict__ bias, const float* __restrict__ resid,
    float* __restrict__ out, int N, int K)
{
    constexpr int ACH = 16;
    constexpr int ASZ = 128 * 64, BSZ = 64 * 64;
    __shared__ __align__(16) u16 At[2 * ASZ];
    __shared__ __align__(16) u16 Bt[2 * BSZ];
    const int tid = threadIdx.x;
    const int l = tid & 63;
    const int w = tid >> 6;
    const int wr = w >> 1, wc = w & 1;

    int lid = blockIdx.y * gridDim.x + blockIdx.x;
    int nwg = gridDim.x * gridDim.y;
    int nlid = (lid & 7) * (nwg >> 3) + (lid >> 3);
    int mb = nlid / gridDim.x;
    int nb = nlid - mb * gridDim.x;

    const int lrow = l >> 3;
    const int lch  = (l & 7) ^ lrow;

    const u16* aTile = A  + (size_t)(mb * 128) * K + (size_t)lrow * K + lch * 8;
    const u16* bTile = Bw + (size_t)(nb * 64) * K + (size_t)lrow * K + lch * 8;

    f32x4 acc[2][2] = {};

    auto stage = [&](int buf, int k0) {
        #pragma unroll
        for (int i = 0; i < 3; ++i) {
            int c = w * 3 + i;
            if (c < ACH) gld16(aTile + (size_t)(c * 8) * K + k0, &At[buf * ASZ + c * 512]);
            else gld16(bTile + (size_t)((c - ACH) * 8) * K + k0, &Bt[buf * BSZ + (c - ACH) * 512]);
        }
    };
    auto compute = [&](int buf) {
        const u16* Ac = &At[buf * ASZ];
        const u16* Bc = &Bt[buf * BSZ];
        #pragma unroll
        for (int kc = 0; kc < 2; ++kc) {
            B8 af[2], bfr[2];
            #pragma unroll
            for (int m = 0; m < 2; ++m) {
                int r = wr * 32 + m * 16 + (l & 15);
                int ch = kc * 4 + (l >> 4);
                af[m].s = *(const s16x8*)&Ac[r * 64 + ((ch ^ (r & 7)) * 8)];
            }
            #pragma unroll
            for (int n = 0; n < 2; ++n) {
                int r = wc * 32 + n * 16 + (l & 15);
                int ch = kc * 4 + (l >> 4);
                bfr[n].s = *(const s16x8*)&Bc[r * 64 + ((ch ^ (r & 7)) * 8)];
            }
            #pragma unroll
            for (int m = 0; m < 2; ++m)
                #pragma unroll
                for (int n = 0; n < 2; ++n)
                    acc[m][n] = __builtin_amdgcn_mfma_f32_16x16x32_bf16(
                        af[m].b, bfr[n].b, acc[m][n], 0, 0, 0);
        }
    };

    stage(0, 0);
    __syncthreads();
    int cur = 0;
    for (int k0 = 0; k0 < K; k0 += 64) {
        if (k0 + 64 < K) stage(cur ^ 1, k0 + 64);
        compute(cur);
        __syncthreads();
        cur ^= 1;
    }

    float bcol[2];
    #pragma unroll
    for (int n = 0; n < 2; ++n)
        bcol[n] = bias[nb * 64 + wc * 32 + n * 16 + (l & 15)];

    #pragma unroll
    for (int m = 0; m < 2; ++m) {
        #pragma unroll
        for (int j = 0; j < 4; ++j) {
            int row = mb * 128 + wr * 32 + m * 16 + (l >> 4) * 4 + j;
            #pragma unroll
            for (int n = 0; n < 2; ++n) {
                int col = nb * 64 + wc * 32 + n * 16 + (l & 15);
                float v = acc[m][n][j] + bcol[n];
                if constexpr (RESID) v += resid[(size_t)row * N + col];
                out[(size_t)row * N + col] = v;
            }
        }
    }
}

// ---------- LayerNorm ----------
__global__ __launch_bounds__(256) void ln_kernel(
    float* __restrict__ x, const float* __restrict__ g, const float* __restrict__ b,
    u16* __restrict__ xb)
{
    int row = blockIdx.x * 4 + (threadIdx.x >> 6);
    int l = threadIdx.x & 63;
    float4* xr = (float4*)(x + row * 512);
    float4 v0 = xr[l];
    float4 v1 = xr[l + 64];
    float s = v0.x + v0.y + v0.z + v0.w + v1.x + v1.y + v1.z + v1.w;
    float q = v0.x * v0.x + v0.y * v0.y + v0.z * v0.z + v0.w * v0.w
            + v1.x * v1.x + v1.y * v1.y + v1.z * v1.z + v1.w * v1.w;
    #pragma unroll
    for (int m = 1; m < 64; m <<= 1) {
        s += __shfl_xor(s, m, 64);
        q += __shfl_xor(q, m, 64);
    }
    float mean = s * (1.0f / 512.0f);
    float var  = q * (1.0f / 512.0f) - mean * mean;
    float rstd = rsqrtf(var + 1e-5f);
    const float4* gv = (const float4*)g;
    const float4* bv = (const float4*)b;
    float4 g0 = gv[l], g1 = gv[l + 64], b0 = bv[l], b1 = bv[l + 64];
    float4 o0, o1;
    o0.x = (v0.x - mean) * rstd * g0.x + b0.x;
    o0.y = (v0.y - mean) * rstd * g0.y + b0.y;
    o0.z = (v0.z - mean) * rstd * g0.z + b0.z;
    o0.w = (v0.w - mean) * rstd * g0.w + b0.w;
    o1.x = (v1.x - mean) * rstd * g1.x + b1.x;
    o1.y = (v1.y - mean) * rstd * g1.y + b1.y;
    o1.z = (v1.z - mean) * rstd * g1.z + b1.z;
    o1.w = (v1.w - mean) * rstd * g1.w + b1.w;
    xr[l] = o0; xr[l + 64] = o1;
    uint2 h0, h1;
    h0.x = pk2bf(o0.x, o0.y); h0.y = pk2bf(o0.z, o0.w);
    h1.x = pk2bf(o1.x, o1.y); h1.y = pk2bf(o1.z, o1.w);
    ((uint2*)(xb + row * 512))[l] = h0;
    ((uint2*)(xb + row * 512))[l + 64] = h1;
}

// ---------- fused attention v6: 8 waves (512 thr), max-free exp2 softmax ------
// grid (64 bh, 4 qb), 8 waves x 32 q-rows = 256 q-rows/block; 1 block/CU,
// 16 waves/CU. Q prescaled by 0.125*log2e -> P = exp2(S'), no max tracking
// (scores are small; softmax is shift-invariant, exp2 of |S'|<~3 is safe).
__global__ __launch_bounds__(512) void attn_kernel(
    const u16* __restrict__ Q, const u16* __restrict__ Km,
    const u16* __restrict__ vT, u16* __restrict__ O)
{
    __shared__ __align__(16) u16 Kt[2][64 * 64];
    __shared__ __align__(16) u16 Vt[2][64 * 64];
    __shared__ __align__(16) char Pl[8][4096];
    const int tid = threadIdx.x;
    const int l = tid & 63;
    const int w = tid >> 6;             // 0..7
    const int g = l >> 4;
    const int q15 = l & 15;
    const int bh = blockIdx.x;
    const int qb = blockIdx.y;          // 0..3
    const int b = bh >> 3, h = bh & 7;
    const int rowQ0 = b * 1024 + qb * 256 + w * 32;
    const int colh = h * 64;
    char* pl = &Pl[w][0];

    const int srow = l >> 3;
    const u16* Kbase = Km + (size_t)(b * 1024) * 512 + colh;
    const u16* Vbase = vT + (size_t)bh * 64 * 1024;

    B8 qf[2][2];
    #pragma unroll
    for (int qt = 0; qt < 2; ++qt)
        #pragma unroll
        for (int kc = 0; kc < 2; ++kc)
            qf[qt][kc].s = *(const s16x8*)&Q[(size_t)(rowQ0 + qt * 16 + q15) * 512
                                            + colh + kc * 32 + g * 8];

    f32x4 oacc[4][2] = {};
    float lrun[2] = {0.0f, 0.0f};

    // wave w stages chunk w (8 rows) of K and of V: one gld16 each.
    auto stage = [&](int buf, int kt) {
        int r = w * 8 + srow;
        int cc = (l & 7) ^ (r & 7);
        gld16(Kbase + (size_t)(kt * 64 + r) * 512 + cc * 8, &Kt[buf][w * 512]);
        gld16(Vbase + (size_t)r * 1024 + kt * 64 + cc * 8, &Vt[buf][w * 512]);
    };

    stage(0, 0);
    __syncthreads();
    int cur = 0;

    for (int kt = 0; kt < 16; ++kt) {
        if (kt < 15) stage(cur ^ 1, kt + 1);
        const u16* KtL = &Kt[cur][0];
        const u16* VtL = &Vt[cur][0];

        // --- S' = K (Q*0.125*log2e)^T
        f32x4 st[2][4];
        #pragma unroll
        for (int mt = 0; mt < 4; ++mt) {
            int r = mt * 16 + q15;
            B8 kf0, kf1;
            kf0.s = *(const s16x8*)&KtL[r * 64 + ((g ^ (r & 7)) * 8)];
            kf1.s = *(const s16x8*)&KtL[r * 64 + (((4 + g) ^ (r & 7)) * 8)];
            #pragma unroll
            for (int qt = 0; qt < 2; ++qt) {
                f32x4 t = {0.f, 0.f, 0.f, 0.f};
                t = __builtin_amdgcn_mfma_f32_16x16x32_bf16(kf0.b, qf[qt][0].b, t, 0, 0, 0);
                t = __builtin_amdgcn_mfma_f32_16x16x32_bf16(kf1.b, qf[qt][1].b, t, 0, 0, 0);
                st[qt][mt] = t;
            }
        }

        // --- P = exp2(S'); row-sum; pack bf16 to per-wave LDS
        #pragma unroll
        for (int qt = 0; qt < 2; ++qt) {
            int qrow = qt * 16 + q15;
            int rbase = qrow * 128;
            int sw = (qrow & 7) << 4;
            float rs = 0.0f;
            #pragma unroll
            for (int mt = 0; mt < 4; ++mt) {
                float e0 = fexp2(st[qt][mt][0]);
                float e1 = fexp2(st[qt][mt][1]);
                float e2 = fexp2(st[qt][mt][2]);
                float e3 = fexp2(st[qt][mt][3]);
                rs += (e0 + e1) + (e2 + e3);
                uint2 pk;
                pk.x = pk2bf(e0, e1);
                pk.y = pk2bf(e2, e3);
                *(uint2*)(pl + rbase + ((mt * 32 + g * 8) ^ sw)) = pk;
            }
            rs += __shfl_xor(rs, 16, 64);
            rs += __shfl_xor(rs, 32, 64);
            lrun[qt] += rs;
        }

        // --- read P^T B-frags
        B8 pf[2][2];
        #pragma unroll
        for (int qt = 0; qt < 2; ++qt) {
            int qrow = qt * 16 + q15;
            int sw = (qrow & 7) << 4;
            pf[qt][0].s = *(const s16x8*)(pl + qrow * 128 + ((g * 16) ^ sw));
            pf[qt][1].s = *(const s16x8*)(pl + qrow * 128 + (((4 + g) * 16) ^ sw));
        }

        // --- O^T += V^T * P^T
        #pragma unroll
        for (int dt = 0; dt < 4; ++dt) {
            int r = dt * 16 + q15;
            B8 vf0, vf1;
            vf0.s = *(const s16x8*)&VtL[r * 64 + ((g ^ (r & 7)) * 8)];
            vf1.s = *(const s16x8*)&VtL[r * 64 + (((4 + g) ^ (r & 7)) * 8)];
            #pragma unroll
            for (int qt = 0; qt < 2; ++qt) {
                oacc[dt][qt] = __builtin_amdgcn_mfma_f32_16x16x32_bf16(
                    vf0.b, pf[qt][0].b, oacc[dt][qt], 0, 0, 0);
                oacc[dt][qt] = __builtin_amdgcn_mfma_f32_16x16x32_bf16(
                    vf1.b, pf[qt][1].b, oacc[dt][qt], 0, 0, 0);
            }
        }
        __syncthreads();
        cur ^= 1;
    }

    // --- epilogue: O[q][d] = O^T / l
    #pragma unroll
    for (int qt = 0; qt < 2; ++qt) {
        float inv = 1.0f / lrun[qt];
        int row = rowQ0 + qt * 16 + q15;
        #pragma unroll
        for (int dt = 0; dt < 4; ++dt) {
            uint2 o;
            o.x = pk2bf(oacc[dt][qt][0] * inv, oacc[dt][qt][1] * inv);
            o.y = pk2bf(oacc[dt][qt][2] * inv, oacc[dt][qt][3] * inv);
            *(uint2*)&O[(size_t)row * 512 + colh + dt * 16 + g * 4] = o;
        }
    }
}

// ---------- launcher ----------
extern "C" void kernel_launch(void* const* d_in, const int* in_sizes, int n_in,
                              void* d_out, int out_size, void* d_ws, size_t ws_size,
                              hipStream_t stream)
{
    const int D = 512, F = 2048, Lc = 4;
    const int Mrows = 8 * 1024;

    const float* Wq   = (const float*)d_in[1];
    const float* Wk   = (const float*)d_in[2];
    const float* Wv   = (const float*)d_in[3];
    const float* bq   = (const float*)d_in[4];
    const float* bk   = (const float*)d_in[5];
    const float* bv   = (const float*)d_in[6];
    const float* Wo   = (const float*)d_in[7];
    const float* bo   = (const float*)d_in[8];
    const float* ln1g = (const float*)d_in[9];
    const float* ln1b = (const float*)d_in[10];
    const float* ln2g = (const float*)d_in[11];
    const float* ln2b = (const float*)d_in[12];
    const float* W1   = (const float*)d_in[13];
    const float* b1   = (const float*)d_in[14];
    const float* W2   = (const float*)d_in[15];
    const float* b2   = (const float*)d_in[16];
    const float* Wout = (const float*)d_in[17];
    const float* bout = (const float*)d_in[18];

    char* p = (char*)d_ws;
    auto alloc = [&](size_t bytes) {
        char* r = p;
        p += (bytes + 255) & ~(size_t)255;
        return r;
    };
    float* xA = (float*)alloc((size_t)Mrows * D * 4);
    float* xB = (float*)alloc((size_t)Mrows * D * 4);
    u16* xb   = (u16*)alloc((size_t)Mrows * D * 2);
    char* pool = alloc((size_t)Mrows * F * 2);
    u16* qb_ = (u16*)pool;
    u16* kb_ = (u16*)(pool + (size_t)Mrows * D * 2);
    u16* vT  = (u16*)(pool + (size_t)Mrows * D * 2 * 2);   // [64 bh][64 d][1024 s]
    u16* ao  = (u16*)(pool + (size_t)Mrows * D * 2 * 3);
    u16* ff1 = (u16*)pool;
    u16* wqkvB = (u16*)alloc((size_t)Lc * 3 * D * D * 2);
    u16* woB   = (u16*)alloc((size_t)Lc * D * D * 2);
    u16* w1B   = (u16*)alloc((size_t)Lc * F * D * 2);
    u16* w2B   = (u16*)alloc((size_t)Lc * D * F * 2);
    u16* woutB = (u16*)alloc((size_t)D * D * 2);

    auto cvt = [&](const float* src, u16* dst, size_t n) {
        int n4 = (int)(n / 4);
        cvt_bf16_kernel<<<(n4 + 255) / 256, 256, 0, stream>>>(src, dst, n4);
    };
    {
        int n4 = Lc * 3 * D * D / 4;
        cvt_qkvw_kernel<<<(n4 + 255) / 256, 256, 0, stream>>>(Wq, Wk, Wv, wqkvB, n4);
    }
    cvt(Wo, woB, (size_t)Lc * D * D);
    cvt(W1, w1B, (size_t)Lc * F * D);
    cvt(W2, w2B, (size_t)Lc * D * F);
    cvt(Wout, woutB, (size_t)D * D);

    // DDIM noise coefficients
    float ac[1000];
    {
        float start = 1e-4f, stop = 0.02f;
        float delta = (stop - start) / 999.0f;
        float prod = 1.0f;
        for (int i = 0; i < 1000; ++i) {
            float beta = start + (float)i * delta;
            prod *= (1.0f - beta);
            ac[i] = prod;
        }
    }
    int ts[2] = {999, 998};
    double cs[2];
    double tail = 1.0;
    for (int idx = 0; idx < 2; ++idx) {
        int t = ts[idx];
        cs[idx] = sqrt(1.0 - (double)ac[t]) * tail;
        tail *= sqrt((double)ac[t]);
    }
    uint32_t kk[2][2];
    for (int idx = 0; idx < 2; ++idx) {
        uint32_t x0 = 0u, x1 = (uint32_t)ts[idx];
        tf2x32_h(0u, 42u, x0, x1);
        kk[idx][0] = x0; kk[idx][1] = x1;
    }
    int n4tot = Mrows * D / 4;
    noise_kernel<<<(n4tot + 255) / 256, 256, 0, stream>>>(
        xA, xb,
        kk[0][0], kk[0][1], (float)cs[0],
        kk[1][0], kk[1][1], (float)cs[1], n4tot);

    dim3 gqkv(3 * D / 128, Mrows / 128);   // (12, 64) = 768
    dim3 g64(D / 64, Mrows / 128);         // (8, 64) = 512
    dim3 gff1(F / 128, Mrows / 128);       // (16, 64) = 1024

    for (int l = 0; l < Lc; ++l) {
        const u16* wqkv_l = wqkvB + (size_t)l * 3 * D * D;
        const u16* wo_l = woB + (size_t)l * D * D;
        const u16* w1_l = w1B + (size_t)l * F * D;
        const u16* w2_l = w2B + (size_t)l * D * F;

        gemm_bt<128, false, true, false, false, true><<<gqkv, 256, 0, stream>>>(
            xb, wqkv_l, bq + l * D, bk + l * D, bv + l * D, nullptr,
            qb_, kb_, vT, Mrows, 3 * D, D);
        attn_kernel<<<dim3(64, 4), 512, 0, stream>>>(qb_, kb_, vT, ao);
        gemm64<true><<<g64, 512, 0, stream>>>(
            ao, wo_l, bo + l * D, xA, xB, D, D);
        ln_kernel<<<Mrows / 4, 256, 0, stream>>>(xB, ln1g + l * D, ln1b + l * D, xb);
        gemm_bt<128, false, false, true, false, true><<<gff1, 256, 0, stream>>>(
            xb, w1_l, b1 + l * F, nullptr, nullptr, nullptr,
            ff1, nullptr, nullptr, Mrows, F, D);
        gemm64<true><<<g64, 512, 0, stream>>>(
            ff1, w2_l, b2 + l * D, xB, xA, D, F);
        ln_kernel<<<Mrows / 4, 256, 0, stream>>>(xA, ln2g + l * D, ln2b + l * D, xb);
    }
    gemm64<false><<<g64, 512, 0, stream>>>(
        xb, woutB, bout, nullptr, (float*)d_out, D, D);
}

// Round 10
// 607.162 us; speedup vs baseline: 1.7608x; 1.0147x over previous
//
#include <hip/hip_runtime.h>
#include <stdint.h>
#include <math.h>

typedef unsigned short u16;
typedef __bf16 bf16x8 __attribute__((ext_vector_type(8)));
typedef float f32x4 __attribute__((ext_vector_type(4)));
typedef short s16x8 __attribute__((ext_vector_type(8)));
union B8 { s16x8 s; bf16x8 b; };

// ---------- helpers ----------
__device__ __forceinline__ u16 f2bf(float f) {
    union { __bf16 h; u16 u; } r;
    r.h = (__bf16)f;
    return r.u;
}
__device__ __forceinline__ uint32_t pk2bf(float a, float b) {
    union { __bf16 h[2]; uint32_t u; } r;
    r.h[0] = (__bf16)a; r.h[1] = (__bf16)b;
    return r.u;
}
__device__ __forceinline__ float bf2f(u16 u) {
    return __uint_as_float(((uint32_t)u) << 16);
}
__device__ __forceinline__ float fexp2(float x) {
    return __builtin_amdgcn_exp2f(x);   // raw v_exp_f32
}

typedef const __attribute__((address_space(1))) uint32_t* gas_t;
typedef __attribute__((address_space(3))) uint32_t* las_t;
__device__ __forceinline__ void gld16(const void* g, void* l) {
    __builtin_amdgcn_global_load_lds((gas_t)g, (las_t)l, 16, 0, 0);
}

__host__ __forceinline__ uint32_t rotl32(uint32_t x, int d) {
    return (x << d) | (x >> (32 - d));
}
__device__ __forceinline__ uint32_t rotl_d(uint32_t x, int d) {
    return __builtin_amdgcn_alignbit(x, x, (uint32_t)(32 - d));
}

// JAX threefry2x32 (20 rounds) — host version (key folding)
__host__ inline void tf2x32_h(uint32_t k0, uint32_t k1, uint32_t& x0, uint32_t& x1) {
    uint32_t k2 = k0 ^ k1 ^ 0x1BD11BDAu;
    x0 += k0; x1 += k1;
    x0 += x1; x1 = rotl32(x1, 13); x1 ^= x0;
    x0 += x1; x1 = rotl32(x1, 15); x1 ^= x0;
    x0 += x1; x1 = rotl32(x1, 26); x1 ^= x0;
    x0 += x1; x1 = rotl32(x1,  6); x1 ^= x0;
    x0 += k1; x1 += k2 + 1u;
    x0 += x1; x1 = rotl32(x1, 17); x1 ^= x0;
    x0 += x1; x1 = rotl32(x1, 29); x1 ^= x0;
    x0 += x1; x1 = rotl32(x1, 16); x1 ^= x0;
    x0 += x1; x1 = rotl32(x1, 24); x1 ^= x0;
    x0 += k2; x1 += k0 + 2u;
    x0 += x1; x1 = rotl32(x1, 13); x1 ^= x0;
    x0 += x1; x1 = rotl32(x1, 15); x1 ^= x0;
    x0 += x1; x1 = rotl32(x1, 26); x1 ^= x0;
    x0 += x1; x1 = rotl32(x1,  6); x1 ^= x0;
    x0 += k0; x1 += k1 + 3u;
    x0 += x1; x1 = rotl32(x1, 17); x1 ^= x0;
    x0 += x1; x1 = rotl32(x1, 29); x1 ^= x0;
    x0 += x1; x1 = rotl32(x1, 16); x1 ^= x0;
    x0 += x1; x1 = rotl32(x1, 24); x1 ^= x0;
    x0 += k1; x1 += k2 + 4u;
    x0 += x1; x1 = rotl32(x1, 13); x1 ^= x0;
    x0 += x1; x1 = rotl32(x1, 15); x1 ^= x0;
    x0 += x1; x1 = rotl32(x1, 26); x1 ^= x0;
    x0 += x1; x1 = rotl32(x1,  6); x1 ^= x0;
    x0 += k2; x1 += k0 + 5u;
}

__device__ __forceinline__ void tf2x32_d(uint32_t k0, uint32_t k1,
                                         uint32_t& x0, uint32_t& x1) {
    uint32_t k2 = k0 ^ k1 ^ 0x1BD11BDAu;
    x0 += k0; x1 += k1;
    x0 += x1; x1 = rotl_d(x1, 13); x1 ^= x0;
    x0 += x1; x1 = rotl_d(x1, 15); x1 ^= x0;
    x0 += x1; x1 = rotl_d(x1, 26); x1 ^= x0;
    x0 += x1; x1 = rotl_d(x1,  6); x1 ^= x0;
    x0 += k1; x1 += k2 + 1u;
    x0 += x1; x1 = rotl_d(x1, 17); x1 ^= x0;
    x0 += x1; x1 = rotl_d(x1, 29); x1 ^= x0;
    x0 += x1; x1 = rotl_d(x1, 16); x1 ^= x0;
    x0 += x1; x1 = rotl_d(x1, 24); x1 ^= x0;
    x0 += k2; x1 += k0 + 2u;
    x0 += x1; x1 = rotl_d(x1, 13); x1 ^= x0;
    x0 += x1; x1 = rotl_d(x1, 15); x1 ^= x0;
    x0 += x1; x1 = rotl_d(x1, 26); x1 ^= x0;
    x0 += x1; x1 = rotl_d(x1,  6); x1 ^= x0;
    x0 += k0; x1 += k1 + 3u;
    x0 += x1; x1 = rotl_d(x1, 17); x1 ^= x0;
    x0 += x1; x1 = rotl_d(x1, 29); x1 ^= x0;
    x0 += x1; x1 = rotl_d(x1, 16); x1 ^= x0;
    x0 += x1; x1 = rotl_d(x1, 24); x1 ^= x0;
    x0 += k1; x1 += k2 + 4u;
    x0 += x1; x1 = rotl_d(x1, 13); x1 ^= x0;
    x0 += x1; x1 = rotl_d(x1, 15); x1 ^= x0;
    x0 += x1; x1 = rotl_d(x1, 26); x1 ^= x0;
    x0 += x1; x1 = rotl_d(x1,  6); x1 ^= x0;
    x0 += k2; x1 += k0 + 5u;
}

// XLA ErfInv f32 (Giles polynomial); log1p(-x^2) -> fast v_log_f32 path
__device__ __forceinline__ float erfinv_f(float x) {
    float w = -__logf(fmaf(x, -x, 1.0f));
    float p;
    if (w < 5.0f) {
        w = w - 2.5f;
        p = 2.81022636e-08f;
        p = p * w + 3.43273939e-07f;
        p = p * w + -3.5233877e-06f;
        p = p * w + -4.39150654e-06f;
        p = p * w + 0.00021858087f;
        p = p * w + -0.00125372503f;
        p = p * w + -0.00417768164f;
        p = p * w + 0.246640727f;
        p = p * w + 1.50140941f;
    } else {
        w = sqrtf(w) - 3.0f;
        p = -0.000200214257f;
        p = p * w + 0.000100950558f;
        p = p * w + 0.00134934322f;
        p = p * w + -0.00367342844f;
        p = p * w + 0.00573950773f;
        p = p * w + -0.0076224613f;
        p = p * w + 0.00943887047f;
        p = p * w + 1.00167406f;
        p = p * w + 2.83297682f;
    }
    return p * x;
}

__device__ __forceinline__ float tf_normal(uint32_t k0, uint32_t k1, uint32_t idx) {
    uint32_t x0 = 0u, x1 = idx;
    tf2x32_d(k0, k1, x0, x1);
    uint32_t bits = x0 ^ x1;
    float f = __uint_as_float((bits >> 9) | 0x3f800000u) - 1.0f;
    float u = f * 2.0f - 0.99999994f;
    u = fmaxf(-0.99999994f, u);
    return 1.41421354f * erfinv_f(u);
}

// ---------- noise init: 4 elements/thread, bf16 out only ----------
__global__ __launch_bounds__(256) void noise_kernel(
    u16* __restrict__ xb,
    uint32_t ka0, uint32_t ka1, float ca,
    uint32_t kb0, uint32_t kb1, float cb, int n4)
{
    int i = blockIdx.x * 256 + threadIdx.x;
    if (i >= n4) return;
    ushort4 vb;
    #pragma unroll
    for (int e = 0; e < 4; ++e) {
        uint32_t idx = (uint32_t)(i * 4 + e);
        float a = ca * tf_normal(ka0, ka1, idx)
                + cb * tf_normal(kb0, kb1, idx);
        (&vb.x)[e] = f2bf(a);
    }
    ((ushort4*)xb)[i] = vb;
}

// ---------- merged weight convert: all weights -> one contiguous bf16 region --
// layout (elements): [0,3145728) qkv interleaved by layer; then Wo(1048576),
// W1(4194304), W2(4194304), Wout(262144).
__global__ __launch_bounds__(256) void cvt_all_kernel(
    const float* __restrict__ Wq, const float* __restrict__ Wk,
    const float* __restrict__ Wv, const float* __restrict__ Wo,
    const float* __restrict__ W1, const float* __restrict__ W2,
    const float* __restrict__ Wout, u16* __restrict__ dst, int n4)
{
    int i = blockIdx.x * 256 + threadIdx.x;
    if (i >= n4) return;
    int e = i * 4;
    const float* src;
    if (e < 3145728) {
        int l = e / 786432;
        int rem = e - l * 786432;
        int sel = rem >> 18;
        int off = rem & 262143;
        src = (sel == 0 ? Wq : sel == 1 ? Wk : Wv) + l * 262144 + off;
    } else if (e < 4194304) src = Wo + (e - 3145728);
    else if (e < 8388608)  src = W1 + (e - 4194304);
    else if (e < 12582912) src = W2 + (e - 8388608);
    else                   src = Wout + (e - 12582912);
    float4 v = *(const float4*)src;
    uint2 o;
    o.x = pk2bf(v.x, v.y);
    o.y = pk2bf(v.z, v.w);
    *(uint2*)(dst + e) = o;
}

// ---------- GEMM (TN=128 shapes): 128x128 tile, 4 waves ----------
template<int TN, bool QKV, bool RELU>
__global__ __launch_bounds__(256) void gemm_bt(
    const u16* __restrict__ A, const u16* __restrict__ Bw,
    const float* __restrict__ bias0, const float* __restrict__ bias1,
    const float* __restrict__ bias2,
    void* __restrict__ out0, void* __restrict__ out1, void* __restrict__ out2,
    int M, int N, int K)
{
    constexpr int ACH = 16;
    constexpr int BCH = TN / 8;
    constexpr int CPW = (ACH + BCH) / 4;
    constexpr int NF = TN / 32;
    constexpr int ASZ = 128 * 64;
    constexpr int BSZ = TN * 64;
    __shared__ __align__(16) u16 At[ASZ];
    __shared__ __align__(16) u16 Bt[BSZ];
    const int tid = threadIdx.x;
    const int l = tid & 63;
    const int w = tid >> 6;
    const int wr = w >> 1, wc = w & 1;

    int lid = blockIdx.y * gridDim.x + blockIdx.x;
    int nwg = gridDim.x * gridDim.y;
    int mb, nb;
    if ((nwg & 7) == 0) {
        int nlid = (lid & 7) * (nwg >> 3) + (lid >> 3);
        mb = nlid / gridDim.x;
        nb = nlid - mb * gridDim.x;
    } else { mb = blockIdx.y; nb = blockIdx.x; }

    const int lrow = l >> 3;
    const int lch  = (l & 7) ^ lrow;

    const u16* aTile = A  + (size_t)(mb * 128) * K + (size_t)lrow * K + lch * 8;
    const u16* bTile = Bw + (size_t)(nb * TN) * K + (size_t)lrow * K + lch * 8;

    f32x4 acc[4][NF] = {};

    for (int k0 = 0; k0 < K; k0 += 64) {
        #pragma unroll
        for (int i = 0; i < CPW; ++i) {
            int c = w * CPW + i;
            if (c < ACH) gld16(aTile + (size_t)(c * 8) * K + k0, &At[c * 512]);
            else gld16(bTile + (size_t)((c - ACH) * 8) * K + k0, &Bt[(c - ACH) * 512]);
        }
        __syncthreads();
        #pragma unroll
        for (int kc = 0; kc < 2; ++kc) {
            B8 af[4], bfr[NF];
            #pragma unroll
            for (int m = 0; m < 4; ++m) {
                int r = wr * 64 + m * 16 + (l & 15);
                int ch = kc * 4 + (l >> 4);
                af[m].s = *(const s16x8*)&At[r * 64 + ((ch ^ (r & 7)) * 8)];
            }
            #pragma unroll
            for (int n = 0; n < NF; ++n) {
                int r = wc * (TN / 2) + n * 16 + (l & 15);
                int ch = kc * 4 + (l >> 4);
                bfr[n].s = *(const s16x8*)&Bt[r * 64 + ((ch ^ (r & 7)) * 8)];
            }
            #pragma unroll
            for (int m = 0; m < 4; ++m)
                #pragma unroll
                for (int n = 0; n < NF; ++n)
                    acc[m][n] = __builtin_amdgcn_mfma_f32_16x16x32_bf16(
                        af[m].b, bfr[n].b, acc[m][n], 0, 0, 0);
        }
        __syncthreads();
    }

    const float* biasp;
    void* outp;
    int colbase, Nout;
    float oscale = 1.0f;
    if constexpr (QKV) {
        int which = nb >> 2;
        colbase = (nb & 3) * 128 + wc * 64;
        if (which == 2) {
            float bcol[NF];
            #pragma unroll
            for (int n = 0; n < NF; ++n)
                bcol[n] = bias2[colbase + n * 16 + (l & 15)];
            u16* vT = (u16*)out2;
            #pragma unroll
            for (int m = 0; m < 4; ++m) {
                int row0 = mb * 128 + wr * 64 + m * 16 + (l >> 4) * 4;
                int bb = row0 >> 10, s0 = row0 & 1023;
                #pragma unroll
                for (int n = 0; n < NF; ++n) {
                    int col = colbase + n * 16 + (l & 15);
                    int hh = col >> 6, dd = col & 63;
                    uint2 o;
                    o.x = pk2bf(acc[m][n][0] + bcol[n], acc[m][n][1] + bcol[n]);
                    o.y = pk2bf(acc[m][n][2] + bcol[n], acc[m][n][3] + bcol[n]);
                    *(uint2*)&vT[((size_t)((bb * 8 + hh) * 64 + dd)) * 1024 + s0] = o;
                }
            }
            return;
        }
        biasp = which == 0 ? bias0 : bias1;
        outp  = which == 0 ? out0  : out1;
        if (which == 0) oscale = 0.18033688f;   // 0.125 * log2(e): exp2 softmax
        Nout = 512;
    } else {
        colbase = nb * TN + wc * (TN / 2);
        biasp = bias0;
        outp = out0;
        Nout = N;
    }

    float bcol[NF];
    #pragma unroll
    for (int n = 0; n < NF; ++n)
        bcol[n] = biasp[colbase + n * 16 + (l & 15)];

    #pragma unroll
    for (int m = 0; m < 4; ++m) {
        #pragma unroll
        for (int j = 0; j < 4; ++j) {
            int row = mb * 128 + wr * 64 + m * 16 + (l >> 4) * 4 + j;
            #pragma unroll
            for (int n = 0; n < NF; ++n) {
                int col = colbase + n * 16 + (l & 15);
                float v = acc[m][n][j] + bcol[n];
                if constexpr (QKV) v *= oscale;
                if constexpr (RELU)  v = fmaxf(v, 0.0f);
                ((u16*)outp)[(size_t)row * Nout + col] = f2bf(v);
            }
        }
    }
}

// ---------- GEMM64: 128x64 tile, 8 waves (512 thr), dbuf ----------
// RESID: += bf16 resid. BF16OUT: bf16 out, else f32 out.
template<bool RESID, bool BF16OUT>
__global__ __launch_bounds__(512) void gemm64(
    const u16* __restrict__ A, const u16* __restrict__ Bw,
    const float* __restrict__ bias, const u16* __restrict__ resid,
    void* __restrict__ out, int N, int K)
{
    constexpr int ACH = 16;
    constexpr int ASZ = 128 * 64, BSZ = 64 * 64;
    __shared__ __align__(16) u16 At[2 * ASZ];
    __shared__ __align__(16) u16 Bt[2 * BSZ];
    const int tid = threadIdx.x;
    const int l = tid & 63;
    const int w = tid >> 6;
    const int wr = w >> 1, wc = w & 1;

    int lid = blockIdx.y * gridDim.x + blockIdx.x;
    int nwg = gridDim.x * gridDim.y;
    int nlid = (lid & 7) * (nwg >> 3) + (lid >> 3);
    int mb = nlid / gridDim.x;
    int nb = nlid - mb * gridDim.x;

    const int lrow = l >> 3;
    const int lch  = (l & 7) ^ lrow;

    const u16* aTile = A  + (size_t)(mb * 128) * K + (size_t)lrow * K + lch * 8;
    const u16* bTile = Bw + (size_t)(nb * 64) * K + (size_t)lrow * K + lch * 8;

    f32x4 acc[2][2] = {};

    auto stage = [&](int buf, int k0) {
        #pragma unroll
        for (int i = 0; i < 3; ++i) {
            int c = w * 3 + i;
            if (c < ACH) gld16(aTile + (size_t)(c * 8) * K + k0, &At[buf * ASZ + c * 512]);
            else gld16(bTile + (size_t)((c - ACH) * 8) * K + k0, &Bt[buf * BSZ + (c - ACH) * 512]);
        }
    };
    auto compute = [&](int buf) {
        const u16* Ac = &At[buf * ASZ];
        const u16* Bc = &Bt[buf * BSZ];
        #pragma unroll
        for (int kc = 0; kc < 2; ++kc) {
            B8 af[2], bfr[2];
            #pragma unroll
            for (int m = 0; m < 2; ++m) {
                int r = wr * 32 + m * 16 + (l & 15);
                int ch = kc * 4 + (l >> 4);
                af[m].s = *(const s16x8*)&Ac[r * 64 + ((ch ^ (r & 7)) * 8)];
            }
            #pragma unroll
            for (int n = 0; n < 2; ++n) {
                int r = wc * 32 + n * 16 + (l & 15);
                int ch = kc * 4 + (l >> 4);
                bfr[n].s = *(const s16x8*)&Bc[r * 64 + ((ch ^ (r & 7)) * 8)];
            }
            #pragma unroll
            for (int m = 0; m < 2; ++m)
                #pragma unroll
                for (int n = 0; n < 2; ++n)
                    acc[m][n] = __builtin_amdgcn_mfma_f32_16x16x32_bf16(
                        af[m].b, bfr[n].b, acc[m][n], 0, 0, 0);
        }
    };

    stage(0, 0);
    __syncthreads();
    int cur = 0;
    for (int k0 = 0; k0 < K; k0 += 64) {
        if (k0 + 64 < K) stage(cur ^ 1, k0 + 64);
        compute(cur);
        __syncthreads();
        cur ^= 1;
    }

    float bcol[2];
    #pragma unroll
    for (int n = 0; n < 2; ++n)
        bcol[n] = bias[nb * 64 + wc * 32 + n * 16 + (l & 15)];

    #pragma unroll
    for (int m = 0; m < 2; ++m) {
        #pragma unroll
        for (int j = 0; j < 4; ++j) {
            int row = mb * 128 + wr * 32 + m * 16 + (l >> 4) * 4 + j;
            #pragma unroll
            for (int n = 0; n < 2; ++n) {
                int col = nb * 64 + wc * 32 + n * 16 + (l & 15);
                float v = acc[m][n][j] + bcol[n];
                if constexpr (RESID) v += bf2f(resid[(size_t)row * N + col]);
                if constexpr (BF16OUT) ((u16*)out)[(size_t)row * N + col] = f2bf(v);
                else                   ((float*)out)[(size_t)row * N + col] = v;
            }
        }
    }
}

// ---------- LayerNorm: bf16 in (y) -> bf16 out (xb). One wave per row of 512. -
__global__ __launch_bounds__(256) void ln_kernel(
    const u16* __restrict__ y, const float* __restrict__ g,
    const float* __restrict__ b, u16* __restrict__ xb)
{
    int row = blockIdx.x * 4 + (threadIdx.x >> 6);
    int l = threadIdx.x & 63;
    uint4 vv = ((const uint4*)(y + (size_t)row * 512))[l];
    uint32_t wsr[4] = {vv.x, vv.y, vv.z, vv.w};
    float xv[8];
    #pragma unroll
    for (int k = 0; k < 4; ++k) {
        xv[2 * k]     = __uint_as_float(wsr[k] << 16);
        xv[2 * k + 1] = __uint_as_float(wsr[k] & 0xFFFF0000u);
    }
    float s = 0.0f, q = 0.0f;
    #pragma unroll
    for (int k = 0; k < 8; ++k) { s += xv[k]; q += xv[k] * xv[k]; }
    #pragma unroll
    for (int m = 1; m < 64; m <<= 1) {
        s += __shfl_xor(s, m, 64);
        q += __shfl_xor(q, m, 64);
    }
    float mean = s * (1.0f / 512.0f);
    float var  = q * (1.0f / 512.0f) - mean * mean;
    float rstd = rsqrtf(var + 1e-5f);
    const float4* gv = (const float4*)g;
    const float4* bv = (const float4*)b;
    float4 g0 = gv[2 * l], g1 = gv[2 * l + 1];
    float4 b0 = bv[2 * l], b1 = bv[2 * l + 1];
    float ov[8];
    ov[0] = (xv[0] - mean) * rstd * g0.x + b0.x;
    ov[1] = (xv[1] - mean) * rstd * g0.y + b0.y;
    ov[2] = (xv[2] - mean) * rstd * g0.z + b0.z;
    ov[3] = (xv[3] - mean) * rstd * g0.w + b0.w;
    ov[4] = (xv[4] - mean) * rstd * g1.x + b1.x;
    ov[5] = (xv[5] - mean) * rstd * g1.y + b1.y;
    ov[6] = (xv[6] - mean) * rstd * g1.z + b1.z;
    ov[7] = (xv[7] - mean) * rstd * g1.w + b1.w;
    uint4 o;
    o.x = pk2bf(ov[0], ov[1]);
    o.y = pk2bf(ov[2], ov[3]);
    o.z = pk2bf(ov[4], ov[5]);
    o.w = pk2bf(ov[6], ov[7]);
    ((uint4*)(xb + (size_t)row * 512))[l] = o;
}

// ---------- fused attention v6: 8 waves (512 thr), max-free exp2 softmax ------
__global__ __launch_bounds__(512) void attn_kernel(
    const u16* __restrict__ Q, const u16* __restrict__ Km,
    const u16* __restrict__ vT, u16* __restrict__ O)
{
    __shared__ __align__(16) u16 Kt[2][64 * 64];
    __shared__ __align__(16) u16 Vt[2][64 * 64];
    __shared__ __align__(16) char Pl[8][4096];
    const int tid = threadIdx.x;
    const int l = tid & 63;
    const int w = tid >> 6;
    const int g = l >> 4;
    const int q15 = l & 15;
    const int bh = blockIdx.x;
    const int qb = blockIdx.y;
    const int b = bh >> 3, h = bh & 7;
    const int rowQ0 = b * 1024 + qb * 256 + w * 32;
    const int colh = h * 64;
    char* pl = &Pl[w][0];

    const int srow = l >> 3;
    const u16* Kbase = Km + (size_t)(b * 1024) * 512 + colh;
    const u16* Vbase = vT + (size_t)bh * 64 * 1024;

    B8 qf[2][2];
    #pragma unroll
    for (int qt = 0; qt < 2; ++qt)
        #pragma unroll
        for (int kc = 0; kc < 2; ++kc)
            qf[qt][kc].s = *(const s16x8*)&Q[(size_t)(rowQ0 + qt * 16 + q15) * 512
                                            + colh + kc * 32 + g * 8];

    f32x4 oacc[4][2] = {};
    float lrun[2] = {0.0f, 0.0f};

    auto stage = [&](int buf, int kt) {
        int r = w * 8 + srow;
        int cc = (l & 7) ^ (r & 7);
        gld16(Kbase + (size_t)(kt * 64 + r) * 512 + cc * 8, &Kt[buf][w * 512]);
        gld16(Vbase + (size_t)r * 1024 + kt * 64 + cc * 8, &Vt[buf][w * 512]);
    };

    stage(0, 0);
    __syncthreads();
    int cur = 0;

    for (int kt = 0; kt < 16; ++kt) {
        if (kt < 15) stage(cur ^ 1, kt + 1);
        const u16* KtL = &Kt[cur][0];
        const u16* VtL = &Vt[cur][0];

        f32x4 st[2][4];
        #pragma unroll
        for (int mt = 0; mt < 4; ++mt) {
            int r = mt * 16 + q15;
            B8 kf0, kf1;
            kf0.s = *(const s16x8*)&KtL[r * 64 + ((g ^ (r & 7)) * 8)];
            kf1.s = *(const s16x8*)&KtL[r * 64 + (((4 + g) ^ (r & 7)) * 8)];
            #pragma unroll
            for (int qt = 0; qt < 2; ++qt) {
                f32x4 t = {0.f, 0.f, 0.f, 0.f};
                t = __builtin_amdgcn_mfma_f32_16x16x32_bf16(kf0.b, qf[qt][0].b, t, 0, 0, 0);
                t = __builtin_amdgcn_mfma_f32_16x16x32_bf16(kf1.b, qf[qt][1].b, t, 0, 0, 0);
                st[qt][mt] = t;
            }
        }

        #pragma unroll
        for (int qt = 0; qt < 2; ++qt) {
            int qrow = qt * 16 + q15;
            int rbase = qrow * 128;
            int sw = (qrow & 7) << 4;
            float rs = 0.0f;
            #pragma unroll
            for (int mt = 0; mt < 4; ++mt) {
                float e0 = fexp2(st[qt][mt][0]);
                float e1 = fexp2(st[qt][mt][1]);
                float e2 = fexp2(st[qt][mt][2]);
                float e3 = fexp2(st[qt][mt][3]);
                rs += (e0 + e1) + (e2 + e3);
                uint2 pk;
                pk.x = pk2bf(e0, e1);
                pk.y = pk2bf(e2, e3);
                *(uint2*)(pl + rbase + ((mt * 32 + g * 8) ^ sw)) = pk;
            }
            rs += __shfl_xor(rs, 16, 64);
            rs += __shfl_xor(rs, 32, 64);
            lrun[qt] += rs;
        }

        B8 pf[2][2];
        #pragma unroll
        for (int qt = 0; qt < 2; ++qt) {
            int qrow = qt * 16 + q15;
            int sw = (qrow & 7) << 4;
            pf[qt][0].s = *(const s16x8*)(pl + qrow * 128 + ((g * 16) ^ sw));
            pf[qt][1].s = *(const s16x8*)(pl + qrow * 128 + (((4 + g) * 16) ^ sw));
        }

        #pragma unroll
        for (int dt = 0; dt < 4; ++dt) {
            int r = dt * 16 + q15;
            B8 vf0, vf1;
            vf0.s = *(const s16x8*)&VtL[r * 64 + ((g ^ (r & 7)) * 8)];
            vf1.s = *(const s16x8*)&VtL[r * 64 + (((4 + g) ^ (r & 7)) * 8)];
            #pragma unroll
            for (int qt = 0; qt < 2; ++qt) {
                oacc[dt][qt] = __builtin_amdgcn_mfma_f32_16x16x32_bf16(
                    vf0.b, pf[qt][0].b, oacc[dt][qt], 0, 0, 0);
                oacc[dt][qt] = __builtin_amdgcn_mfma_f32_16x16x32_bf16(
                    vf1.b, pf[qt][1].b, oacc[dt][qt], 0, 0, 0);
            }
        }
        __syncthreads();
        cur ^= 1;
    }

    #pragma unroll
    for (int qt = 0; qt < 2; ++qt) {
        float inv = 1.0f / lrun[qt];
        int row = rowQ0 + qt * 16 + q15;
        #pragma unroll
        for (int dt = 0; dt < 4; ++dt) {
            uint2 o;
            o.x = pk2bf(oacc[dt][qt][0] * inv, oacc[dt][qt][1] * inv);
            o.y = pk2bf(oacc[dt][qt][2] * inv, oacc[dt][qt][3] * inv);
            *(uint2*)&O[(size_t)row * 512 + colh + dt * 16 + g * 4] = o;
        }
    }
}

// ---------- launcher ----------
extern "C" void kernel_launch(void* const* d_in, const int* in_sizes, int n_in,
                              void* d_out, int out_size, void* d_ws, size_t ws_size,
                              hipStream_t stream)
{
    const int D = 512, F = 2048, Lc = 4;
    const int Mrows = 8 * 1024;

    const float* Wq   = (const float*)d_in[1];
    const float* Wk   = (const float*)d_in[2];
    const float* Wv   = (const float*)d_in[3];
    const float* bq   = (const float*)d_in[4];
    const float* bk   = (const float*)d_in[5];
    const float* bv   = (const float*)d_in[6];
    const float* Wo   = (const float*)d_in[7];
    const float* bo   = (const float*)d_in[8];
    const float* ln1g = (const float*)d_in[9];
    const float* ln1b = (const float*)d_in[10];
    const float* ln2g = (const float*)d_in[11];
    const float* ln2b = (const float*)d_in[12];
    const float* W1   = (const float*)d_in[13];
    const float* b1   = (const float*)d_in[14];
    const float* W2   = (const float*)d_in[15];
    const float* b2   = (const float*)d_in[16];
    const float* Wout = (const float*)d_in[17];
    const float* bout = (const float*)d_in[18];

    char* p = (char*)d_ws;
    auto alloc = [&](size_t bytes) {
        char* r = p;
        p += (bytes + 255) & ~(size_t)255;
        return r;
    };
    u16* xb = (u16*)alloc((size_t)Mrows * D * 2);          // bf16 activation master
    u16* y  = (u16*)alloc((size_t)Mrows * D * 2);          // bf16 pre-LN sum
    char* pool = alloc((size_t)Mrows * F * 2);
    u16* qb_ = (u16*)pool;
    u16* kb_ = (u16*)(pool + (size_t)Mrows * D * 2);
    u16* vT  = (u16*)(pool + (size_t)Mrows * D * 2 * 2);   // [64 bh][64 d][1024 s]
    u16* ao  = (u16*)(pool + (size_t)Mrows * D * 2 * 3);
    u16* ff1 = (u16*)pool;
    // contiguous weight region (element offsets match cvt_all_kernel)
    u16* wAll  = (u16*)alloc((size_t)12845056 * 2);
    u16* wqkvB = wAll;
    u16* woB   = wAll + 3145728;
    u16* w1B   = wAll + 4194304;
    u16* w2B   = wAll + 8388608;
    u16* woutB = wAll + 12582912;

    {
        int n4 = 12845056 / 4;
        cvt_all_kernel<<<(n4 + 255) / 256, 256, 0, stream>>>(
            Wq, Wk, Wv, Wo, W1, W2, Wout, wAll, n4);
    }

    // DDIM noise coefficients
    float ac[1000];
    {
        float start = 1e-4f, stop = 0.02f;
        float delta = (stop - start) / 999.0f;
        float prod = 1.0f;
        for (int i = 0; i < 1000; ++i) {
            float beta = start + (float)i * delta;
            prod *= (1.0f - beta);
            ac[i] = prod;
        }
    }
    int ts[2] = {999, 998};
    double cs[2];
    double tail = 1.0;
    for (int idx = 0; idx < 2; ++idx) {
        int t = ts[idx];
        cs[idx] = sqrt(1.0 - (double)ac[t]) * tail;
        tail *= sqrt((double)ac[t]);
    }
    uint32_t kk[2][2];
    for (int idx = 0; idx < 2; ++idx) {
        uint32_t x0 = 0u, x1 = (uint32_t)ts[idx];
        tf2x32_h(0u, 42u, x0, x1);
        kk[idx][0] = x0; kk[idx][1] = x1;
    }
    int n4tot = Mrows * D / 4;
    noise_kernel<<<(n4tot + 255) / 256, 256, 0, stream>>>(
        xb,
        kk[0][0], kk[0][1], (float)cs[0],
        kk[1][0], kk[1][1], (float)cs[1], n4tot);

    dim3 gqkv(3 * D / 128, Mrows / 128);   // (12, 64) = 768
    dim3 g64(D / 64, Mrows / 128);         // (8, 64) = 512
    dim3 gff1(F / 128, Mrows / 128);       // (16, 64) = 1024

    for (int l = 0; l < Lc; ++l) {
        const u16* wqkv_l = wqkvB + (size_t)l * 3 * D * D;
        const u16* wo_l = woB + (size_t)l * D * D;
        const u16* w1_l = w1B + (size_t)l * F * D;
        const u16* w2_l = w2B + (size_t)l * D * F;

        gemm_bt<128, true, false><<<gqkv, 256, 0, stream>>>(
            xb, wqkv_l, bq + l * D, bk + l * D, bv + l * D,
            qb_, kb_, vT, Mrows, 3 * D, D);
        attn_kernel<<<dim3(64, 4), 512, 0, stream>>>(qb_, kb_, vT, ao);
        // y = ao @ Wo^T + bo + xb(resid)
        gemm64<true, true><<<g64, 512, 0, stream>>>(
            ao, wo_l, bo + l * D, xb, y, D, D);
        ln_kernel<<<Mrows / 4, 256, 0, stream>>>(y, ln1g + l * D, ln1b + l * D, xb);
        gemm_bt<128, false, true><<<gff1, 256, 0, stream>>>(
            xb, w1_l, b1 + l * F, nullptr, nullptr,
            ff1, nullptr, nullptr, Mrows, F, D);
        // y = ff1 @ W2^T + b2 + xb(resid)
        gemm64<true, true><<<g64, 512, 0, stream>>>(
            ff1, w2_l, b2 + l * D, xb, y, D, F);
        ln_kernel<<<Mrows / 4, 256, 0, stream>>>(y, ln2g + l * D, ln2b + l * D, xb);
    }
    gemm64<false, false><<<g64, 512, 0, stream>>>(
        xb, woutB, bout, nullptr, (float*)d_out, D, D);
}

// Round 11
// 588.089 us; speedup vs baseline: 1.8179x; 1.0324x over previous
//
#include <hip/hip_runtime.h>
#include <stdint.h>
#include <math.h>

typedef unsigned short u16;
typedef __bf16 bf16x8 __attribute__((ext_vector_type(8)));
typedef float f32x4 __attribute__((ext_vector_type(4)));
typedef short s16x8 __attribute__((ext_vector_type(8)));
union B8 { s16x8 s; bf16x8 b; };

// ---------- helpers ----------
__device__ __forceinline__ u16 f2bf(float f) {
    union { __bf16 h; u16 u; } r;
    r.h = (__bf16)f;
    return r.u;
}
__device__ __forceinline__ uint32_t pk2bf(float a, float b) {
    union { __bf16 h[2]; uint32_t u; } r;
    r.h[0] = (__bf16)a; r.h[1] = (__bf16)b;
    return r.u;
}
__device__ __forceinline__ float bf2f(u16 u) {
    return __uint_as_float(((uint32_t)u) << 16);
}
__device__ __forceinline__ float fexp2(float x) {
    return __builtin_amdgcn_exp2f(x);   // raw v_exp_f32
}

typedef const __attribute__((address_space(1))) uint32_t* gas_t;
typedef __attribute__((address_space(3))) uint32_t* las_t;
__device__ __forceinline__ void gld16(const void* g, void* l) {
    __builtin_amdgcn_global_load_lds((gas_t)g, (las_t)l, 16, 0, 0);
}

__host__ __forceinline__ uint32_t rotl32(uint32_t x, int d) {
    return (x << d) | (x >> (32 - d));
}
__device__ __forceinline__ uint32_t rotl_d(uint32_t x, int d) {
    return __builtin_amdgcn_alignbit(x, x, (uint32_t)(32 - d));
}

// JAX threefry2x32 (20 rounds) — host version (key folding)
__host__ inline void tf2x32_h(uint32_t k0, uint32_t k1, uint32_t& x0, uint32_t& x1) {
    uint32_t k2 = k0 ^ k1 ^ 0x1BD11BDAu;
    x0 += k0; x1 += k1;
    x0 += x1; x1 = rotl32(x1, 13); x1 ^= x0;
    x0 += x1; x1 = rotl32(x1, 15); x1 ^= x0;
    x0 += x1; x1 = rotl32(x1, 26); x1 ^= x0;
    x0 += x1; x1 = rotl32(x1,  6); x1 ^= x0;
    x0 += k1; x1 += k2 + 1u;
    x0 += x1; x1 = rotl32(x1, 17); x1 ^= x0;
    x0 += x1; x1 = rotl32(x1, 29); x1 ^= x0;
    x0 += x1; x1 = rotl32(x1, 16); x1 ^= x0;
    x0 += x1; x1 = rotl32(x1, 24); x1 ^= x0;
    x0 += k2; x1 += k0 + 2u;
    x0 += x1; x1 = rotl32(x1, 13); x1 ^= x0;
    x0 += x1; x1 = rotl32(x1, 15); x1 ^= x0;
    x0 += x1; x1 = rotl32(x1, 26); x1 ^= x0;
    x0 += x1; x1 = rotl32(x1,  6); x1 ^= x0;
    x0 += k0; x1 += k1 + 3u;
    x0 += x1; x1 = rotl32(x1, 17); x1 ^= x0;
    x0 += x1; x1 = rotl32(x1, 29); x1 ^= x0;
    x0 += x1; x1 = rotl32(x1, 16); x1 ^= x0;
    x0 += x1; x1 = rotl32(x1, 24); x1 ^= x0;
    x0 += k1; x1 += k2 + 4u;
    x0 += x1; x1 = rotl32(x1, 13); x1 ^= x0;
    x0 += x1; x1 = rotl32(x1, 15); x1 ^= x0;
    x0 += x1; x1 = rotl32(x1, 26); x1 ^= x0;
    x0 += x1; x1 = rotl32(x1,  6); x1 ^= x0;
    x0 += k2; x1 += k0 + 5u;
}

__device__ __forceinline__ void tf2x32_d(uint32_t k0, uint32_t k1,
                                         uint32_t& x0, uint32_t& x1) {
    uint32_t k2 = k0 ^ k1 ^ 0x1BD11BDAu;
    x0 += k0; x1 += k1;
    x0 += x1; x1 = rotl_d(x1, 13); x1 ^= x0;
    x0 += x1; x1 = rotl_d(x1, 15); x1 ^= x0;
    x0 += x1; x1 = rotl_d(x1, 26); x1 ^= x0;
    x0 += x1; x1 = rotl_d(x1,  6); x1 ^= x0;
    x0 += k1; x1 += k2 + 1u;
    x0 += x1; x1 = rotl_d(x1, 17); x1 ^= x0;
    x0 += x1; x1 = rotl_d(x1, 29); x1 ^= x0;
    x0 += x1; x1 = rotl_d(x1, 16); x1 ^= x0;
    x0 += x1; x1 = rotl_d(x1, 24); x1 ^= x0;
    x0 += k2; x1 += k0 + 2u;
    x0 += x1; x1 = rotl_d(x1, 13); x1 ^= x0;
    x0 += x1; x1 = rotl_d(x1, 15); x1 ^= x0;
    x0 += x1; x1 = rotl_d(x1, 26); x1 ^= x0;
    x0 += x1; x1 = rotl_d(x1,  6); x1 ^= x0;
    x0 += k0; x1 += k1 + 3u;
    x0 += x1; x1 = rotl_d(x1, 17); x1 ^= x0;
    x0 += x1; x1 = rotl_d(x1, 29); x1 ^= x0;
    x0 += x1; x1 = rotl_d(x1, 16); x1 ^= x0;
    x0 += x1; x1 = rotl_d(x1, 24); x1 ^= x0;
    x0 += k1; x1 += k2 + 4u;
    x0 += x1; x1 = rotl_d(x1, 13); x1 ^= x0;
    x0 += x1; x1 = rotl_d(x1, 15); x1 ^= x0;
    x0 += x1; x1 = rotl_d(x1, 26); x1 ^= x0;
    x0 += x1; x1 = rotl_d(x1,  6); x1 ^= x0;
    x0 += k2; x1 += k0 + 5u;
}

// XLA ErfInv f32 (Giles polynomial); log1p(-x^2) -> fast v_log_f32 path
__device__ __forceinline__ float erfinv_f(float x) {
    float w = -__logf(fmaf(x, -x, 1.0f));
    float p;
    if (w < 5.0f) {
        w = w - 2.5f;
        p = 2.81022636e-08f;
        p = p * w + 3.43273939e-07f;
        p = p * w + -3.5233877e-06f;
        p = p * w + -4.39150654e-06f;
        p = p * w + 0.00021858087f;
        p = p * w + -0.00125372503f;
        p = p * w + -0.00417768164f;
        p = p * w + 0.246640727f;
        p = p * w + 1.50140941f;
    } else {
        w = sqrtf(w) - 3.0f;
        p = -0.000200214257f;
        p = p * w + 0.000100950558f;
        p = p * w + 0.00134934322f;
        p = p * w + -0.00367342844f;
        p = p * w + 0.00573950773f;
        p = p * w + -0.0076224613f;
        p = p * w + 0.00943887047f;
        p = p * w + 1.00167406f;
        p = p * w + 2.83297682f;
    }
    return p * x;
}

__device__ __forceinline__ float tf_normal(uint32_t k0, uint32_t k1, uint32_t idx) {
    uint32_t x0 = 0u, x1 = idx;
    tf2x32_d(k0, k1, x0, x1);
    uint32_t bits = x0 ^ x1;
    float f = __uint_as_float((bits >> 9) | 0x3f800000u) - 1.0f;
    float u = f * 2.0f - 0.99999994f;
    u = fmaxf(-0.99999994f, u);
    return 1.41421354f * erfinv_f(u);
}

// ---------- noise init: 4 elements/thread, bf16 out only ----------
__global__ __launch_bounds__(256) void noise_kernel(
    u16* __restrict__ xb,
    uint32_t ka0, uint32_t ka1, float ca,
    uint32_t kb0, uint32_t kb1, float cb, int n4)
{
    int i = blockIdx.x * 256 + threadIdx.x;
    if (i >= n4) return;
    ushort4 vb;
    #pragma unroll
    for (int e = 0; e < 4; ++e) {
        uint32_t idx = (uint32_t)(i * 4 + e);
        float a = ca * tf_normal(ka0, ka1, idx)
                + cb * tf_normal(kb0, kb1, idx);
        (&vb.x)[e] = f2bf(a);
    }
    ((ushort4*)xb)[i] = vb;
}

// ---------- merged weight convert ----------
__global__ __launch_bounds__(256) void cvt_all_kernel(
    const float* __restrict__ Wq, const float* __restrict__ Wk,
    const float* __restrict__ Wv, const float* __restrict__ Wo,
    const float* __restrict__ W1, const float* __restrict__ W2,
    const float* __restrict__ Wout, u16* __restrict__ dst, int n4)
{
    int i = blockIdx.x * 256 + threadIdx.x;
    if (i >= n4) return;
    int e = i * 4;
    const float* src;
    if (e < 3145728) {
        int l = e / 786432;
        int rem = e - l * 786432;
        int sel = rem >> 18;
        int off = rem & 262143;
        src = (sel == 0 ? Wq : sel == 1 ? Wk : Wv) + l * 262144 + off;
    } else if (e < 4194304) src = Wo + (e - 3145728);
    else if (e < 8388608)  src = W1 + (e - 4194304);
    else if (e < 12582912) src = W2 + (e - 8388608);
    else                   src = Wout + (e - 12582912);
    float4 v = *(const float4*)src;
    uint2 o;
    o.x = pk2bf(v.x, v.y);
    o.y = pk2bf(v.z, v.w);
    *(uint2*)(dst + e) = o;
}

// ---------- unified GEMM: 128x64 tile, 8 waves (512 thr), dbuf, XCD swizzle ---
// EPI: 0 = f32 out; 1 = bf16 out + bf16 resid; 2 = bf16 out + relu;
//      3 = QKV split (which=nb>>3: Q*log2e-scale -> out0, K -> out1,
//          V transposed -> out2 vT[bh][64 d][1024 s])
template<int EPI>
__global__ __launch_bounds__(512) void gemm64u(
    const u16* __restrict__ A, const u16* __restrict__ Bw,
    const float* __restrict__ bias0, const float* __restrict__ bias1,
    const float* __restrict__ bias2, const u16* __restrict__ resid,
    void* __restrict__ out0, void* __restrict__ out1, void* __restrict__ out2,
    int N, int K)
{
    constexpr int ACH = 16;
    constexpr int ASZ = 128 * 64, BSZ = 64 * 64;
    __shared__ __align__(16) u16 At[2 * ASZ];
    __shared__ __align__(16) u16 Bt[2 * BSZ];
    const int tid = threadIdx.x;
    const int l = tid & 63;
    const int w = tid >> 6;            // 0..7
    const int wr = w >> 1, wc = w & 1; // 4x2 wave grid, 32x32 per wave

    int lid = blockIdx.y * gridDim.x + blockIdx.x;
    int nwg = gridDim.x * gridDim.y;
    int nlid = (lid & 7) * (nwg >> 3) + (lid >> 3);
    int mb = nlid / gridDim.x;
    int nb = nlid - mb * gridDim.x;

    const int lrow = l >> 3;
    const int lch  = (l & 7) ^ lrow;

    const u16* aTile = A  + (size_t)(mb * 128) * K + (size_t)lrow * K + lch * 8;
    const u16* bTile = Bw + (size_t)(nb * 64) * K + (size_t)lrow * K + lch * 8;

    f32x4 acc[2][2] = {};

    auto stage = [&](int buf, int k0) {
        #pragma unroll
        for (int i = 0; i < 3; ++i) {
            int c = w * 3 + i;                 // 0..23
            if (c < ACH) gld16(aTile + (size_t)(c * 8) * K + k0, &At[buf * ASZ + c * 512]);
            else gld16(bTile + (size_t)((c - ACH) * 8) * K + k0, &Bt[buf * BSZ + (c - ACH) * 512]);
        }
    };
    auto compute = [&](int buf) {
        const u16* Ac = &At[buf * ASZ];
        const u16* Bc = &Bt[buf * BSZ];
        #pragma unroll
        for (int kc = 0; kc < 2; ++kc) {
            B8 af[2], bfr[2];
            #pragma unroll
            for (int m = 0; m < 2; ++m) {
                int r = wr * 32 + m * 16 + (l & 15);
                int ch = kc * 4 + (l >> 4);
                af[m].s = *(const s16x8*)&Ac[r * 64 + ((ch ^ (r & 7)) * 8)];
            }
            #pragma unroll
            for (int n = 0; n < 2; ++n) {
                int r = wc * 32 + n * 16 + (l & 15);
                int ch = kc * 4 + (l >> 4);
                bfr[n].s = *(const s16x8*)&Bc[r * 64 + ((ch ^ (r & 7)) * 8)];
            }
            #pragma unroll
            for (int m = 0; m < 2; ++m)
                #pragma unroll
                for (int n = 0; n < 2; ++n)
                    acc[m][n] = __builtin_amdgcn_mfma_f32_16x16x32_bf16(
                        af[m].b, bfr[n].b, acc[m][n], 0, 0, 0);
        }
    };

    stage(0, 0);
    __syncthreads();
    int cur = 0;
    for (int k0 = 0; k0 < K; k0 += 64) {
        if (k0 + 64 < K) stage(cur ^ 1, k0 + 64);
        compute(cur);
        __syncthreads();
        cur ^= 1;
    }

    if constexpr (EPI == 3) {
        int which = nb >> 3;                       // 0=Q 1=K 2=V
        int colseg = (nb & 7) * 64 + wc * 32;      // within 512
        const float* biasp = which == 0 ? bias0 : which == 1 ? bias1 : bias2;
        float bcol[2];
        #pragma unroll
        for (int n = 0; n < 2; ++n)
            bcol[n] = biasp[colseg + n * 16 + (l & 15)];
        if (which == 2) {
            u16* vT = (u16*)out2;
            #pragma unroll
            for (int m = 0; m < 2; ++m) {
                int row0 = mb * 128 + wr * 32 + m * 16 + (l >> 4) * 4;
                int bb = row0 >> 10, s0 = row0 & 1023;
                #pragma unroll
                for (int n = 0; n < 2; ++n) {
                    int col = colseg + n * 16 + (l & 15);
                    int hh = col >> 6, dd = col & 63;
                    uint2 o;
                    o.x = pk2bf(acc[m][n][0] + bcol[n], acc[m][n][1] + bcol[n]);
                    o.y = pk2bf(acc[m][n][2] + bcol[n], acc[m][n][3] + bcol[n]);
                    *(uint2*)&vT[((size_t)((bb * 8 + hh) * 64 + dd)) * 1024 + s0] = o;
                }
            }
            return;
        }
        float oscale = (which == 0) ? 0.18033688f : 1.0f;  // 0.125*log2(e)
        u16* outp = (u16*)(which == 0 ? out0 : out1);
        #pragma unroll
        for (int m = 0; m < 2; ++m) {
            #pragma unroll
            for (int j = 0; j < 4; ++j) {
                int row = mb * 128 + wr * 32 + m * 16 + (l >> 4) * 4 + j;
                #pragma unroll
                for (int n = 0; n < 2; ++n) {
                    int col = colseg + n * 16 + (l & 15);
                    outp[(size_t)row * 512 + col] = f2bf((acc[m][n][j] + bcol[n]) * oscale);
                }
            }
        }
        return;
    }

    float bcol[2];
    #pragma unroll
    for (int n = 0; n < 2; ++n)
        bcol[n] = bias0[nb * 64 + wc * 32 + n * 16 + (l & 15)];

    #pragma unroll
    for (int m = 0; m < 2; ++m) {
        #pragma unroll
        for (int j = 0; j < 4; ++j) {
            int row = mb * 128 + wr * 32 + m * 16 + (l >> 4) * 4 + j;
            #pragma unroll
            for (int n = 0; n < 2; ++n) {
                int col = nb * 64 + wc * 32 + n * 16 + (l & 15);
                float v = acc[m][n][j] + bcol[n];
                if constexpr (EPI == 1) v += bf2f(resid[(size_t)row * N + col]);
                if constexpr (EPI == 2) v = fmaxf(v, 0.0f);
                if constexpr (EPI == 0) ((float*)out0)[(size_t)row * N + col] = v;
                else                    ((u16*)out0)[(size_t)row * N + col] = f2bf(v);
            }
        }
    }
}

// ---------- LayerNorm: bf16 in (y) -> bf16 out (xb). One wave per row of 512. -
__global__ __launch_bounds__(256) void ln_kernel(
    const u16* __restrict__ y, const float* __restrict__ g,
    const float* __restrict__ b, u16* __restrict__ xb)
{
    int row = blockIdx.x * 4 + (threadIdx.x >> 6);
    int l = threadIdx.x & 63;
    uint4 vv = ((const uint4*)(y + (size_t)row * 512))[l];
    uint32_t wsr[4] = {vv.x, vv.y, vv.z, vv.w};
    float xv[8];
    #pragma unroll
    for (int k = 0; k < 4; ++k) {
        xv[2 * k]     = __uint_as_float(wsr[k] << 16);
        xv[2 * k + 1] = __uint_as_float(wsr[k] & 0xFFFF0000u);
    }
    float s = 0.0f, q = 0.0f;
    #pragma unroll
    for (int k = 0; k < 8; ++k) { s += xv[k]; q += xv[k] * xv[k]; }
    #pragma unroll
    for (int m = 1; m < 64; m <<= 1) {
        s += __shfl_xor(s, m, 64);
        q += __shfl_xor(q, m, 64);
    }
    float mean = s * (1.0f / 512.0f);
    float var  = q * (1.0f / 512.0f) - mean * mean;
    float rstd = rsqrtf(var + 1e-5f);
    const float4* gv = (const float4*)g;
    const float4* bv = (const float4*)b;
    float4 g0 = gv[2 * l], g1 = gv[2 * l + 1];
    float4 b0 = bv[2 * l], b1 = bv[2 * l + 1];
    float ov[8];
    ov[0] = (xv[0] - mean) * rstd * g0.x + b0.x;
    ov[1] = (xv[1] - mean) * rstd * g0.y + b0.y;
    ov[2] = (xv[2] - mean) * rstd * g0.z + b0.z;
    ov[3] = (xv[3] - mean) * rstd * g0.w + b0.w;
    ov[4] = (xv[4] - mean) * rstd * g1.x + b1.x;
    ov[5] = (xv[5] - mean) * rstd * g1.y + b1.y;
    ov[6] = (xv[6] - mean) * rstd * g1.z + b1.z;
    ov[7] = (xv[7] - mean) * rstd * g1.w + b1.w;
    uint4 o;
    o.x = pk2bf(ov[0], ov[1]);
    o.y = pk2bf(ov[2], ov[3]);
    o.z = pk2bf(ov[4], ov[5]);
    o.w = pk2bf(ov[6], ov[7]);
    ((uint4*)(xb + (size_t)row * 512))[l] = o;
}

// ---------- fused attention v6: 8 waves (512 thr), max-free exp2 softmax ------
__global__ __launch_bounds__(512) void attn_kernel(
    const u16* __restrict__ Q, const u16* __restrict__ Km,
    const u16* __restrict__ vT, u16* __restrict__ O)
{
    __shared__ __align__(16) u16 Kt[2][64 * 64];
    __shared__ __align__(16) u16 Vt[2][64 * 64];
    __shared__ __align__(16) char Pl[8][4096];
    const int tid = threadIdx.x;
    const int l = tid & 63;
    const int w = tid >> 6;
    const int g = l >> 4;
    const int q15 = l & 15;
    const int bh = blockIdx.x;
    const int qb = blockIdx.y;
    const int b = bh >> 3, h = bh & 7;
    const int rowQ0 = b * 1024 + qb * 256 + w * 32;
    const int colh = h * 64;
    char* pl = &Pl[w][0];

    const int srow = l >> 3;
    const u16* Kbase = Km + (size_t)(b * 1024) * 512 + colh;
    const u16* Vbase = vT + (size_t)bh * 64 * 1024;

    B8 qf[2][2];
    #pragma unroll
    for (int qt = 0; qt < 2; ++qt)
        #pragma unroll
        for (int kc = 0; kc < 2; ++kc)
            qf[qt][kc].s = *(const s16x8*)&Q[(size_t)(rowQ0 + qt * 16 + q15) * 512
                                            + colh + kc * 32 + g * 8];

    f32x4 oacc[4][2] = {};
    float lrun[2] = {0.0f, 0.0f};

    auto stage = [&](int buf, int kt) {
        int r = w * 8 + srow;
        int cc = (l & 7) ^ (r & 7);
        gld16(Kbase + (size_t)(kt * 64 + r) * 512 + cc * 8, &Kt[buf][w * 512]);
        gld16(Vbase + (size_t)r * 1024 + kt * 64 + cc * 8, &Vt[buf][w * 512]);
    };

    stage(0, 0);
    __syncthreads();
    int cur = 0;

    for (int kt = 0; kt < 16; ++kt) {
        if (kt < 15) stage(cur ^ 1, kt + 1);
        const u16* KtL = &Kt[cur][0];
        const u16* VtL = &Vt[cur][0];

        f32x4 st[2][4];
        #pragma unroll
        for (int mt = 0; mt < 4; ++mt) {
            int r = mt * 16 + q15;
            B8 kf0, kf1;
            kf0.s = *(const s16x8*)&KtL[r * 64 + ((g ^ (r & 7)) * 8)];
            kf1.s = *(const s16x8*)&KtL[r * 64 + (((4 + g) ^ (r & 7)) * 8)];
            #pragma unroll
            for (int qt = 0; qt < 2; ++qt) {
                f32x4 t = {0.f, 0.f, 0.f, 0.f};
                t = __builtin_amdgcn_mfma_f32_16x16x32_bf16(kf0.b, qf[qt][0].b, t, 0, 0, 0);
                t = __builtin_amdgcn_mfma_f32_16x16x32_bf16(kf1.b, qf[qt][1].b, t, 0, 0, 0);
                st[qt][mt] = t;
            }
        }

        #pragma unroll
        for (int qt = 0; qt < 2; ++qt) {
            int qrow = qt * 16 + q15;
            int rbase = qrow * 128;
            int sw = (qrow & 7) << 4;
            float rs = 0.0f;
            #pragma unroll
            for (int mt = 0; mt < 4; ++mt) {
                float e0 = fexp2(st[qt][mt][0]);
                float e1 = fexp2(st[qt][mt][1]);
                float e2 = fexp2(st[qt][mt][2]);
                float e3 = fexp2(st[qt][mt][3]);
                rs += (e0 + e1) + (e2 + e3);
                uint2 pk;
                pk.x = pk2bf(e0, e1);
                pk.y = pk2bf(e2, e3);
                *(uint2*)(pl + rbase + ((mt * 32 + g * 8) ^ sw)) = pk;
            }
            rs += __shfl_xor(rs, 16, 64);
            rs += __shfl_xor(rs, 32, 64);
            lrun[qt] += rs;
        }

        B8 pf[2][2];
        #pragma unroll
        for (int qt = 0; qt < 2; ++qt) {
            int qrow = qt * 16 + q15;
            int sw = (qrow & 7) << 4;
            pf[qt][0].s = *(const s16x8*)(pl + qrow * 128 + ((g * 16) ^ sw));
            pf[qt][1].s = *(const s16x8*)(pl + qrow * 128 + (((4 + g) * 16) ^ sw));
        }

        #pragma unroll
        for (int dt = 0; dt < 4; ++dt) {
            int r = dt * 16 + q15;
            B8 vf0, vf1;
            vf0.s = *(const s16x8*)&VtL[r * 64 + ((g ^ (r & 7)) * 8)];
            vf1.s = *(const s16x8*)&VtL[r * 64 + (((4 + g) ^ (r & 7)) * 8)];
            #pragma unroll
            for (int qt = 0; qt < 2; ++qt) {
                oacc[dt][qt] = __builtin_amdgcn_mfma_f32_16x16x32_bf16(
                    vf0.b, pf[qt][0].b, oacc[dt][qt], 0, 0, 0);
                oacc[dt][qt] = __builtin_amdgcn_mfma_f32_16x16x32_bf16(
                    vf1.b, pf[qt][1].b, oacc[dt][qt], 0, 0, 0);
            }
        }
        __syncthreads();
        cur ^= 1;
    }

    #pragma unroll
    for (int qt = 0; qt < 2; ++qt) {
        float inv = 1.0f / lrun[qt];
        int row = rowQ0 + qt * 16 + q15;
        #pragma unroll
        for (int dt = 0; dt < 4; ++dt) {
            uint2 o;
            o.x = pk2bf(oacc[dt][qt][0] * inv, oacc[dt][qt][1] * inv);
            o.y = pk2bf(oacc[dt][qt][2] * inv, oacc[dt][qt][3] * inv);
            *(uint2*)&O[(size_t)row * 512 + colh + dt * 16 + g * 4] = o;
        }
    }
}

// ---------- launcher ----------
extern "C" void kernel_launch(void* const* d_in, const int* in_sizes, int n_in,
                              void* d_out, int out_size, void* d_ws, size_t ws_size,
                              hipStream_t stream)
{
    const int D = 512, F = 2048, Lc = 4;
    const int Mrows = 8 * 1024;

    const float* Wq   = (const float*)d_in[1];
    const float* Wk   = (const float*)d_in[2];
    const float* Wv   = (const float*)d_in[3];
    const float* bq   = (const float*)d_in[4];
    const float* bk   = (const float*)d_in[5];
    const float* bv   = (const float*)d_in[6];
    const float* Wo   = (const float*)d_in[7];
    const float* bo   = (const float*)d_in[8];
    const float* ln1g = (const float*)d_in[9];
    const float* ln1b = (const float*)d_in[10];
    const float* ln2g = (const float*)d_in[11];
    const float* ln2b = (const float*)d_in[12];
    const float* W1   = (const float*)d_in[13];
    const float* b1   = (const float*)d_in[14];
    const float* W2   = (const float*)d_in[15];
    const float* b2   = (const float*)d_in[16];
    const float* Wout = (const float*)d_in[17];
    const float* bout = (const float*)d_in[18];

    char* p = (char*)d_ws;
    auto alloc = [&](size_t bytes) {
        char* r = p;
        p += (bytes + 255) & ~(size_t)255;
        return r;
    };
    u16* xb = (u16*)alloc((size_t)Mrows * D * 2);          // bf16 activation master
    u16* y  = (u16*)alloc((size_t)Mrows * D * 2);          // bf16 pre-LN sum
    char* pool = alloc((size_t)Mrows * F * 2);
    u16* qb_ = (u16*)pool;
    u16* kb_ = (u16*)(pool + (size_t)Mrows * D * 2);
    u16* vT  = (u16*)(pool + (size_t)Mrows * D * 2 * 2);   // [64 bh][64 d][1024 s]
    u16* ao  = (u16*)(pool + (size_t)Mrows * D * 2 * 3);
    u16* ff1 = (u16*)pool;
    u16* wAll  = (u16*)alloc((size_t)12845056 * 2);
    u16* wqkvB = wAll;
    u16* woB   = wAll + 3145728;
    u16* w1B   = wAll + 4194304;
    u16* w2B   = wAll + 8388608;
    u16* woutB = wAll + 12582912;

    {
        int n4 = 12845056 / 4;
        cvt_all_kernel<<<(n4 + 255) / 256, 256, 0, stream>>>(
            Wq, Wk, Wv, Wo, W1, W2, Wout, wAll, n4);
    }

    // DDIM noise coefficients
    float ac[1000];
    {
        float start = 1e-4f, stop = 0.02f;
        float delta = (stop - start) / 999.0f;
        float prod = 1.0f;
        for (int i = 0; i < 1000; ++i) {
            float beta = start + (float)i * delta;
            prod *= (1.0f - beta);
            ac[i] = prod;
        }
    }
    int ts[2] = {999, 998};
    double cs[2];
    double tail = 1.0;
    for (int idx = 0; idx < 2; ++idx) {
        int t = ts[idx];
        cs[idx] = sqrt(1.0 - (double)ac[t]) * tail;
        tail *= sqrt((double)ac[t]);
    }
    uint32_t kk[2][2];
    for (int idx = 0; idx < 2; ++idx) {
        uint32_t x0 = 0u, x1 = (uint32_t)ts[idx];
        tf2x32_h(0u, 42u, x0, x1);
        kk[idx][0] = x0; kk[idx][1] = x1;
    }
    int n4tot = Mrows * D / 4;
    noise_kernel<<<(n4tot + 255) / 256, 256, 0, stream>>>(
        xb,
        kk[0][0], kk[0][1], (float)cs[0],
        kk[1][0], kk[1][1], (float)cs[1], n4tot);

    dim3 gqkv(3 * D / 64, Mrows / 128);    // (24, 64) = 1536
    dim3 g64(D / 64, Mrows / 128);         // (8, 64) = 512
    dim3 gff1(F / 64, Mrows / 128);        // (32, 64) = 2048

    for (int l = 0; l < Lc; ++l) {
        const u16* wqkv_l = wqkvB + (size_t)l * 3 * D * D;
        const u16* wo_l = woB + (size_t)l * D * D;
        const u16* w1_l = w1B + (size_t)l * F * D;
        const u16* w2_l = w2B + (size_t)l * D * F;

        gemm64u<3><<<gqkv, 512, 0, stream>>>(
            xb, wqkv_l, bq + l * D, bk + l * D, bv + l * D, nullptr,
            qb_, kb_, vT, 3 * D, D);
        attn_kernel<<<dim3(64, 4), 512, 0, stream>>>(qb_, kb_, vT, ao);
        gemm64u<1><<<g64, 512, 0, stream>>>(
            ao, wo_l, bo + l * D, nullptr, nullptr, xb,
            y, nullptr, nullptr, D, D);
        ln_kernel<<<Mrows / 4, 256, 0, stream>>>(y, ln1g + l * D, ln1b + l * D, xb);
        gemm64u<2><<<gff1, 512, 0, stream>>>(
            xb, w1_l, b1 + l * F, nullptr, nullptr, nullptr,
            ff1, nullptr, nullptr, F, D);
        gemm64u<1><<<g64, 512, 0, stream>>>(
            ff1, w2_l, b2 + l * D, nullptr, nullptr, xb,
            y, nullptr, nullptr, D, F);
        ln_kernel<<<Mrows / 4, 256, 0, stream>>>(y, ln2g + l * D, ln2b + l * D, xb);
    }
    gemm64u<0><<<g64, 512, 0, stream>>>(
        xb, woutB, bout, nullptr, nullptr, nullptr,
        d_out, nullptr, nullptr, D, D);
}

// Round 12
// 576.984 us; speedup vs baseline: 1.8529x; 1.0192x over previous
//
#include <hip/hip_runtime.h>
#include <stdint.h>
#include <math.h>

typedef unsigned short u16;
typedef __bf16 bf16x8 __attribute__((ext_vector_type(8)));
typedef float f32x4 __attribute__((ext_vector_type(4)));
typedef short s16x8 __attribute__((ext_vector_type(8)));
union B8 { s16x8 s; bf16x8 b; };

// ---------- helpers ----------
__device__ __forceinline__ u16 f2bf(float f) {
    union { __bf16 h; u16 u; } r;
    r.h = (__bf16)f;
    return r.u;
}
__device__ __forceinline__ uint32_t pk2bf(float a, float b) {
    union { __bf16 h[2]; uint32_t u; } r;
    r.h[0] = (__bf16)a; r.h[1] = (__bf16)b;
    return r.u;
}
__device__ __forceinline__ float bf2f(u16 u) {
    return __uint_as_float(((uint32_t)u) << 16);
}
__device__ __forceinline__ float fexp2(float x) {
    return __builtin_amdgcn_exp2f(x);   // raw v_exp_f32
}

typedef const __attribute__((address_space(1))) uint32_t* gas_t;
typedef __attribute__((address_space(3))) uint32_t* las_t;
__device__ __forceinline__ void gld16(const void* g, void* l) {
    __builtin_amdgcn_global_load_lds((gas_t)g, (las_t)l, 16, 0, 0);
}

__host__ __forceinline__ uint32_t rotl32(uint32_t x, int d) {
    return (x << d) | (x >> (32 - d));
}
__device__ __forceinline__ uint32_t rotl_d(uint32_t x, int d) {
    return __builtin_amdgcn_alignbit(x, x, (uint32_t)(32 - d));
}

// JAX threefry2x32 (20 rounds) — host version (key folding)
__host__ inline void tf2x32_h(uint32_t k0, uint32_t k1, uint32_t& x0, uint32_t& x1) {
    uint32_t k2 = k0 ^ k1 ^ 0x1BD11BDAu;
    x0 += k0; x1 += k1;
    x0 += x1; x1 = rotl32(x1, 13); x1 ^= x0;
    x0 += x1; x1 = rotl32(x1, 15); x1 ^= x0;
    x0 += x1; x1 = rotl32(x1, 26); x1 ^= x0;
    x0 += x1; x1 = rotl32(x1,  6); x1 ^= x0;
    x0 += k1; x1 += k2 + 1u;
    x0 += x1; x1 = rotl32(x1, 17); x1 ^= x0;
    x0 += x1; x1 = rotl32(x1, 29); x1 ^= x0;
    x0 += x1; x1 = rotl32(x1, 16); x1 ^= x0;
    x0 += x1; x1 = rotl32(x1, 24); x1 ^= x0;
    x0 += k2; x1 += k0 + 2u;
    x0 += x1; x1 = rotl32(x1, 13); x1 ^= x0;
    x0 += x1; x1 = rotl32(x1, 15); x1 ^= x0;
    x0 += x1; x1 = rotl32(x1, 26); x1 ^= x0;
    x0 += x1; x1 = rotl32(x1,  6); x1 ^= x0;
    x0 += k0; x1 += k1 + 3u;
    x0 += x1; x1 = rotl32(x1, 17); x1 ^= x0;
    x0 += x1; x1 = rotl32(x1, 29); x1 ^= x0;
    x0 += x1; x1 = rotl32(x1, 16); x1 ^= x0;
    x0 += x1; x1 = rotl32(x1, 24); x1 ^= x0;
    x0 += k1; x1 += k2 + 4u;
    x0 += x1; x1 = rotl32(x1, 13); x1 ^= x0;
    x0 += x1; x1 = rotl32(x1, 15); x1 ^= x0;
    x0 += x1; x1 = rotl32(x1, 26); x1 ^= x0;
    x0 += x1; x1 = rotl32(x1,  6); x1 ^= x0;
    x0 += k2; x1 += k0 + 5u;
}

__device__ __forceinline__ void tf2x32_d(uint32_t k0, uint32_t k1,
                                         uint32_t& x0, uint32_t& x1) {
    uint32_t k2 = k0 ^ k1 ^ 0x1BD11BDAu;
    x0 += k0; x1 += k1;
    x0 += x1; x1 = rotl_d(x1, 13); x1 ^= x0;
    x0 += x1; x1 = rotl_d(x1, 15); x1 ^= x0;
    x0 += x1; x1 = rotl_d(x1, 26); x1 ^= x0;
    x0 += x1; x1 = rotl_d(x1,  6); x1 ^= x0;
    x0 += k1; x1 += k2 + 1u;
    x0 += x1; x1 = rotl_d(x1, 17); x1 ^= x0;
    x0 += x1; x1 = rotl_d(x1, 29); x1 ^= x0;
    x0 += x1; x1 = rotl_d(x1, 16); x1 ^= x0;
    x0 += x1; x1 = rotl_d(x1, 24); x1 ^= x0;
    x0 += k2; x1 += k0 + 2u;
    x0 += x1; x1 = rotl_d(x1, 13); x1 ^= x0;
    x0 += x1; x1 = rotl_d(x1, 15); x1 ^= x0;
    x0 += x1; x1 = rotl_d(x1, 26); x1 ^= x0;
    x0 += x1; x1 = rotl_d(x1,  6); x1 ^= x0;
    x0 += k0; x1 += k1 + 3u;
    x0 += x1; x1 = rotl_d(x1, 17); x1 ^= x0;
    x0 += x1; x1 = rotl_d(x1, 29); x1 ^= x0;
    x0 += x1; x1 = rotl_d(x1, 16); x1 ^= x0;
    x0 += x1; x1 = rotl_d(x1, 24); x1 ^= x0;
    x0 += k1; x1 += k2 + 4u;
    x0 += x1; x1 = rotl_d(x1, 13); x1 ^= x0;
    x0 += x1; x1 = rotl_d(x1, 15); x1 ^= x0;
    x0 += x1; x1 = rotl_d(x1, 26); x1 ^= x0;
    x0 += x1; x1 = rotl_d(x1,  6); x1 ^= x0;
    x0 += k2; x1 += k0 + 5u;
}

// XLA ErfInv f32 (Giles polynomial); log1p(-x^2) -> fast v_log_f32 path
__device__ __forceinline__ float erfinv_f(float x) {
    float w = -__logf(fmaf(x, -x, 1.0f));
    float p;
    if (w < 5.0f) {
        w = w - 2.5f;
        p = 2.81022636e-08f;
        p = p * w + 3.43273939e-07f;
        p = p * w + -3.5233877e-06f;
        p = p * w + -4.39150654e-06f;
        p = p * w + 0.00021858087f;
        p = p * w + -0.00125372503f;
        p = p * w + -0.00417768164f;
        p = p * w + 0.246640727f;
        p = p * w + 1.50140941f;
    } else {
        w = sqrtf(w) - 3.0f;
        p = -0.000200214257f;
        p = p * w + 0.000100950558f;
        p = p * w + 0.00134934322f;
        p = p * w + -0.00367342844f;
        p = p * w + 0.00573950773f;
        p = p * w + -0.0076224613f;
        p = p * w + 0.00943887047f;
        p = p * w + 1.00167406f;
        p = p * w + 2.83297682f;
    }
    return p * x;
}

__device__ __forceinline__ float tf_normal(uint32_t k0, uint32_t k1, uint32_t idx) {
    uint32_t x0 = 0u, x1 = idx;
    tf2x32_d(k0, k1, x0, x1);
    uint32_t bits = x0 ^ x1;
    float f = __uint_as_float((bits >> 9) | 0x3f800000u) - 1.0f;
    float u = f * 2.0f - 0.99999994f;
    u = fmaxf(-0.99999994f, u);
    return 1.41421354f * erfinv_f(u);
}

// ---------- noise init: 4 elements/thread, bf16 out only ----------
__global__ __launch_bounds__(256) void noise_kernel(
    u16* __restrict__ xb,
    uint32_t ka0, uint32_t ka1, float ca,
    uint32_t kb0, uint32_t kb1, float cb, int n4)
{
    int i = blockIdx.x * 256 + threadIdx.x;
    if (i >= n4) return;
    ushort4 vb;
    #pragma unroll
    for (int e = 0; e < 4; ++e) {
        uint32_t idx = (uint32_t)(i * 4 + e);
        float a = ca * tf_normal(ka0, ka1, idx)
                + cb * tf_normal(kb0, kb1, idx);
        (&vb.x)[e] = f2bf(a);
    }
    ((ushort4*)xb)[i] = vb;
}

// ---------- merged weight convert ----------
__global__ __launch_bounds__(256) void cvt_all_kernel(
    const float* __restrict__ Wq, const float* __restrict__ Wk,
    const float* __restrict__ Wv, const float* __restrict__ Wo,
    const float* __restrict__ W1, const float* __restrict__ W2,
    const float* __restrict__ Wout, u16* __restrict__ dst, int n4)
{
    int i = blockIdx.x * 256 + threadIdx.x;
    if (i >= n4) return;
    int e = i * 4;
    const float* src;
    if (e < 3145728) {
        int l = e / 786432;
        int rem = e - l * 786432;
        int sel = rem >> 18;
        int off = rem & 262143;
        src = (sel == 0 ? Wq : sel == 1 ? Wk : Wv) + l * 262144 + off;
    } else if (e < 4194304) src = Wo + (e - 3145728);
    else if (e < 8388608)  src = W1 + (e - 4194304);
    else if (e < 12582912) src = W2 + (e - 8388608);
    else                   src = Wout + (e - 12582912);
    float4 v = *(const float4*)src;
    uint2 o;
    o.x = pk2bf(v.x, v.y);
    o.y = pk2bf(v.z, v.w);
    *(uint2*)(dst + e) = o;
}

// ---------- unified GEMM: 128x64 tile, 8 waves (512 thr), dbuf, XCD swizzle ---
// EPI: 0 = f32 out; 1 = bf16 out + bf16 resid; 2 = bf16 out + relu;
//      3 = QKV split
template<int EPI>
__global__ __launch_bounds__(512) void gemm64u(
    const u16* __restrict__ A, const u16* __restrict__ Bw,
    const float* __restrict__ bias0, const float* __restrict__ bias1,
    const float* __restrict__ bias2, const u16* __restrict__ resid,
    void* __restrict__ out0, void* __restrict__ out1, void* __restrict__ out2,
    int N, int K)
{
    constexpr int ACH = 16;
    constexpr int ASZ = 128 * 64, BSZ = 64 * 64;
    __shared__ __align__(16) u16 At[2 * ASZ];
    __shared__ __align__(16) u16 Bt[2 * BSZ];
    const int tid = threadIdx.x;
    const int l = tid & 63;
    const int w = tid >> 6;
    const int wr = w >> 1, wc = w & 1;

    int lid = blockIdx.y * gridDim.x + blockIdx.x;
    int nwg = gridDim.x * gridDim.y;
    int nlid = (lid & 7) * (nwg >> 3) + (lid >> 3);
    int mb = nlid / gridDim.x;
    int nb = nlid - mb * gridDim.x;

    const int lrow = l >> 3;
    const int lch  = (l & 7) ^ lrow;

    const u16* aTile = A  + (size_t)(mb * 128) * K + (size_t)lrow * K + lch * 8;
    const u16* bTile = Bw + (size_t)(nb * 64) * K + (size_t)lrow * K + lch * 8;

    f32x4 acc[2][2] = {};

    auto stage = [&](int buf, int k0) {
        #pragma unroll
        for (int i = 0; i < 3; ++i) {
            int c = w * 3 + i;
            if (c < ACH) gld16(aTile + (size_t)(c * 8) * K + k0, &At[buf * ASZ + c * 512]);
            else gld16(bTile + (size_t)((c - ACH) * 8) * K + k0, &Bt[buf * BSZ + (c - ACH) * 512]);
        }
    };
    auto compute = [&](int buf) {
        const u16* Ac = &At[buf * ASZ];
        const u16* Bc = &Bt[buf * BSZ];
        #pragma unroll
        for (int kc = 0; kc < 2; ++kc) {
            B8 af[2], bfr[2];
            #pragma unroll
            for (int m = 0; m < 2; ++m) {
                int r = wr * 32 + m * 16 + (l & 15);
                int ch = kc * 4 + (l >> 4);
                af[m].s = *(const s16x8*)&Ac[r * 64 + ((ch ^ (r & 7)) * 8)];
            }
            #pragma unroll
            for (int n = 0; n < 2; ++n) {
                int r = wc * 32 + n * 16 + (l & 15);
                int ch = kc * 4 + (l >> 4);
                bfr[n].s = *(const s16x8*)&Bc[r * 64 + ((ch ^ (r & 7)) * 8)];
            }
            #pragma unroll
            for (int m = 0; m < 2; ++m)
                #pragma unroll
                for (int n = 0; n < 2; ++n)
                    acc[m][n] = __builtin_amdgcn_mfma_f32_16x16x32_bf16(
                        af[m].b, bfr[n].b, acc[m][n], 0, 0, 0);
        }
    };

    stage(0, 0);
    __syncthreads();
    int cur = 0;
    for (int k0 = 0; k0 < K; k0 += 64) {
        if (k0 + 64 < K) stage(cur ^ 1, k0 + 64);
        compute(cur);
        __syncthreads();
        cur ^= 1;
    }

    if constexpr (EPI == 3) {
        int which = nb >> 3;
        int colseg = (nb & 7) * 64 + wc * 32;
        const float* biasp = which == 0 ? bias0 : which == 1 ? bias1 : bias2;
        float bcol[2];
        #pragma unroll
        for (int n = 0; n < 2; ++n)
            bcol[n] = biasp[colseg + n * 16 + (l & 15)];
        if (which == 2) {
            u16* vT = (u16*)out2;
            #pragma unroll
            for (int m = 0; m < 2; ++m) {
                int row0 = mb * 128 + wr * 32 + m * 16 + (l >> 4) * 4;
                int bb = row0 >> 10, s0 = row0 & 1023;
                #pragma unroll
                for (int n = 0; n < 2; ++n) {
                    int col = colseg + n * 16 + (l & 15);
                    int hh = col >> 6, dd = col & 63;
                    uint2 o;
                    o.x = pk2bf(acc[m][n][0] + bcol[n], acc[m][n][1] + bcol[n]);
                    o.y = pk2bf(acc[m][n][2] + bcol[n], acc[m][n][3] + bcol[n]);
                    *(uint2*)&vT[((size_t)((bb * 8 + hh) * 64 + dd)) * 1024 + s0] = o;
                }
            }
            return;
        }
        float oscale = (which == 0) ? 0.18033688f : 1.0f;  // 0.125*log2(e)
        u16* outp = (u16*)(which == 0 ? out0 : out1);
        #pragma unroll
        for (int m = 0; m < 2; ++m) {
            #pragma unroll
            for (int j = 0; j < 4; ++j) {
                int row = mb * 128 + wr * 32 + m * 16 + (l >> 4) * 4 + j;
                #pragma unroll
                for (int n = 0; n < 2; ++n) {
                    int col = colseg + n * 16 + (l & 15);
                    outp[(size_t)row * 512 + col] = f2bf((acc[m][n][j] + bcol[n]) * oscale);
                }
            }
        }
        return;
    }

    float bcol[2];
    #pragma unroll
    for (int n = 0; n < 2; ++n)
        bcol[n] = bias0[nb * 64 + wc * 32 + n * 16 + (l & 15)];

    #pragma unroll
    for (int m = 0; m < 2; ++m) {
        #pragma unroll
        for (int j = 0; j < 4; ++j) {
            int row = mb * 128 + wr * 32 + m * 16 + (l >> 4) * 4 + j;
            #pragma unroll
            for (int n = 0; n < 2; ++n) {
                int col = nb * 64 + wc * 32 + n * 16 + (l & 15);
                float v = acc[m][n][j] + bcol[n];
                if constexpr (EPI == 1) v += bf2f(resid[(size_t)row * N + col]);
                if constexpr (EPI == 2) v = fmaxf(v, 0.0f);
                if constexpr (EPI == 0) ((float*)out0)[(size_t)row * N + col] = v;
                else                    ((u16*)out0)[(size_t)row * N + col] = f2bf(v);
            }
        }
    }
}

// ---------- LayerNorm: bf16 in (y) -> bf16 out (xb). One wave per row of 512. -
__global__ __launch_bounds__(256) void ln_kernel(
    const u16* __restrict__ y, const float* __restrict__ g,
    const float* __restrict__ b, u16* __restrict__ xb)
{
    int row = blockIdx.x * 4 + (threadIdx.x >> 6);
    int l = threadIdx.x & 63;
    uint4 vv = ((const uint4*)(y + (size_t)row * 512))[l];
    uint32_t wsr[4] = {vv.x, vv.y, vv.z, vv.w};
    float xv[8];
    #pragma unroll
    for (int k = 0; k < 4; ++k) {
        xv[2 * k]     = __uint_as_float(wsr[k] << 16);
        xv[2 * k + 1] = __uint_as_float(wsr[k] & 0xFFFF0000u);
    }
    float s = 0.0f, q = 0.0f;
    #pragma unroll
    for (int k = 0; k < 8; ++k) { s += xv[k]; q += xv[k] * xv[k]; }
    #pragma unroll
    for (int m = 1; m < 64; m <<= 1) {
        s += __shfl_xor(s, m, 64);
        q += __shfl_xor(q, m, 64);
    }
    float mean = s * (1.0f / 512.0f);
    float var  = q * (1.0f / 512.0f) - mean * mean;
    float rstd = rsqrtf(var + 1e-5f);
    const float4* gv = (const float4*)g;
    const float4* bv = (const float4*)b;
    float4 g0 = gv[2 * l], g1 = gv[2 * l + 1];
    float4 b0 = bv[2 * l], b1 = bv[2 * l + 1];
    float ov[8];
    ov[0] = (xv[0] - mean) * rstd * g0.x + b0.x;
    ov[1] = (xv[1] - mean) * rstd * g0.y + b0.y;
    ov[2] = (xv[2] - mean) * rstd * g0.z + b0.z;
    ov[3] = (xv[3] - mean) * rstd * g0.w + b0.w;
    ov[4] = (xv[4] - mean) * rstd * g1.x + b1.x;
    ov[5] = (xv[5] - mean) * rstd * g1.y + b1.y;
    ov[6] = (xv[6] - mean) * rstd * g1.z + b1.z;
    ov[7] = (xv[7] - mean) * rstd * g1.w + b1.w;
    uint4 o;
    o.x = pk2bf(ov[0], ov[1]);
    o.y = pk2bf(ov[2], ov[3]);
    o.z = pk2bf(ov[4], ov[5]);
    o.w = pk2bf(ov[6], ov[7]);
    ((uint4*)(xb + (size_t)row * 512))[l] = o;
}

// ---------- fused attention v7: 8 waves x 16 q-rows, 2 blocks/CU, setprio -----
// grid (64 bh, 8 qb), 512 thr. Max-free exp2 softmax (Q prescaled 0.125*log2e).
// LDS 48KB: K/V dbuf (32KB) + per-wave 2KB P tile.
__global__ __launch_bounds__(512) void attn_kernel(
    const u16* __restrict__ Q, const u16* __restrict__ Km,
    const u16* __restrict__ vT, u16* __restrict__ O)
{
    __shared__ __align__(16) u16 Kt[2][64 * 64];
    __shared__ __align__(16) u16 Vt[2][64 * 64];
    __shared__ __align__(16) char Pl[8][2048];
    const int tid = threadIdx.x;
    const int l = tid & 63;
    const int w = tid >> 6;             // 0..7
    const int g = l >> 4;
    const int q15 = l & 15;
    const int bh = blockIdx.x;
    const int qb = blockIdx.y;          // 0..7
    const int b = bh >> 3, h = bh & 7;
    const int rowQ0 = b * 1024 + qb * 128 + w * 16;
    const int colh = h * 64;
    char* pl = &Pl[w][0];
    const int rbase = q15 * 128;
    const int sw = (q15 & 7) << 4;

    const int srow = l >> 3;
    const u16* Kbase = Km + (size_t)(b * 1024) * 512 + colh;
    const u16* Vbase = vT + (size_t)bh * 64 * 1024;

    B8 qf[2];
    #pragma unroll
    for (int kc = 0; kc < 2; ++kc)
        qf[kc].s = *(const s16x8*)&Q[(size_t)(rowQ0 + q15) * 512
                                     + colh + kc * 32 + g * 8];

    f32x4 oacc[4] = {};
    float lrun = 0.0f;

    // wave w stages chunk w (8 rows) of K and of V: one gld16 each.
    auto stage = [&](int buf, int kt) {
        int r = w * 8 + srow;
        int cc = (l & 7) ^ (r & 7);
        gld16(Kbase + (size_t)(kt * 64 + r) * 512 + cc * 8, &Kt[buf][w * 512]);
        gld16(Vbase + (size_t)r * 1024 + kt * 64 + cc * 8, &Vt[buf][w * 512]);
    };

    stage(0, 0);
    __syncthreads();
    int cur = 0;

    for (int kt = 0; kt < 16; ++kt) {
        if (kt < 15) stage(cur ^ 1, kt + 1);
        const u16* KtL = &Kt[cur][0];
        const u16* VtL = &Vt[cur][0];

        // --- S' = K (Q*0.125*log2e)^T; lane holds S'[mt*16+g*4+jj][q15]
        f32x4 st[4];
        __builtin_amdgcn_s_setprio(1);
        #pragma unroll
        for (int mt = 0; mt < 4; ++mt) {
            int r = mt * 16 + q15;
            B8 kf0, kf1;
            kf0.s = *(const s16x8*)&KtL[r * 64 + ((g ^ (r & 7)) * 8)];
            kf1.s = *(const s16x8*)&KtL[r * 64 + (((4 + g) ^ (r & 7)) * 8)];
            f32x4 t = {0.f, 0.f, 0.f, 0.f};
            t = __builtin_amdgcn_mfma_f32_16x16x32_bf16(kf0.b, qf[0].b, t, 0, 0, 0);
            t = __builtin_amdgcn_mfma_f32_16x16x32_bf16(kf1.b, qf[1].b, t, 0, 0, 0);
            st[mt] = t;
        }
        __builtin_amdgcn_s_setprio(0);

        // --- P = exp2(S'); row-sum; pack bf16 to per-wave LDS
        float rs = 0.0f;
        #pragma unroll
        for (int mt = 0; mt < 4; ++mt) {
            float e0 = fexp2(st[mt][0]);
            float e1 = fexp2(st[mt][1]);
            float e2 = fexp2(st[mt][2]);
            float e3 = fexp2(st[mt][3]);
            rs += (e0 + e1) + (e2 + e3);
            uint2 pk;
            pk.x = pk2bf(e0, e1);
            pk.y = pk2bf(e2, e3);
            *(uint2*)(pl + rbase + ((mt * 32 + g * 8) ^ sw)) = pk;
        }
        rs += __shfl_xor(rs, 16, 64);
        rs += __shfl_xor(rs, 32, 64);
        lrun += rs;

        // --- read P^T B-frags
        B8 pf0, pf1;
        pf0.s = *(const s16x8*)(pl + rbase + ((g * 16) ^ sw));
        pf1.s = *(const s16x8*)(pl + rbase + (((4 + g) * 16) ^ sw));

        // --- O^T += V^T * P^T
        __builtin_amdgcn_s_setprio(1);
        #pragma unroll
        for (int dt = 0; dt < 4; ++dt) {
            int r = dt * 16 + q15;
            B8 vf0, vf1;
            vf0.s = *(const s16x8*)&VtL[r * 64 + ((g ^ (r & 7)) * 8)];
            vf1.s = *(const s16x8*)&VtL[r * 64 + (((4 + g) ^ (r & 7)) * 8)];
            oacc[dt] = __builtin_amdgcn_mfma_f32_16x16x32_bf16(
                vf0.b, pf0.b, oacc[dt], 0, 0, 0);
            oacc[dt] = __builtin_amdgcn_mfma_f32_16x16x32_bf16(
                vf1.b, pf1.b, oacc[dt], 0, 0, 0);
        }
        __builtin_amdgcn_s_setprio(0);
        __syncthreads();
        cur ^= 1;
    }

    // --- epilogue: O[q][d] = O^T / l
    float inv = 1.0f / lrun;
    int row = rowQ0 + q15;
    #pragma unroll
    for (int dt = 0; dt < 4; ++dt) {
        uint2 o;
        o.x = pk2bf(oacc[dt][0] * inv, oacc[dt][1] * inv);
        o.y = pk2bf(oacc[dt][2] * inv, oacc[dt][3] * inv);
        *(uint2*)&O[(size_t)row * 512 + colh + dt * 16 + g * 4] = o;
    }
}

// ---------- launcher ----------
extern "C" void kernel_launch(void* const* d_in, const int* in_sizes, int n_in,
                              void* d_out, int out_size, void* d_ws, size_t ws_size,
                              hipStream_t stream)
{
    const int D = 512, F = 2048, Lc = 4;
    const int Mrows = 8 * 1024;

    const float* Wq   = (const float*)d_in[1];
    const float* Wk   = (const float*)d_in[2];
    const float* Wv   = (const float*)d_in[3];
    const float* bq   = (const float*)d_in[4];
    const float* bk   = (const float*)d_in[5];
    const float* bv   = (const float*)d_in[6];
    const float* Wo   = (const float*)d_in[7];
    const float* bo   = (const float*)d_in[8];
    const float* ln1g = (const float*)d_in[9];
    const float* ln1b = (const float*)d_in[10];
    const float* ln2g = (const float*)d_in[11];
    const float* ln2b = (const float*)d_in[12];
    const float* W1   = (const float*)d_in[13];
    const float* b1   = (const float*)d_in[14];
    const float* W2   = (const float*)d_in[15];
    const float* b2   = (const float*)d_in[16];
    const float* Wout = (const float*)d_in[17];
    const float* bout = (const float*)d_in[18];

    char* p = (char*)d_ws;
    auto alloc = [&](size_t bytes) {
        char* r = p;
        p += (bytes + 255) & ~(size_t)255;
        return r;
    };
    u16* xb = (u16*)alloc((size_t)Mrows * D * 2);
    u16* y  = (u16*)alloc((size_t)Mrows * D * 2);
    char* pool = alloc((size_t)Mrows * F * 2);
    u16* qb_ = (u16*)pool;
    u16* kb_ = (u16*)(pool + (size_t)Mrows * D * 2);
    u16* vT  = (u16*)(pool + (size_t)Mrows * D * 2 * 2);
    u16* ao  = (u16*)(pool + (size_t)Mrows * D * 2 * 3);
    u16* ff1 = (u16*)pool;
    u16* wAll  = (u16*)alloc((size_t)12845056 * 2);
    u16* wqkvB = wAll;
    u16* woB   = wAll + 3145728;
    u16* w1B   = wAll + 4194304;
    u16* w2B   = wAll + 8388608;
    u16* woutB = wAll + 12582912;

    {
        int n4 = 12845056 / 4;
        cvt_all_kernel<<<(n4 + 255) / 256, 256, 0, stream>>>(
            Wq, Wk, Wv, Wo, W1, W2, Wout, wAll, n4);
    }

    // DDIM noise coefficients
    float ac[1000];
    {
        float start = 1e-4f, stop = 0.02f;
        float delta = (stop - start) / 999.0f;
        float prod = 1.0f;
        for (int i = 0; i < 1000; ++i) {
            float beta = start + (float)i * delta;
            prod *= (1.0f - beta);
            ac[i] = prod;
        }
    }
    int ts[2] = {999, 998};
    double cs[2];
    double tail = 1.0;
    for (int idx = 0; idx < 2; ++idx) {
        int t = ts[idx];
        cs[idx] = sqrt(1.0 - (double)ac[t]) * tail;
        tail *= sqrt((double)ac[t]);
    }
    uint32_t kk[2][2];
    for (int idx = 0; idx < 2; ++idx) {
        uint32_t x0 = 0u, x1 = (uint32_t)ts[idx];
        tf2x32_h(0u, 42u, x0, x1);
        kk[idx][0] = x0; kk[idx][1] = x1;
    }
    int n4tot = Mrows * D / 4;
    noise_kernel<<<(n4tot + 255) / 256, 256, 0, stream>>>(
        xb,
        kk[0][0], kk[0][1], (float)cs[0],
        kk[1][0], kk[1][1], (float)cs[1], n4tot);

    dim3 gqkv(3 * D / 64, Mrows / 128);    // (24, 64) = 1536
    dim3 g64(D / 64, Mrows / 128);         // (8, 64) = 512
    dim3 gff1(F / 64, Mrows / 128);        // (32, 64) = 2048

    for (int l = 0; l < Lc; ++l) {
        const u16* wqkv_l = wqkvB + (size_t)l * 3 * D * D;
        const u16* wo_l = woB + (size_t)l * D * D;
        const u16* w1_l = w1B + (size_t)l * F * D;
        const u16* w2_l = w2B + (size_t)l * D * F;

        gemm64u<3><<<gqkv, 512, 0, stream>>>(
            xb, wqkv_l, bq + l * D, bk + l * D, bv + l * D, nullptr,
            qb_, kb_, vT, 3 * D, D);
        attn_kernel<<<dim3(64, 8), 512, 0, stream>>>(qb_, kb_, vT, ao);
        gemm64u<1><<<g64, 512, 0, stream>>>(
            ao, wo_l, bo + l * D, nullptr, nullptr, xb,
            y, nullptr, nullptr, D, D);
        ln_kernel<<<Mrows / 4, 256, 0, stream>>>(y, ln1g + l * D, ln1b + l * D, xb);
        gemm64u<2><<<gff1, 512, 0, stream>>>(
            xb, w1_l, b1 + l * F, nullptr, nullptr, nullptr,
            ff1, nullptr, nullptr, F, D);
        gemm64u<1><<<g64, 512, 0, stream>>>(
            ff1, w2_l, b2 + l * D, nullptr, nullptr, xb,
            y, nullptr, nullptr, D, F);
        ln_kernel<<<Mrows / 4, 256, 0, stream>>>(y, ln2g + l * D, ln2b + l * D, xb);
    }
    gemm64u<0><<<g64, 512, 0, stream>>>(
        xb, woutB, bout, nullptr, nullptr, nullptr,
        d_out, nullptr, nullptr, D, D);
}